// Round 2
// baseline (1205.431 us; speedup 1.0000x reference)
//
#include <hip/hip_runtime.h>
#include <math.h>

#define N_NODES 512
#define T 128
#define E_EDGES 4096
#define C0 64
#define EMBED 256
#define C1 128
#define C2 128
#define NG 8
#define EPS 1e-5f

// ---------------- small setup kernels ----------------

__global__ void k_zero(float* S, int* DEG, int* CUR) {
    int i = threadIdx.x;
    if (i < 640) S[i] = 0.f;
    if (i < 512) { DEG[i] = 0; CUR[i] = 0; }
}

__global__ void k_count(const int* __restrict__ dst, int* DEG) {
    int e = blockIdx.x * 256 + threadIdx.x;
    if (e < E_EDGES) atomicAdd(&DEG[dst[e]], 1);
}

__global__ void k_scan(const int* __restrict__ DEG, int* RS, float* DINV) {
    __shared__ int s[512];
    int n = threadIdx.x;
    int d = DEG[n];
    s[n] = d;
    DINV[n] = rsqrtf((float)d + 1.0f);
    __syncthreads();
    for (int off = 1; off < 512; off <<= 1) {
        int v = (n >= off) ? s[n - off] : 0;
        __syncthreads();
        s[n] += v;
        __syncthreads();
    }
    RS[n + 1] = s[n];
    if (n == 0) RS[0] = 0;
}

__global__ void k_fill(const int* __restrict__ src, const int* __restrict__ dst,
                       const int* __restrict__ RS, int* CUR, int* CSR) {
    int e = blockIdx.x * 256 + threadIdx.x;
    if (e < E_EDGES) {
        int d = dst[e];
        int p = atomicAdd(&CUR[d], 1);
        CSR[RS[d] + p] = src[e];
    }
}

// ---------------- position encoder MLP ----------------
__global__ void k_pe(const float* __restrict__ pos, const float* __restrict__ Wp1,
                     const float* __restrict__ bp1, const float* __restrict__ Wp2,
                     const float* __restrict__ bp2, float* __restrict__ PE) {
    int n = blockIdx.x;
    int c = threadIdx.x; // 64
    __shared__ float hid[64];
    float p0 = pos[n * 3], p1 = pos[n * 3 + 1], p2 = pos[n * 3 + 2];
    float h = p0 * Wp1[c] + p1 * Wp1[64 + c] + p2 * Wp1[128 + c] + bp1[c];
    hid[c] = fmaxf(h, 0.f);
    __syncthreads();
    float acc = bp2[c];
    #pragma unroll
    for (int j = 0; j < 64; ++j) acc += hid[j] * Wp2[j * 64 + c];
    PE[n * 64 + c] = acc;
}

// ---------------- conv1 (1->64, k=7, SAME) + BN stats ----------------
__global__ void k_conv1(const float* __restrict__ x, const float* __restrict__ W1,
                        float* __restrict__ C, float* S) {
    int n = blockIdx.x;
    int tid = threadIdx.x; // 256
    int c = tid & 63, tg = tid >> 6;
    __shared__ float xs[134];
    __shared__ float ws[448];
    __shared__ float red[256];
    for (int i = tid; i < 448; i += 256) ws[i] = W1[i];
    for (int i = tid; i < 134; i += 256) {
        int t = i - 3;
        xs[i] = (t >= 0 && t < T) ? x[n * T + t] : 0.f;
    }
    __syncthreads();
    float s1 = 0.f, s2 = 0.f;
    for (int t = tg; t < T; t += 4) {
        float acc = 0.f;
        #pragma unroll
        for (int k = 0; k < 7; ++k) acc += xs[t + k] * ws[k * 64 + c];
        C[(n * T + t) * 64 + c] = acc;
        s1 += acc; s2 += acc * acc;
    }
    red[tid] = s1; __syncthreads();
    if (tg == 0) { float v = red[c] + red[64 + c] + red[128 + c] + red[192 + c]; atomicAdd(&S[c], v); }
    __syncthreads();
    red[tid] = s2; __syncthreads();
    if (tg == 0) { float v = red[c] + red[64 + c] + red[128 + c] + red[192 + c]; atomicAdd(&S[64 + c], v); }
}

// ---------------- BN1 apply + ReLU + add pe (in place) ----------------
__global__ void k_bn1(float* __restrict__ C, const float* __restrict__ S,
                      const float* __restrict__ g1, const float* __restrict__ b1,
                      const float* __restrict__ PE) {
    int n = blockIdx.x, tid = threadIdx.x;
    int c = tid & 63, tg = tid >> 6;
    const float inv = 1.f / (float)(N_NODES * T);
    float mean = S[c] * inv;
    float var  = S[64 + c] * inv - mean * mean;
    float sc = g1[c] * rsqrtf(var + EPS);
    float sh = b1[c] - mean * sc;
    float pe = PE[n * 64 + c];
    for (int t = tg; t < T; t += 4) {
        int idx = (n * T + t) * 64 + c;
        C[idx] = fmaxf(C[idx] * sc + sh, 0.f) + pe;
    }
}

// ---------------- register-tiled GEMM: (65536 x K) @ (K x 256) ----------------
template <int K>
__global__ __launch_bounds__(256) void k_gemm(const float* __restrict__ X,
                                              const float* __restrict__ W,
                                              float* __restrict__ Y) {
    __shared__ float As[32][65];   // [k][r], padded
    __shared__ float Ws[32 * 256]; // [k][c]
    int tid = threadIdx.x;
    int ct = tid & 31, rt = tid >> 5;
    int row0 = blockIdx.x * 64;
    float acc[8][8];
    #pragma unroll
    for (int i = 0; i < 8; ++i)
        #pragma unroll
        for (int j = 0; j < 8; ++j) acc[i][j] = 0.f;
    int lr = tid >> 2;        // 0..63
    int lk = (tid & 3) * 8;   // 0,8,16,24
    for (int kk = 0; kk < K; kk += 32) {
        __syncthreads();
        #pragma unroll
        for (int k = 0; k < 32; ++k) Ws[k * 256 + tid] = W[(kk + k) * 256 + tid];
        const float* xp = &X[(size_t)(row0 + lr) * K + kk + lk];
        #pragma unroll
        for (int j = 0; j < 8; ++j) As[lk + j][lr] = xp[j];
        __syncthreads();
        for (int k = 0; k < 32; ++k) {
            float a[8], w[8];
            #pragma unroll
            for (int i = 0; i < 8; ++i) a[i] = As[k][rt * 8 + i];
            #pragma unroll
            for (int j = 0; j < 8; ++j) w[j] = Ws[k * 256 + ct + 32 * j];
            #pragma unroll
            for (int i = 0; i < 8; ++i)
                #pragma unroll
                for (int j = 0; j < 8; ++j) acc[i][j] += a[i] * w[j];
        }
    }
    #pragma unroll
    for (int i = 0; i < 8; ++i) {
        size_t row = row0 + rt * 8 + i;
        #pragma unroll
        for (int j = 0; j < 8; ++j) Y[row * 256 + ct + 32 * j] = acc[i][j];
    }
}

// ---------------- GCN aggregation: Y[n] = relu(sum_e norm*X[src] + X[n]*dinv^2 + b) ----------------
__global__ void k_agg(const float* __restrict__ X, float* __restrict__ Y,
                      const float* __restrict__ bias, const float* __restrict__ DINV,
                      const int* __restrict__ RS, const int* __restrict__ CSR) {
    int n = blockIdx.x, tq = blockIdx.y;
    int c = threadIdx.x; // 256
    __shared__ int   ss[512];
    __shared__ float sw[512];
    int start = RS[n], deg = RS[n + 1] - start;
    float dn = DINV[n];
    for (int j = c; j < deg; j += 256) {
        int s = CSR[start + j];
        ss[j] = s;
        sw[j] = dn * DINV[s];
    }
    __syncthreads();
    float b = bias[c];
    float dn2 = dn * dn;
    for (int t = tq * 32; t < tq * 32 + 32; ++t) {
        float acc = X[((size_t)n * T + t) * EMBED + c] * dn2;
        for (int j = 0; j < deg; ++j)
            acc += X[((size_t)ss[j] * T + t) * EMBED + c] * sw[j];
        Y[((size_t)n * T + t) * EMBED + c] = fmaxf(acc + b, 0.f);
    }
}

// ---------------- conv2 (256->128, k=7, VALID): 8 outputs per block ----------------
__global__ __launch_bounds__(128) void k_conv2(const float* __restrict__ H,
                                               const float* __restrict__ W2,
                                               float* __restrict__ OUT) {
    int chunk = blockIdx.x; // 0..15
    int n = blockIdx.y;
    int c = threadIdx.x;    // 128
    int t0 = chunk * 8;
    __shared__ float hs[14 * 256];
    int nrows = min(14, T - t0);
    for (int i = c; i < nrows * 256; i += 128) hs[i] = H[((size_t)n * T + t0) * 256 + i];
    __syncthreads();
    float acc[8];
    #pragma unroll
    for (int j = 0; j < 8; ++j) acc[j] = 0.f;
    for (int cin = 0; cin < 256; ++cin) {
        float hreg[14];
        #pragma unroll
        for (int r = 0; r < 14; ++r) hreg[r] = hs[r * 256 + cin];
        #pragma unroll
        for (int k = 0; k < 7; ++k) {
            float w = W2[(k * 256 + cin) * 128 + c];
            #pragma unroll
            for (int j = 0; j < 8; ++j) acc[j] += hreg[j + k] * w;
        }
    }
    #pragma unroll
    for (int j = 0; j < 8; ++j) {
        int t = t0 + j;
        if (t < 122) OUT[((size_t)n * 122 + t) * 128 + c] = acc[j];
    }
}

// ---------------- BN2 stats reduction ----------------
__global__ void k_stats2(const float* __restrict__ OUT, float* S) {
    int c = threadIdx.x; // 128
    int b = blockIdx.x;  // 256
    const int R = N_NODES * 122;       // 62464
    const int chunk = (R + 255) / 256; // 244
    int r0 = b * chunk, r1 = min(R, r0 + chunk);
    float s1 = 0.f, s2 = 0.f;
    for (int r = r0; r < r1; ++r) {
        float v = OUT[(size_t)r * 128 + c];
        s1 += v; s2 += v * v;
    }
    atomicAdd(&S[128 + c], s1);
    atomicAdd(&S[256 + c], s2);
}

// ---------------- BN2 apply + avgpool4 + ReLU ----------------
__global__ void k_bn2pool(const float* __restrict__ OUT, const float* __restrict__ S,
                          const float* __restrict__ g2, const float* __restrict__ b2,
                          float* __restrict__ P1) {
    int n = blockIdx.x;
    int c = threadIdx.x; // 128
    const float inv = 1.f / (float)(N_NODES * 122);
    float mean = S[128 + c] * inv;
    float var  = S[256 + c] * inv - mean * mean;
    float sc = g2[c] * rsqrtf(var + EPS);
    float sh = b2[c] - mean * sc;
    for (int tp = 0; tp < 30; ++tp) {
        float s = 0.f;
        #pragma unroll
        for (int i = 0; i < 4; ++i) s += OUT[((size_t)n * 122 + tp * 4 + i) * 128 + c];
        P1[((size_t)n * 30 + tp) * 128 + c] = fmaxf(s * 0.25f * sc + sh, 0.f);
    }
}

// ---------------- global mean pool over 64 nodes/graph ----------------
__global__ void k_gmean(const float* __restrict__ P1, float* __restrict__ GP) {
    int b = blockIdx.x / 30, tp = blockIdx.x % 30;
    int c = threadIdx.x; // 128
    float s = 0.f;
    for (int i = 0; i < 64; ++i) s += P1[((size_t)(b * 64 + i) * 30 + tp) * 128 + c];
    GP[((size_t)b * 30 + tp) * 128 + c] = s * (1.f / 64.f);
}

// ---------------- conv3 (128->128, k=3, VALID) + BN3 stats ----------------
__global__ void k_conv3(const float* __restrict__ GP, const float* __restrict__ W3,
                        float* __restrict__ C3, float* S) {
    int b = blockIdx.x / 28, t = blockIdx.x % 28;
    int c = threadIdx.x; // 128
    __shared__ float gs[3 * 128];
    for (int i = c; i < 384; i += 128) gs[i] = GP[((size_t)b * 30 + t) * 128 + i];
    __syncthreads();
    float acc = 0.f;
    for (int i = 0; i < 384; ++i) acc += gs[i] * W3[i * 128 + c];
    C3[((size_t)b * 28 + t) * 128 + c] = acc;
    atomicAdd(&S[384 + c], acc);
    atomicAdd(&S[512 + c], acc * acc);
}

// ---------------- BN3 apply + avgpool4 + ReLU ----------------
__global__ void k_bn3pool(const float* __restrict__ C3, const float* __restrict__ S,
                          const float* __restrict__ g3, const float* __restrict__ b3,
                          float* __restrict__ P2) {
    int b = blockIdx.x;  // 8
    int c = threadIdx.x; // 128
    const float inv = 1.f / (float)(NG * 28);
    float mean = S[384 + c] * inv;
    float var  = S[512 + c] * inv - mean * mean;
    float sc = g3[c] * rsqrtf(var + EPS);
    float sh = b3[c] - mean * sc;
    for (int tp = 0; tp < 7; ++tp) {
        float s = 0.f;
        #pragma unroll
        for (int i = 0; i < 4; ++i) s += C3[((size_t)b * 28 + tp * 4 + i) * 128 + c];
        P2[((size_t)b * 7 + tp) * 128 + c] = fmaxf(s * 0.25f * sc + sh, 0.f);
    }
}

// ---------------- final linear + log_softmax ----------------
__global__ void k_final(const float* __restrict__ P2, const float* __restrict__ Wd,
                        const float* __restrict__ bd, float* __restrict__ out) {
    int tid = threadIdx.x; // 32
    int b = tid >> 2, j = tid & 3;
    float acc = bd[j];
    for (int i = 0; i < 896; ++i) acc += P2[b * 896 + i] * Wd[i * 4 + j];
    float m = acc;
    m = fmaxf(m, __shfl_xor(m, 1, 4));
    m = fmaxf(m, __shfl_xor(m, 2, 4));
    float e = expf(acc - m);
    float s = e;
    s += __shfl_xor(s, 1, 4);
    s += __shfl_xor(s, 2, 4);
    out[tid] = acc - m - logf(s);
}

extern "C" void kernel_launch(void* const* d_in, const int* in_sizes, int n_in,
                              void* d_out, int out_size, void* d_ws, size_t ws_size,
                              hipStream_t stream) {
    const float* x   = (const float*)d_in[0];
    const float* pos = (const float*)d_in[1];
    const int*   ei  = (const int*)d_in[2];
    // d_in[3] = batch (deterministic arange//64, not needed)
    const float* W1  = (const float*)d_in[4];
    const float* g1  = (const float*)d_in[5];
    const float* b1  = (const float*)d_in[6];
    const float* Wp1 = (const float*)d_in[7];
    const float* bp1 = (const float*)d_in[8];
    const float* Wp2 = (const float*)d_in[9];
    const float* bp2 = (const float*)d_in[10];
    const float* Wg1 = (const float*)d_in[11];
    const float* bg1 = (const float*)d_in[12];
    const float* Wg2 = (const float*)d_in[13];
    const float* bg2 = (const float*)d_in[14];
    const float* W2  = (const float*)d_in[15];
    const float* g2  = (const float*)d_in[16];
    const float* b2  = (const float*)d_in[17];
    const float* W3  = (const float*)d_in[18];
    const float* g3  = (const float*)d_in[19];
    const float* b3  = (const float*)d_in[20];
    const float* Wd  = (const float*)d_in[21];
    const float* bd  = (const float*)d_in[22];
    float* out = (float*)d_out;

    float* ws = (float*)d_ws;
    float* A   = ws;                 // 16,777,216 : GCN matmul out / conv2 out
    float* B   = A + 16777216;       // 16,777,216 : GCN agg out
    float* C   = B + 16777216;       //  4,194,304 : conv1 / h0 (in-place BN)
    float* PE  = C + 4194304;        //     32,768
    float* P1  = PE + 32768;         //  1,966,080
    float* GPb = P1 + 1966080;       //     30,720
    float* C3  = GPb + 30720;        //     28,672
    float* P2  = C3 + 28672;         //      7,168
    float* S   = P2 + 7168;          //        640 : BN stats
    float* DINV = S + 640;           //        512
    int* DEG = (int*)(DINV + 512);   //        512
    int* RS  = DEG + 512;            //        513
    int* CUR = RS + 513;             //        512
    int* CSR = CUR + 512;            //      4,096
    const int* srcv = ei;
    const int* dstv = ei + E_EDGES;

    hipLaunchKernelGGL(k_zero,  dim3(1),        dim3(1024), 0, stream, S, DEG, CUR);
    hipLaunchKernelGGL(k_count, dim3(16),       dim3(256),  0, stream, dstv, DEG);
    hipLaunchKernelGGL(k_scan,  dim3(1),        dim3(512),  0, stream, DEG, RS, DINV);
    hipLaunchKernelGGL(k_fill,  dim3(16),       dim3(256),  0, stream, srcv, dstv, RS, CUR, CSR);
    hipLaunchKernelGGL(k_pe,    dim3(512),      dim3(64),   0, stream, pos, Wp1, bp1, Wp2, bp2, PE);
    hipLaunchKernelGGL(k_conv1, dim3(512),      dim3(256),  0, stream, x, W1, C, S);
    hipLaunchKernelGGL(k_bn1,   dim3(512),      dim3(256),  0, stream, C, S, g1, b1, PE);
    hipLaunchKernelGGL(k_gemm<64>,  dim3(1024), dim3(256),  0, stream, C, Wg1, A);
    hipLaunchKernelGGL(k_agg,   dim3(512, 4),   dim3(256),  0, stream, A, B, bg1, DINV, RS, CSR);
    hipLaunchKernelGGL(k_gemm<256>, dim3(1024), dim3(256),  0, stream, B, Wg2, A);
    hipLaunchKernelGGL(k_agg,   dim3(512, 4),   dim3(256),  0, stream, A, B, bg2, DINV, RS, CSR);
    hipLaunchKernelGGL(k_conv2, dim3(16, 512),  dim3(128),  0, stream, B, W2, A);
    hipLaunchKernelGGL(k_stats2, dim3(256),     dim3(128),  0, stream, A, S);
    hipLaunchKernelGGL(k_bn2pool, dim3(512),    dim3(128),  0, stream, A, S, g2, b2, P1);
    hipLaunchKernelGGL(k_gmean, dim3(240),      dim3(128),  0, stream, P1, GPb);
    hipLaunchKernelGGL(k_conv3, dim3(224),      dim3(128),  0, stream, GPb, W3, C3, S);
    hipLaunchKernelGGL(k_bn3pool, dim3(8),      dim3(128),  0, stream, C3, S, g3, b3, P2);
    hipLaunchKernelGGL(k_final, dim3(1),        dim3(32),   0, stream, P2, Wd, bd, out);
}

// Round 3
// 708.224 us; speedup vs baseline: 1.7020x; 1.7020x over previous
//
#include <hip/hip_runtime.h>
#include <math.h>

#define N_NODES 512
#define T 128
#define E_EDGES 4096
#define C0 64
#define EMBED 256
#define C1 128
#define C2 128
#define NG 8
#define EPS 1e-5f

typedef unsigned short ushort_t;
typedef short bf16x8 __attribute__((ext_vector_type(8)));
typedef float f32x4 __attribute__((ext_vector_type(4)));

__device__ __forceinline__ ushort_t f2bf(float f) {
    union { float f; unsigned int u; } v; v.f = f;
    unsigned int r = v.u + 0x7fffu + ((v.u >> 16) & 1u);
    return (ushort_t)(r >> 16);
}
__device__ __forceinline__ float bf2f(ushort_t h) {
    union { unsigned int u; float f; } v; v.u = ((unsigned int)h) << 16;
    return v.f;
}

// ---------------- small setup kernels ----------------

__global__ void k_zero(float* S, int* DEG, int* CUR) {
    int i = threadIdx.x;
    if (i < 640) S[i] = 0.f;
    if (i < 512) { DEG[i] = 0; CUR[i] = 0; }
}

__global__ void k_count(const int* __restrict__ dst, int* DEG) {
    int e = blockIdx.x * 256 + threadIdx.x;
    if (e < E_EDGES) atomicAdd(&DEG[dst[e]], 1);
}

__global__ void k_scan(const int* __restrict__ DEG, int* RS, float* DINV) {
    __shared__ int s[512];
    int n = threadIdx.x;
    int d = DEG[n];
    s[n] = d;
    DINV[n] = rsqrtf((float)d + 1.0f);
    __syncthreads();
    for (int off = 1; off < 512; off <<= 1) {
        int v = (n >= off) ? s[n - off] : 0;
        __syncthreads();
        s[n] += v;
        __syncthreads();
    }
    RS[n + 1] = s[n];
    if (n == 0) RS[0] = 0;
}

__global__ void k_fill(const int* __restrict__ src, const int* __restrict__ dst,
                       const int* __restrict__ RS, int* CUR, int* CSR) {
    int e = blockIdx.x * 256 + threadIdx.x;
    if (e < E_EDGES) {
        int d = dst[e];
        int p = atomicAdd(&CUR[d], 1);
        CSR[RS[d] + p] = src[e];
    }
}

// ---------------- weight convert+transpose: in f32 (K x N) -> out bf16 (N x K) ----------------
__global__ void k_cvtw(const float* __restrict__ in, ushort_t* __restrict__ out, int K, int N) {
    int i = blockIdx.x * 256 + threadIdx.x;
    if (i < K * N) {
        int n = i / K, k = i % K;
        out[i] = f2bf(in[k * N + n]);
    }
}

// ---------------- position encoder MLP ----------------
__global__ void k_pe(const float* __restrict__ pos, const float* __restrict__ Wp1,
                     const float* __restrict__ bp1, const float* __restrict__ Wp2,
                     const float* __restrict__ bp2, float* __restrict__ PE) {
    int n = blockIdx.x;
    int c = threadIdx.x; // 64
    __shared__ float hid[64];
    float p0 = pos[n * 3], p1 = pos[n * 3 + 1], p2 = pos[n * 3 + 2];
    float h = p0 * Wp1[c] + p1 * Wp1[64 + c] + p2 * Wp1[128 + c] + bp1[c];
    hid[c] = fmaxf(h, 0.f);
    __syncthreads();
    float acc = bp2[c];
    #pragma unroll
    for (int j = 0; j < 64; ++j) acc += hid[j] * Wp2[j * 64 + c];
    PE[n * 64 + c] = acc;
}

// ---------------- conv1 (1->64, k=7, SAME) + BN stats ----------------
__global__ void k_conv1(const float* __restrict__ x, const float* __restrict__ W1,
                        float* __restrict__ C, float* S) {
    int n = blockIdx.x;
    int tid = threadIdx.x; // 256
    int c = tid & 63, tg = tid >> 6;
    __shared__ float xs[134];
    __shared__ float ws[448];
    __shared__ float red[256];
    for (int i = tid; i < 448; i += 256) ws[i] = W1[i];
    for (int i = tid; i < 134; i += 256) {
        int t = i - 3;
        xs[i] = (t >= 0 && t < T) ? x[n * T + t] : 0.f;
    }
    __syncthreads();
    float s1 = 0.f, s2 = 0.f;
    for (int t = tg; t < T; t += 4) {
        float acc = 0.f;
        #pragma unroll
        for (int k = 0; k < 7; ++k) acc += xs[t + k] * ws[k * 64 + c];
        C[(n * T + t) * 64 + c] = acc;
        s1 += acc; s2 += acc * acc;
    }
    red[tid] = s1; __syncthreads();
    if (tg == 0) { float v = red[c] + red[64 + c] + red[128 + c] + red[192 + c]; atomicAdd(&S[c], v); }
    __syncthreads();
    red[tid] = s2; __syncthreads();
    if (tg == 0) { float v = red[c] + red[64 + c] + red[128 + c] + red[192 + c]; atomicAdd(&S[64 + c], v); }
}

// ---------------- BN1 apply + ReLU + add pe -> bf16 H0 ----------------
__global__ void k_bn1(const float* __restrict__ C, const float* __restrict__ S,
                      const float* __restrict__ g1, const float* __restrict__ b1,
                      const float* __restrict__ PE, ushort_t* __restrict__ H0b) {
    int n = blockIdx.x, tid = threadIdx.x;
    int c = tid & 63, tg = tid >> 6;
    const float inv = 1.f / (float)(N_NODES * T);
    float mean = S[c] * inv;
    float var  = S[64 + c] * inv - mean * mean;
    float sc = g1[c] * rsqrtf(var + EPS);
    float sh = b1[c] - mean * sc;
    float pe = PE[n * 64 + c];
    for (int t = tg; t < T; t += 4) {
        int idx = (n * T + t) * 64 + c;
        H0b[idx] = f2bf(fmaxf(C[idx] * sc + sh, 0.f) + pe);
    }
}

// ---------------- MFMA GEMM: X (65536 x K) bf16 @ WT (256 x K) bf16 -> Y (65536 x 256) bf16 ----------------
template <int K>
__global__ __launch_bounds__(512) void k_gemm_mfma(const ushort_t* __restrict__ X,
                                                   const ushort_t* __restrict__ WT,
                                                   ushort_t* __restrict__ Y) {
    __shared__ ushort_t Xs[128 * 40];
    __shared__ ushort_t Ws[256 * 40];
    int tid = threadIdx.x;
    int l = tid & 63, wid = tid >> 6;
    int wr = wid >> 2, wc = wid & 3;
    int row0 = blockIdx.x * 128;
    int lrow = l & 15, lko = (l >> 4) * 8;

    f32x4 acc[4][4];
    #pragma unroll
    for (int i = 0; i < 4; ++i)
        #pragma unroll
        for (int j = 0; j < 4; ++j) acc[i][j] = (f32x4){0.f, 0.f, 0.f, 0.f};

    int srow = tid >> 2, schunk = (tid & 3) * 8;
    for (int kk = 0; kk < K; kk += 32) {
        __syncthreads();
        // stage X tile: 128 rows x 32 k
        *reinterpret_cast<bf16x8*>(&Xs[srow * 40 + schunk]) =
            *reinterpret_cast<const bf16x8*>(&X[(size_t)(row0 + srow) * K + kk + schunk]);
        // stage W tile: 256 rows x 32 k
        #pragma unroll
        for (int rep = 0; rep < 2; ++rep) {
            int wrow = rep * 128 + srow;
            *reinterpret_cast<bf16x8*>(&Ws[wrow * 40 + schunk]) =
                *reinterpret_cast<const bf16x8*>(&WT[(size_t)wrow * K + kk + schunk]);
        }
        __syncthreads();
        bf16x8 a[4], b[4];
        #pragma unroll
        for (int mi = 0; mi < 4; ++mi)
            a[mi] = *reinterpret_cast<const bf16x8*>(&Xs[(wr * 64 + mi * 16 + lrow) * 40 + lko]);
        #pragma unroll
        for (int ni = 0; ni < 4; ++ni)
            b[ni] = *reinterpret_cast<const bf16x8*>(&Ws[(wc * 64 + ni * 16 + lrow) * 40 + lko]);
        #pragma unroll
        for (int mi = 0; mi < 4; ++mi)
            #pragma unroll
            for (int ni = 0; ni < 4; ++ni)
                acc[mi][ni] = __builtin_amdgcn_mfma_f32_16x16x32_bf16(a[mi], b[ni], acc[mi][ni], 0, 0, 0);
    }
    #pragma unroll
    for (int mi = 0; mi < 4; ++mi) {
        #pragma unroll
        for (int ni = 0; ni < 4; ++ni) {
            int col = wc * 64 + ni * 16 + lrow;
            #pragma unroll
            for (int r = 0; r < 4; ++r) {
                size_t row = row0 + wr * 64 + mi * 16 + (l >> 4) * 4 + r;
                Y[row * 256 + col] = f2bf(acc[mi][ni][r]);
            }
        }
    }
}

// ---------------- GCN aggregation (bf16 in/out): Y[n] = relu(sum norm*X[src] + X[n]*dinv^2 + b) ----------------
__global__ void k_agg(const ushort_t* __restrict__ X, ushort_t* __restrict__ Y,
                      const float* __restrict__ bias, const float* __restrict__ DINV,
                      const int* __restrict__ RS, const int* __restrict__ CSR) {
    int n = blockIdx.x, tq = blockIdx.y;
    int c = threadIdx.x; // 256
    __shared__ int   ss[512];
    __shared__ float sw[512];
    int start = RS[n], deg = RS[n + 1] - start;
    float dn = DINV[n];
    for (int j = c; j < deg; j += 256) {
        int s = CSR[start + j];
        ss[j] = s;
        sw[j] = dn * DINV[s];
    }
    __syncthreads();
    float b = bias[c];
    float dn2 = dn * dn;
    for (int t = tq * 32; t < tq * 32 + 32; ++t) {
        float acc = bf2f(X[((size_t)n * T + t) * EMBED + c]) * dn2;
        for (int j = 0; j < deg; ++j)
            acc += bf2f(X[((size_t)ss[j] * T + t) * EMBED + c]) * sw[j];
        Y[((size_t)n * T + t) * EMBED + c] = f2bf(fmaxf(acc + b, 0.f));
    }
}

// ---------------- conv2 as implicit MFMA GEMM: H (bf16 65536x256) * WT2 (bf16 128x1792) -> OUT f32 ----------------
__global__ __launch_bounds__(256) void k_conv2_mfma(const ushort_t* __restrict__ H,
                                                    const ushort_t* __restrict__ WT2,
                                                    float* __restrict__ OUT) {
    __shared__ ushort_t Hs[70 * 264];
    int n = blockIdx.y;
    int t0 = blockIdx.x * 64;
    int tid = threadIdx.x;
    int l = tid & 63, wid = tid >> 6;
    int lrow = l & 15, lko = (l >> 4) * 8;

    // stage 70 rows of H (clamp past end of node's time axis; results guarded)
    for (int i = tid; i < 70 * 32; i += 256) {
        int row = i >> 5, chunk = (i & 31) * 8;
        int srow = t0 + row; if (srow > 127) srow = 127;
        *reinterpret_cast<bf16x8*>(&Hs[row * 264 + chunk]) =
            *reinterpret_cast<const bf16x8*>(&H[((size_t)n * T + srow) * 256 + chunk]);
    }
    __syncthreads();

    f32x4 acc[8];
    #pragma unroll
    for (int i = 0; i < 8; ++i) acc[i] = (f32x4){0.f, 0.f, 0.f, 0.f};

    for (int tap = 0; tap < 7; ++tap) {
        for (int cinc = 0; cinc < 8; ++cinc) {
            bf16x8 a = *reinterpret_cast<const bf16x8*>(
                &Hs[(wid * 16 + lrow + tap) * 264 + cinc * 32 + lko]);
            #pragma unroll
            for (int ni = 0; ni < 8; ++ni) {
                bf16x8 b = *reinterpret_cast<const bf16x8*>(
                    &WT2[(size_t)(ni * 16 + lrow) * 1792 + tap * 256 + cinc * 32 + lko]);
                acc[ni] = __builtin_amdgcn_mfma_f32_16x16x32_bf16(a, b, acc[ni], 0, 0, 0);
            }
        }
    }
    #pragma unroll
    for (int ni = 0; ni < 8; ++ni) {
        int col = ni * 16 + lrow;
        #pragma unroll
        for (int r = 0; r < 4; ++r) {
            int t = t0 + wid * 16 + (l >> 4) * 4 + r;
            if (t < 122) OUT[((size_t)n * 122 + t) * 128 + col] = acc[ni][r];
        }
    }
}

// ---------------- BN2 stats reduction ----------------
__global__ void k_stats2(const float* __restrict__ OUT, float* S) {
    int c = threadIdx.x; // 128
    int b = blockIdx.x;  // 256
    const int R = N_NODES * 122;       // 62464
    const int chunk = (R + 255) / 256; // 244
    int r0 = b * chunk, r1 = min(R, r0 + chunk);
    float s1 = 0.f, s2 = 0.f;
    for (int r = r0; r < r1; ++r) {
        float v = OUT[(size_t)r * 128 + c];
        s1 += v; s2 += v * v;
    }
    atomicAdd(&S[128 + c], s1);
    atomicAdd(&S[256 + c], s2);
}

// ---------------- BN2 apply + avgpool4 + ReLU ----------------
__global__ void k_bn2pool(const float* __restrict__ OUT, const float* __restrict__ S,
                          const float* __restrict__ g2, const float* __restrict__ b2,
                          float* __restrict__ P1) {
    int n = blockIdx.x;
    int c = threadIdx.x; // 128
    const float inv = 1.f / (float)(N_NODES * 122);
    float mean = S[128 + c] * inv;
    float var  = S[256 + c] * inv - mean * mean;
    float sc = g2[c] * rsqrtf(var + EPS);
    float sh = b2[c] - mean * sc;
    for (int tp = 0; tp < 30; ++tp) {
        float s = 0.f;
        #pragma unroll
        for (int i = 0; i < 4; ++i) s += OUT[((size_t)n * 122 + tp * 4 + i) * 128 + c];
        P1[((size_t)n * 30 + tp) * 128 + c] = fmaxf(s * 0.25f * sc + sh, 0.f);
    }
}

// ---------------- global mean pool over 64 nodes/graph ----------------
__global__ void k_gmean(const float* __restrict__ P1, float* __restrict__ GP) {
    int b = blockIdx.x / 30, tp = blockIdx.x % 30;
    int c = threadIdx.x; // 128
    float s = 0.f;
    for (int i = 0; i < 64; ++i) s += P1[((size_t)(b * 64 + i) * 30 + tp) * 128 + c];
    GP[((size_t)b * 30 + tp) * 128 + c] = s * (1.f / 64.f);
}

// ---------------- conv3 (128->128, k=3, VALID) + BN3 stats ----------------
__global__ void k_conv3(const float* __restrict__ GP, const float* __restrict__ W3,
                        float* __restrict__ C3, float* S) {
    int b = blockIdx.x / 28, t = blockIdx.x % 28;
    int c = threadIdx.x; // 128
    __shared__ float gs[3 * 128];
    for (int i = c; i < 384; i += 128) gs[i] = GP[((size_t)b * 30 + t) * 128 + i];
    __syncthreads();
    float acc = 0.f;
    for (int i = 0; i < 384; ++i) acc += gs[i] * W3[i * 128 + c];
    C3[((size_t)b * 28 + t) * 128 + c] = acc;
    atomicAdd(&S[384 + c], acc);
    atomicAdd(&S[512 + c], acc * acc);
}

// ---------------- BN3 apply + avgpool4 + ReLU ----------------
__global__ void k_bn3pool(const float* __restrict__ C3, const float* __restrict__ S,
                          const float* __restrict__ g3, const float* __restrict__ b3,
                          float* __restrict__ P2) {
    int b = blockIdx.x;  // 8
    int c = threadIdx.x; // 128
    const float inv = 1.f / (float)(NG * 28);
    float mean = S[384 + c] * inv;
    float var  = S[512 + c] * inv - mean * mean;
    float sc = g3[c] * rsqrtf(var + EPS);
    float sh = b3[c] - mean * sc;
    for (int tp = 0; tp < 7; ++tp) {
        float s = 0.f;
        #pragma unroll
        for (int i = 0; i < 4; ++i) s += C3[((size_t)b * 28 + tp * 4 + i) * 128 + c];
        P2[((size_t)b * 7 + tp) * 128 + c] = fmaxf(s * 0.25f * sc + sh, 0.f);
    }
}

// ---------------- final linear + log_softmax ----------------
__global__ void k_final(const float* __restrict__ P2, const float* __restrict__ Wd,
                        const float* __restrict__ bd, float* __restrict__ out) {
    int tid = threadIdx.x; // 32
    int b = tid >> 2, j = tid & 3;
    float acc = bd[j];
    for (int i = 0; i < 896; ++i) acc += P2[b * 896 + i] * Wd[i * 4 + j];
    float m = acc;
    m = fmaxf(m, __shfl_xor(m, 1, 4));
    m = fmaxf(m, __shfl_xor(m, 2, 4));
    float e = expf(acc - m);
    float s = e;
    s += __shfl_xor(s, 1, 4);
    s += __shfl_xor(s, 2, 4);
    out[tid] = acc - m - logf(s);
}

extern "C" void kernel_launch(void* const* d_in, const int* in_sizes, int n_in,
                              void* d_out, int out_size, void* d_ws, size_t ws_size,
                              hipStream_t stream) {
    const float* x   = (const float*)d_in[0];
    const float* pos = (const float*)d_in[1];
    const int*   ei  = (const int*)d_in[2];
    const float* W1  = (const float*)d_in[4];
    const float* g1  = (const float*)d_in[5];
    const float* b1  = (const float*)d_in[6];
    const float* Wp1 = (const float*)d_in[7];
    const float* bp1 = (const float*)d_in[8];
    const float* Wp2 = (const float*)d_in[9];
    const float* bp2 = (const float*)d_in[10];
    const float* Wg1 = (const float*)d_in[11];
    const float* bg1 = (const float*)d_in[12];
    const float* Wg2 = (const float*)d_in[13];
    const float* bg2 = (const float*)d_in[14];
    const float* W2  = (const float*)d_in[15];
    const float* g2  = (const float*)d_in[16];
    const float* b2  = (const float*)d_in[17];
    const float* W3  = (const float*)d_in[18];
    const float* g3  = (const float*)d_in[19];
    const float* b3  = (const float*)d_in[20];
    const float* Wd  = (const float*)d_in[21];
    const float* bd  = (const float*)d_in[22];
    float* out = (float*)d_out;

    float* ws = (float*)d_ws;
    float* C    = ws;                  //  4,194,304 f : conv1 out (f32)
    float* OUT  = C + 4194304;         //  7,995,392 f : conv2 out (f32)
    float* PE   = OUT + 7995392;       //     32,768 f
    float* P1   = PE + 32768;          //  1,966,080 f
    float* GPb  = P1 + 1966080;        //     30,720 f
    float* C3   = GPb + 30720;         //     28,672 f
    float* P2   = C3 + 28672;          //      7,168 f
    float* S    = P2 + 7168;           //        640 f : BN stats
    float* DINV = S + 640;             //        512 f
    ushort_t* H0b  = (ushort_t*)(DINV + 512); //  4,194,304 us : bn1 out bf16
    ushort_t* Ybuf = H0b + 4194304;           // 16,777,216 us : gemm out bf16
    ushort_t* Bbuf = Ybuf + 16777216;         // 16,777,216 us : agg out bf16
    ushort_t* Wg1T = Bbuf + 16777216;         //     16,384 us
    ushort_t* Wg2T = Wg1T + 16384;            //     65,536 us
    ushort_t* WT2  = Wg2T + 65536;            //    229,376 us
    int* DEG = (int*)(WT2 + 229376);   // 512
    int* RS  = DEG + 512;              // 513
    int* CUR = RS + 513;               // 512
    int* CSR = CUR + 512;              // 4096
    const int* srcv = ei;
    const int* dstv = ei + E_EDGES;

    hipLaunchKernelGGL(k_zero,  dim3(1),   dim3(1024), 0, stream, S, DEG, CUR);
    hipLaunchKernelGGL(k_count, dim3(16),  dim3(256),  0, stream, dstv, DEG);
    hipLaunchKernelGGL(k_scan,  dim3(1),   dim3(512),  0, stream, DEG, RS, DINV);
    hipLaunchKernelGGL(k_fill,  dim3(16),  dim3(256),  0, stream, srcv, dstv, RS, CUR, CSR);
    hipLaunchKernelGGL(k_cvtw,  dim3(64),  dim3(256),  0, stream, Wg1, Wg1T, 64, 256);
    hipLaunchKernelGGL(k_cvtw,  dim3(256), dim3(256),  0, stream, Wg2, Wg2T, 256, 256);
    hipLaunchKernelGGL(k_cvtw,  dim3(896), dim3(256),  0, stream, W2, WT2, 1792, 128);
    hipLaunchKernelGGL(k_pe,    dim3(512), dim3(64),   0, stream, pos, Wp1, bp1, Wp2, bp2, PE);
    hipLaunchKernelGGL(k_conv1, dim3(512), dim3(256),  0, stream, x, W1, C, S);
    hipLaunchKernelGGL(k_bn1,   dim3(512), dim3(256),  0, stream, C, S, g1, b1, PE, H0b);
    hipLaunchKernelGGL(k_gemm_mfma<64>,  dim3(512), dim3(512), 0, stream, H0b, Wg1T, Ybuf);
    hipLaunchKernelGGL(k_agg,   dim3(512, 4), dim3(256), 0, stream, Ybuf, Bbuf, bg1, DINV, RS, CSR);
    hipLaunchKernelGGL(k_gemm_mfma<256>, dim3(512), dim3(512), 0, stream, Bbuf, Wg2T, Ybuf);
    hipLaunchKernelGGL(k_agg,   dim3(512, 4), dim3(256), 0, stream, Ybuf, Bbuf, bg2, DINV, RS, CSR);
    hipLaunchKernelGGL(k_conv2_mfma, dim3(2, 512), dim3(256), 0, stream, Bbuf, WT2, OUT);
    hipLaunchKernelGGL(k_stats2, dim3(256), dim3(128), 0, stream, OUT, S);
    hipLaunchKernelGGL(k_bn2pool, dim3(512), dim3(128), 0, stream, OUT, S, g2, b2, P1);
    hipLaunchKernelGGL(k_gmean, dim3(240), dim3(128), 0, stream, P1, GPb);
    hipLaunchKernelGGL(k_conv3, dim3(224), dim3(128), 0, stream, GPb, W3, C3, S);
    hipLaunchKernelGGL(k_bn3pool, dim3(8), dim3(128), 0, stream, C3, S, g3, b3, P2);
    hipLaunchKernelGGL(k_final, dim3(1),   dim3(32),  0, stream, P2, Wd, bd, out);
}

// Round 4
// 391.660 us; speedup vs baseline: 3.0778x; 1.8083x over previous
//
#include <hip/hip_runtime.h>
#include <math.h>

#define N_NODES 512
#define T 128
#define E_EDGES 4096
#define C0 64
#define EMBED 256
#define C1 128
#define C2 128
#define NG 8
#define EPS 1e-5f

typedef unsigned short ushort_t;
typedef short bf16x8 __attribute__((ext_vector_type(8)));
typedef float f32x4 __attribute__((ext_vector_type(4)));

__device__ __forceinline__ ushort_t f2bf(float f) {
    union { float f; unsigned int u; } v; v.f = f;
    unsigned int r = v.u + 0x7fffu + ((v.u >> 16) & 1u);
    return (ushort_t)(r >> 16);
}
__device__ __forceinline__ float bf2f(ushort_t h) {
    union { unsigned int u; float f; } v; v.u = ((unsigned int)h) << 16;
    return v.f;
}

// ---------------- setup ----------------

__global__ void k_zero(float* S, int* DEG, float* AH) {
    int i = blockIdx.x * 1024 + threadIdx.x;
    if (i < 32768) AH[i] = 0.f;
    if (i < 640) S[i] = 0.f;
    if (i < 512) DEG[i] = 0;
}

__global__ void k_count(const int* __restrict__ dst, int* DEG) {
    int e = blockIdx.x * 256 + threadIdx.x;
    if (e < E_EDGES) atomicAdd(&DEG[dst[e]], 1);
}

__global__ void k_dinv(const int* __restrict__ DEG, float* DINV) {
    int n = threadIdx.x;
    DINV[n] = rsqrtf((float)DEG[n] + 1.0f);
}

__global__ void k_abuild(const int* __restrict__ src, const int* __restrict__ dst,
                         const float* __restrict__ DINV, float* AH) {
    int e = blockIdx.x * 256 + threadIdx.x;
    if (e < E_EDGES) {
        int d = dst[e], s = src[e];
        atomicAdd(&AH[(d >> 6) * 4096 + (d & 63) * 64 + (s & 63)], DINV[d] * DINV[s]);
    }
}

__global__ void k_adiag(const float* __restrict__ DINV, float* AH) {
    int n = threadIdx.x; // 512
    AH[(n >> 6) * 4096 + (n & 63) * 65] += DINV[n] * DINV[n];
}

__global__ void k_cvta(const float* __restrict__ AH, ushort_t* __restrict__ AHb) {
    int i = blockIdx.x * 256 + threadIdx.x;
    if (i < 32768) AHb[i] = f2bf(AH[i]);
}

// weight convert+transpose: in f32 (K x N) -> out bf16 (N x K)
__global__ void k_cvtw(const float* __restrict__ in, ushort_t* __restrict__ out, int K, int N) {
    int i = blockIdx.x * 256 + threadIdx.x;
    if (i < K * N) {
        int n = i / K, k = i % K;
        out[i] = f2bf(in[k * N + n]);
    }
}

// ---------------- position encoder MLP ----------------
__global__ void k_pe(const float* __restrict__ pos, const float* __restrict__ Wp1,
                     const float* __restrict__ bp1, const float* __restrict__ Wp2,
                     const float* __restrict__ bp2, float* __restrict__ PE) {
    int n = blockIdx.x;
    int c = threadIdx.x; // 64
    __shared__ float hid[64];
    float p0 = pos[n * 3], p1 = pos[n * 3 + 1], p2 = pos[n * 3 + 2];
    float h = p0 * Wp1[c] + p1 * Wp1[64 + c] + p2 * Wp1[128 + c] + bp1[c];
    hid[c] = fmaxf(h, 0.f);
    __syncthreads();
    float acc = bp2[c];
    #pragma unroll
    for (int j = 0; j < 64; ++j) acc += hid[j] * Wp2[j * 64 + c];
    PE[n * 64 + c] = acc;
}

// ---------------- conv1 (1->64, k=7, SAME) + BN stats ----------------
__global__ void k_conv1(const float* __restrict__ x, const float* __restrict__ W1,
                        float* __restrict__ C, float* S) {
    int n = blockIdx.x;
    int tid = threadIdx.x; // 256
    int c = tid & 63, tg = tid >> 6;
    __shared__ float xs[134];
    __shared__ float ws[448];
    __shared__ float red[256];
    for (int i = tid; i < 448; i += 256) ws[i] = W1[i];
    for (int i = tid; i < 134; i += 256) {
        int t = i - 3;
        xs[i] = (t >= 0 && t < T) ? x[n * T + t] : 0.f;
    }
    __syncthreads();
    float s1 = 0.f, s2 = 0.f;
    for (int t = tg; t < T; t += 4) {
        float acc = 0.f;
        #pragma unroll
        for (int k = 0; k < 7; ++k) acc += xs[t + k] * ws[k * 64 + c];
        C[(n * T + t) * 64 + c] = acc;
        s1 += acc; s2 += acc * acc;
    }
    red[tid] = s1; __syncthreads();
    if (tg == 0) { float v = red[c] + red[64 + c] + red[128 + c] + red[192 + c]; atomicAdd(&S[c], v); }
    __syncthreads();
    red[tid] = s2; __syncthreads();
    if (tg == 0) { float v = red[c] + red[64 + c] + red[128 + c] + red[192 + c]; atomicAdd(&S[64 + c], v); }
}

// ---------------- BN1 apply + ReLU + add pe -> bf16 H0 ----------------
__global__ void k_bn1(const float* __restrict__ C, const float* __restrict__ S,
                      const float* __restrict__ g1, const float* __restrict__ b1,
                      const float* __restrict__ PE, ushort_t* __restrict__ H0b) {
    int n = blockIdx.x, tid = threadIdx.x;
    int c = tid & 63, tg = tid >> 6;
    const float inv = 1.f / (float)(N_NODES * T);
    float mean = S[c] * inv;
    float var  = S[64 + c] * inv - mean * mean;
    float sc = g1[c] * rsqrtf(var + EPS);
    float sh = b1[c] - mean * sc;
    float pe = PE[n * 64 + c];
    for (int t = tg; t < T; t += 4) {
        int idx = (n * T + t) * 64 + c;
        H0b[idx] = f2bf(fmaxf(C[idx] * sc + sh, 0.f) + pe);
    }
}

// ---------------- MFMA GEMM: X (65536 x K) bf16 @ WT (256 x K) bf16 -> Y (65536 x 256) bf16 ----------------
template <int K>
__global__ __launch_bounds__(512) void k_gemm_mfma(const ushort_t* __restrict__ X,
                                                   const ushort_t* __restrict__ WT,
                                                   ushort_t* __restrict__ Y) {
    __shared__ ushort_t Xs[128 * 40];
    __shared__ ushort_t Ws[256 * 40];
    int tid = threadIdx.x;
    int l = tid & 63, wid = tid >> 6;
    int wr = wid >> 2, wc = wid & 3;
    int row0 = blockIdx.x * 128;
    int lrow = l & 15, lko = (l >> 4) * 8;

    f32x4 acc[4][4];
    #pragma unroll
    for (int i = 0; i < 4; ++i)
        #pragma unroll
        for (int j = 0; j < 4; ++j) acc[i][j] = (f32x4){0.f, 0.f, 0.f, 0.f};

    int srow = tid >> 2, schunk = (tid & 3) * 8;
    for (int kk = 0; kk < K; kk += 32) {
        __syncthreads();
        *reinterpret_cast<bf16x8*>(&Xs[srow * 40 + schunk]) =
            *reinterpret_cast<const bf16x8*>(&X[(size_t)(row0 + srow) * K + kk + schunk]);
        #pragma unroll
        for (int rep = 0; rep < 2; ++rep) {
            int wrow = rep * 128 + srow;
            *reinterpret_cast<bf16x8*>(&Ws[wrow * 40 + schunk]) =
                *reinterpret_cast<const bf16x8*>(&WT[(size_t)wrow * K + kk + schunk]);
        }
        __syncthreads();
        bf16x8 a[4], b[4];
        #pragma unroll
        for (int mi = 0; mi < 4; ++mi)
            a[mi] = *reinterpret_cast<const bf16x8*>(&Xs[(wr * 64 + mi * 16 + lrow) * 40 + lko]);
        #pragma unroll
        for (int ni = 0; ni < 4; ++ni)
            b[ni] = *reinterpret_cast<const bf16x8*>(&Ws[(wc * 64 + ni * 16 + lrow) * 40 + lko]);
        #pragma unroll
        for (int mi = 0; mi < 4; ++mi)
            #pragma unroll
            for (int ni = 0; ni < 4; ++ni)
                acc[mi][ni] = __builtin_amdgcn_mfma_f32_16x16x32_bf16(a[mi], b[ni], acc[mi][ni], 0, 0, 0);
    }
    #pragma unroll
    for (int mi = 0; mi < 4; ++mi) {
        #pragma unroll
        for (int ni = 0; ni < 4; ++ni) {
            int col = wc * 64 + ni * 16 + lrow;
            #pragma unroll
            for (int r = 0; r < 4; ++r) {
                size_t row = row0 + wr * 64 + mi * 16 + (l >> 4) * 4 + r;
                Y[row * 256 + col] = f2bf(acc[mi][ni][r]);
            }
        }
    }
}

// ---------------- GCN aggregation as dense per-graph 64x64 MFMA GEMM ----------------
// Y[g*64+m][t*256+c] = relu( sum_k AH[g][m][k] * X[g*64+k][t*256+c] + bias[c] )
__global__ __launch_bounds__(512) void k_agg_mfma(const ushort_t* __restrict__ X,
                                                  const ushort_t* __restrict__ AHb,
                                                  const float* __restrict__ bias,
                                                  ushort_t* __restrict__ Y) {
    __shared__ ushort_t A_lds[64 * 72];
    __shared__ ushort_t Xt[256 * 72];
    int g = blockIdx.x >> 7;
    int t = blockIdx.x & 127;
    int tid = threadIdx.x;
    int l = tid & 63, w = tid >> 6;
    int lrow = l & 15, lko = (l >> 4) * 8;

    // stage A (64x64, row-major k-contig)
    {
        int row = tid >> 3, off = (tid & 7) * 8;
        *reinterpret_cast<bf16x8*>(&A_lds[row * 72 + off]) =
            *reinterpret_cast<const bf16x8*>(&AHb[g * 4096 + row * 64 + off]);
    }
    // stage X transposed: Xt[c][node]
    #pragma unroll
    for (int it = 0; it < 4; ++it) {
        int lin = it * 512 + tid;
        int node = lin & 63, chunk = lin >> 6;
        bf16x8 v = *reinterpret_cast<const bf16x8*>(
            &X[((size_t)(g * 64 + node)) * 32768 + t * 256 + chunk * 8]);
        #pragma unroll
        for (int j = 0; j < 8; ++j) Xt[(chunk * 8 + j) * 72 + node] = v[j];
    }
    __syncthreads();

    f32x4 acc[4][2];
    #pragma unroll
    for (int i = 0; i < 4; ++i)
        #pragma unroll
        for (int j = 0; j < 2; ++j) acc[i][j] = (f32x4){0.f, 0.f, 0.f, 0.f};

    #pragma unroll
    for (int kc = 0; kc < 2; ++kc) {
        bf16x8 a[4], b[2];
        #pragma unroll
        for (int mi = 0; mi < 4; ++mi)
            a[mi] = *reinterpret_cast<const bf16x8*>(&A_lds[(mi * 16 + lrow) * 72 + kc * 32 + lko]);
        #pragma unroll
        for (int ni = 0; ni < 2; ++ni)
            b[ni] = *reinterpret_cast<const bf16x8*>(&Xt[(w * 32 + ni * 16 + lrow) * 72 + kc * 32 + lko]);
        #pragma unroll
        for (int mi = 0; mi < 4; ++mi)
            #pragma unroll
            for (int ni = 0; ni < 2; ++ni)
                acc[mi][ni] = __builtin_amdgcn_mfma_f32_16x16x32_bf16(b[ni], a[mi], acc[mi][ni], 0, 0, 0);
    }
    // NOTE: mfma(b, a, ...) computes D[col_of_b? ] -- see write below (we pass X^T as 'a' role swapped)
    // Actually we computed D = b*a: D[row=Xcol? ]. To keep the verified convention (same as k_gemm_mfma:
    // D[row of first operand rows][col = rows of second operand]), first operand rows = Xt rows = channel cols,
    // second operand rows = A rows = output nodes. So acc[mi][ni] holds [col=lane&15 -> A row (out node)],
    // [row -> Xt row (channel col)]. Write accordingly:
    #pragma unroll
    for (int mi = 0; mi < 4; ++mi) {
        #pragma unroll
        for (int ni = 0; ni < 2; ++ni) {
            int node = mi * 16 + lrow; // col index of D = rows of 2nd operand (A) = out node
            #pragma unroll
            for (int r = 0; r < 4; ++r) {
                int lc = w * 32 + ni * 16 + (l >> 4) * 4 + r; // row of D = rows of 1st operand (Xt) = channel
                float v = fmaxf(acc[mi][ni][r] + bias[lc], 0.f);
                Y[((size_t)(g * 64 + node)) * 32768 + t * 256 + lc] = f2bf(v);
            }
        }
    }
}

// ---------------- conv2 as implicit GEMM, both operands in LDS ----------------
// one block per node: M=128 (t rows), N=128 (out ch), K=1792 (tap*256+cin)
__global__ __launch_bounds__(512) void k_conv2_mfma(const ushort_t* __restrict__ H,
                                                    const ushort_t* __restrict__ WT2,
                                                    float* __restrict__ OUT) {
    __shared__ ushort_t Xs[128 * 40];
    __shared__ ushort_t Ws[128 * 40];
    int n = blockIdx.x;
    int tid = threadIdx.x;
    int l = tid & 63, wid = tid >> 6;
    int wr = wid >> 1, wc = wid & 1;
    int lrow = l & 15, lko = (l >> 4) * 8;

    f32x4 acc[2][4];
    #pragma unroll
    for (int i = 0; i < 2; ++i)
        #pragma unroll
        for (int j = 0; j < 4; ++j) acc[i][j] = (f32x4){0.f, 0.f, 0.f, 0.f};

    int srow = tid >> 2, soff = (tid & 3) * 8;
    for (int kk = 0; kk < 1792; kk += 32) {
        int tap = kk >> 8;
        int cin0 = kk & 255;
        __syncthreads();
        int hrow = srow + tap; if (hrow > 127) hrow = 127; // overflow rows feed discarded outputs only
        *reinterpret_cast<bf16x8*>(&Xs[srow * 40 + soff]) =
            *reinterpret_cast<const bf16x8*>(&H[((size_t)n * T + hrow) * 256 + cin0 + soff]);
        *reinterpret_cast<bf16x8*>(&Ws[srow * 40 + soff]) =
            *reinterpret_cast<const bf16x8*>(&WT2[(size_t)srow * 1792 + kk + soff]);
        __syncthreads();
        bf16x8 a[2], b[4];
        #pragma unroll
        for (int mi = 0; mi < 2; ++mi)
            a[mi] = *reinterpret_cast<const bf16x8*>(&Xs[(wr * 32 + mi * 16 + lrow) * 40 + lko]);
        #pragma unroll
        for (int ni = 0; ni < 4; ++ni)
            b[ni] = *reinterpret_cast<const bf16x8*>(&Ws[(wc * 64 + ni * 16 + lrow) * 40 + lko]);
        #pragma unroll
        for (int mi = 0; mi < 2; ++mi)
            #pragma unroll
            for (int ni = 0; ni < 4; ++ni)
                acc[mi][ni] = __builtin_amdgcn_mfma_f32_16x16x32_bf16(a[mi], b[ni], acc[mi][ni], 0, 0, 0);
    }
    #pragma unroll
    for (int mi = 0; mi < 2; ++mi) {
        #pragma unroll
        for (int ni = 0; ni < 4; ++ni) {
            int col = wc * 64 + ni * 16 + lrow;
            #pragma unroll
            for (int r = 0; r < 4; ++r) {
                int t = wr * 32 + mi * 16 + (l >> 4) * 4 + r;
                if (t < 122) OUT[((size_t)n * 122 + t) * 128 + col] = acc[mi][ni][r];
            }
        }
    }
}

// ---------------- BN2 stats reduction ----------------
__global__ void k_stats2(const float* __restrict__ OUT, float* S) {
    int c = threadIdx.x; // 128
    int b = blockIdx.x;  // 256
    const int R = N_NODES * 122;
    const int chunk = (R + 255) / 256;
    int r0 = b * chunk, r1 = min(R, r0 + chunk);
    float s1 = 0.f, s2 = 0.f;
    for (int r = r0; r < r1; ++r) {
        float v = OUT[(size_t)r * 128 + c];
        s1 += v; s2 += v * v;
    }
    atomicAdd(&S[128 + c], s1);
    atomicAdd(&S[256 + c], s2);
}

// ---------------- BN2 apply + avgpool4 + ReLU ----------------
__global__ void k_bn2pool(const float* __restrict__ OUT, const float* __restrict__ S,
                          const float* __restrict__ g2, const float* __restrict__ b2,
                          float* __restrict__ P1) {
    int n = blockIdx.x;
    int c = threadIdx.x; // 128
    const float inv = 1.f / (float)(N_NODES * 122);
    float mean = S[128 + c] * inv;
    float var  = S[256 + c] * inv - mean * mean;
    float sc = g2[c] * rsqrtf(var + EPS);
    float sh = b2[c] - mean * sc;
    for (int tp = 0; tp < 30; ++tp) {
        float s = 0.f;
        #pragma unroll
        for (int i = 0; i < 4; ++i) s += OUT[((size_t)n * 122 + tp * 4 + i) * 128 + c];
        P1[((size_t)n * 30 + tp) * 128 + c] = fmaxf(s * 0.25f * sc + sh, 0.f);
    }
}

// ---------------- global mean pool ----------------
__global__ void k_gmean(const float* __restrict__ P1, float* __restrict__ GP) {
    int b = blockIdx.x / 30, tp = blockIdx.x % 30;
    int c = threadIdx.x; // 128
    float s = 0.f;
    for (int i = 0; i < 64; ++i) s += P1[((size_t)(b * 64 + i) * 30 + tp) * 128 + c];
    GP[((size_t)b * 30 + tp) * 128 + c] = s * (1.f / 64.f);
}

// ---------------- conv3 (128->128, k=3, VALID) + BN3 stats ----------------
__global__ void k_conv3(const float* __restrict__ GP, const float* __restrict__ W3,
                        float* __restrict__ C3, float* S) {
    int b = blockIdx.x / 28, t = blockIdx.x % 28;
    int c = threadIdx.x; // 128
    __shared__ float gs[3 * 128];
    for (int i = c; i < 384; i += 128) gs[i] = GP[((size_t)b * 30 + t) * 128 + i];
    __syncthreads();
    float acc = 0.f;
    for (int i = 0; i < 384; ++i) acc += gs[i] * W3[i * 128 + c];
    C3[((size_t)b * 28 + t) * 128 + c] = acc;
    atomicAdd(&S[384 + c], acc);
    atomicAdd(&S[512 + c], acc * acc);
}

// ---------------- BN3 apply + avgpool4 + ReLU ----------------
__global__ void k_bn3pool(const float* __restrict__ C3, const float* __restrict__ S,
                          const float* __restrict__ g3, const float* __restrict__ b3,
                          float* __restrict__ P2) {
    int b = blockIdx.x;  // 8
    int c = threadIdx.x; // 128
    const float inv = 1.f / (float)(NG * 28);
    float mean = S[384 + c] * inv;
    float var  = S[512 + c] * inv - mean * mean;
    float sc = g3[c] * rsqrtf(var + EPS);
    float sh = b3[c] - mean * sc;
    for (int tp = 0; tp < 7; ++tp) {
        float s = 0.f;
        #pragma unroll
        for (int i = 0; i < 4; ++i) s += C3[((size_t)b * 28 + tp * 4 + i) * 128 + c];
        P2[((size_t)b * 7 + tp) * 128 + c] = fmaxf(s * 0.25f * sc + sh, 0.f);
    }
}

// ---------------- final linear + log_softmax ----------------
__global__ void k_final(const float* __restrict__ P2, const float* __restrict__ Wd,
                        const float* __restrict__ bd, float* __restrict__ out) {
    int tid = threadIdx.x; // 32
    int b = tid >> 2, j = tid & 3;
    float acc = bd[j];
    for (int i = 0; i < 896; ++i) acc += P2[b * 896 + i] * Wd[i * 4 + j];
    float m = acc;
    m = fmaxf(m, __shfl_xor(m, 1, 4));
    m = fmaxf(m, __shfl_xor(m, 2, 4));
    float e = expf(acc - m);
    float s = e;
    s += __shfl_xor(s, 1, 4);
    s += __shfl_xor(s, 2, 4);
    out[tid] = acc - m - logf(s);
}

extern "C" void kernel_launch(void* const* d_in, const int* in_sizes, int n_in,
                              void* d_out, int out_size, void* d_ws, size_t ws_size,
                              hipStream_t stream) {
    const float* x   = (const float*)d_in[0];
    const float* pos = (const float*)d_in[1];
    const int*   ei  = (const int*)d_in[2];
    const float* W1  = (const float*)d_in[4];
    const float* g1  = (const float*)d_in[5];
    const float* b1  = (const float*)d_in[6];
    const float* Wp1 = (const float*)d_in[7];
    const float* bp1 = (const float*)d_in[8];
    const float* Wp2 = (const float*)d_in[9];
    const float* bp2 = (const float*)d_in[10];
    const float* Wg1 = (const float*)d_in[11];
    const float* bg1 = (const float*)d_in[12];
    const float* Wg2 = (const float*)d_in[13];
    const float* bg2 = (const float*)d_in[14];
    const float* W2  = (const float*)d_in[15];
    const float* g2  = (const float*)d_in[16];
    const float* b2  = (const float*)d_in[17];
    const float* W3  = (const float*)d_in[18];
    const float* g3  = (const float*)d_in[19];
    const float* b3  = (const float*)d_in[20];
    const float* Wd  = (const float*)d_in[21];
    const float* bd  = (const float*)d_in[22];
    float* out = (float*)d_out;

    float* ws = (float*)d_ws;
    float* C    = ws;                  //  4,194,304 f
    float* OUT  = C + 4194304;         //  7,995,392 f
    float* PE   = OUT + 7995392;       //     32,768 f
    float* P1   = PE + 32768;          //  1,966,080 f
    float* GPb  = P1 + 1966080;        //     30,720 f
    float* C3   = GPb + 30720;         //     28,672 f
    float* P2   = C3 + 28672;          //      7,168 f
    float* S    = P2 + 7168;           //        640 f
    float* DINV = S + 640;             //        512 f
    float* AH   = DINV + 512;          //     32,768 f
    ushort_t* H0b  = (ushort_t*)(AH + 32768); //  4,194,304 us
    ushort_t* Ybuf = H0b + 4194304;           // 16,777,216 us
    ushort_t* Bbuf = Ybuf + 16777216;         // 16,777,216 us
    ushort_t* Wg1T = Bbuf + 16777216;         //     16,384 us
    ushort_t* Wg2T = Wg1T + 16384;            //     65,536 us
    ushort_t* WT2  = Wg2T + 65536;            //    229,376 us
    ushort_t* AHb  = WT2 + 229376;            //     32,768 us
    int* DEG = (int*)(AHb + 32768);           //        512 i
    const int* srcv = ei;
    const int* dstv = ei + E_EDGES;

    hipLaunchKernelGGL(k_zero,   dim3(32),  dim3(1024), 0, stream, S, DEG, AH);
    hipLaunchKernelGGL(k_count,  dim3(16),  dim3(256),  0, stream, dstv, DEG);
    hipLaunchKernelGGL(k_dinv,   dim3(1),   dim3(512),  0, stream, DEG, DINV);
    hipLaunchKernelGGL(k_abuild, dim3(16),  dim3(256),  0, stream, srcv, dstv, DINV, AH);
    hipLaunchKernelGGL(k_adiag,  dim3(1),   dim3(512),  0, stream, DINV, AH);
    hipLaunchKernelGGL(k_cvta,   dim3(128), dim3(256),  0, stream, AH, AHb);
    hipLaunchKernelGGL(k_cvtw,   dim3(64),  dim3(256),  0, stream, Wg1, Wg1T, 64, 256);
    hipLaunchKernelGGL(k_cvtw,   dim3(256), dim3(256),  0, stream, Wg2, Wg2T, 256, 256);
    hipLaunchKernelGGL(k_cvtw,   dim3(896), dim3(256),  0, stream, W2, WT2, 1792, 128);
    hipLaunchKernelGGL(k_pe,     dim3(512), dim3(64),   0, stream, pos, Wp1, bp1, Wp2, bp2, PE);
    hipLaunchKernelGGL(k_conv1,  dim3(512), dim3(256),  0, stream, x, W1, C, S);
    hipLaunchKernelGGL(k_bn1,    dim3(512), dim3(256),  0, stream, C, S, g1, b1, PE, H0b);
    hipLaunchKernelGGL(k_gemm_mfma<64>,  dim3(512), dim3(512), 0, stream, H0b, Wg1T, Ybuf);
    hipLaunchKernelGGL(k_agg_mfma, dim3(1024), dim3(512), 0, stream, Ybuf, AHb, bg1, Bbuf);
    hipLaunchKernelGGL(k_gemm_mfma<256>, dim3(512), dim3(512), 0, stream, Bbuf, Wg2T, Ybuf);
    hipLaunchKernelGGL(k_agg_mfma, dim3(1024), dim3(512), 0, stream, Ybuf, AHb, bg2, Bbuf);
    hipLaunchKernelGGL(k_conv2_mfma, dim3(512), dim3(512), 0, stream, Bbuf, WT2, OUT);
    hipLaunchKernelGGL(k_stats2, dim3(256), dim3(128), 0, stream, OUT, S);
    hipLaunchKernelGGL(k_bn2pool, dim3(512), dim3(128), 0, stream, OUT, S, g2, b2, P1);
    hipLaunchKernelGGL(k_gmean,  dim3(240), dim3(128), 0, stream, P1, GPb);
    hipLaunchKernelGGL(k_conv3,  dim3(224), dim3(128), 0, stream, GPb, W3, C3, S);
    hipLaunchKernelGGL(k_bn3pool, dim3(8),  dim3(128), 0, stream, C3, S, g3, b3, P2);
    hipLaunchKernelGGL(k_final,  dim3(1),   dim3(32),  0, stream, P2, Wd, bd, out);
}

// Round 6
// 345.642 us; speedup vs baseline: 3.4875x; 1.1331x over previous
//
#include <hip/hip_runtime.h>
#include <math.h>

#define N_NODES 512
#define T 128
#define E_EDGES 4096
#define C0 64
#define EMBED 256
#define C1 128
#define C2 128
#define NG 8
#define EPS 1e-5f

typedef unsigned short ushort_t;
typedef short bf16x8 __attribute__((ext_vector_type(8)));
typedef float f32x4 __attribute__((ext_vector_type(4)));

__device__ __forceinline__ ushort_t f2bf(float f) {
    union { float f; unsigned int u; } v; v.f = f;
    unsigned int r = v.u + 0x7fffu + ((v.u >> 16) & 1u);
    return (ushort_t)(r >> 16);
}
__device__ __forceinline__ float bf2f(ushort_t h) {
    union { unsigned int u; float f; } v; v.u = ((unsigned int)h) << 16;
    return v.f;
}

// ---------------- setup ----------------

__global__ void k_zero(float* S, int* DEG, float* AH, float* GP) {
    int i = blockIdx.x * 1024 + threadIdx.x;
    if (i < 640) S[i] = 0.f;
    if (i < 512) DEG[i] = 0;
    if (i < 32768) AH[i] = 0.f;
    if (i < 30720) GP[i] = 0.f;
}

__global__ void k_count(const int* __restrict__ dst, int* DEG) {
    int e = blockIdx.x * 256 + threadIdx.x;
    if (e < E_EDGES) atomicAdd(&DEG[dst[e]], 1);
}

__global__ void k_dinv(const int* __restrict__ DEG, float* DINV) {
    int n = threadIdx.x;
    DINV[n] = rsqrtf((float)DEG[n] + 1.0f);
}

__global__ void k_abuild(const int* __restrict__ src, const int* __restrict__ dst,
                         const float* __restrict__ DINV, float* AH) {
    int e = blockIdx.x * 256 + threadIdx.x;
    if (e < E_EDGES) {
        int d = dst[e], s = src[e];
        atomicAdd(&AH[(d >> 6) * 4096 + (d & 63) * 64 + (s & 63)], DINV[d] * DINV[s]);
    }
}

__global__ void k_adiag(const float* __restrict__ DINV, float* AH) {
    int n = threadIdx.x; // 512
    AH[(n >> 6) * 4096 + (n & 63) * 65] += DINV[n] * DINV[n];
}

__global__ void k_cvta(const float* __restrict__ AH, ushort_t* __restrict__ AHb) {
    int i = blockIdx.x * 256 + threadIdx.x;
    if (i < 32768) AHb[i] = f2bf(AH[i]);
}

// weight convert+transpose: in f32 (K x N) -> out bf16 (N x K)
__global__ void k_cvtw(const float* __restrict__ in, ushort_t* __restrict__ out, int K, int N) {
    int i = blockIdx.x * 256 + threadIdx.x;
    if (i < K * N) {
        int n = i / K, k = i % K;
        out[i] = f2bf(in[k * N + n]);
    }
}

// ---------------- position encoder MLP ----------------
__global__ void k_pe(const float* __restrict__ pos, const float* __restrict__ Wp1,
                     const float* __restrict__ bp1, const float* __restrict__ Wp2,
                     const float* __restrict__ bp2, float* __restrict__ PE) {
    int n = blockIdx.x;
    int c = threadIdx.x; // 64
    __shared__ float hid[64];
    float p0 = pos[n * 3], p1 = pos[n * 3 + 1], p2 = pos[n * 3 + 2];
    float h = p0 * Wp1[c] + p1 * Wp1[64 + c] + p2 * Wp1[128 + c] + bp1[c];
    hid[c] = fmaxf(h, 0.f);
    __syncthreads();
    float acc = bp2[c];
    #pragma unroll
    for (int j = 0; j < 64; ++j) acc += hid[j] * Wp2[j * 64 + c];
    PE[n * 64 + c] = acc;
}

// ---------------- conv1 (1->64, k=7, SAME) + BN stats ----------------
__global__ void k_conv1(const float* __restrict__ x, const float* __restrict__ W1,
                        float* __restrict__ C, float* S) {
    int n = blockIdx.x;
    int tid = threadIdx.x; // 256
    int c = tid & 63, tg = tid >> 6;
    __shared__ float xs[134];
    __shared__ float ws[448];
    __shared__ float red[256];
    for (int i = tid; i < 448; i += 256) ws[i] = W1[i];
    for (int i = tid; i < 134; i += 256) {
        int t = i - 3;
        xs[i] = (t >= 0 && t < T) ? x[n * T + t] : 0.f;
    }
    __syncthreads();
    float s1 = 0.f, s2 = 0.f;
    for (int t = tg; t < T; t += 4) {
        float acc = 0.f;
        #pragma unroll
        for (int k = 0; k < 7; ++k) acc += xs[t + k] * ws[k * 64 + c];
        C[(n * T + t) * 64 + c] = acc;
        s1 += acc; s2 += acc * acc;
    }
    red[tid] = s1; __syncthreads();
    if (tg == 0) { float v = red[c] + red[64 + c] + red[128 + c] + red[192 + c]; atomicAdd(&S[c], v); }
    __syncthreads();
    red[tid] = s2; __syncthreads();
    if (tg == 0) { float v = red[c] + red[64 + c] + red[128 + c] + red[192 + c]; atomicAdd(&S[64 + c], v); }
}

// ---------------- BN1 apply + ReLU + add pe -> bf16 H0 ----------------
__global__ void k_bn1(const float* __restrict__ C, const float* __restrict__ S,
                      const float* __restrict__ g1, const float* __restrict__ b1,
                      const float* __restrict__ PE, ushort_t* __restrict__ H0b) {
    int n = blockIdx.x, tid = threadIdx.x;
    int c = tid & 63, tg = tid >> 6;
    const float inv = 1.f / (float)(N_NODES * T);
    float mean = S[c] * inv;
    float var  = S[64 + c] * inv - mean * mean;
    float sc = g1[c] * rsqrtf(var + EPS);
    float sh = b1[c] - mean * sc;
    float pe = PE[n * 64 + c];
    for (int t = tg; t < T; t += 4) {
        int idx = (n * T + t) * 64 + c;
        H0b[idx] = f2bf(fmaxf(C[idx] * sc + sh, 0.f) + pe);
    }
}

// ---------------- MFMA GEMM: X (65536 x K) bf16 @ WT (256 x K) bf16 -> Y (65536 x 256) bf16 ----------------
template <int K>
__global__ __launch_bounds__(512) void k_gemm_mfma(const ushort_t* __restrict__ X,
                                                   const ushort_t* __restrict__ WT,
                                                   ushort_t* __restrict__ Y) {
    __shared__ ushort_t Xs[128 * 40];
    __shared__ ushort_t Ws[256 * 40];
    int tid = threadIdx.x;
    int l = tid & 63, wid = tid >> 6;
    int wr = wid >> 2, wc = wid & 3;
    int row0 = blockIdx.x * 128;
    int lrow = l & 15, lko = (l >> 4) * 8;

    f32x4 acc[4][4];
    #pragma unroll
    for (int i = 0; i < 4; ++i)
        #pragma unroll
        for (int j = 0; j < 4; ++j) acc[i][j] = (f32x4){0.f, 0.f, 0.f, 0.f};

    int srow = tid >> 2, schunk = (tid & 3) * 8;
    for (int kk = 0; kk < K; kk += 32) {
        __syncthreads();
        *reinterpret_cast<bf16x8*>(&Xs[srow * 40 + schunk]) =
            *reinterpret_cast<const bf16x8*>(&X[(size_t)(row0 + srow) * K + kk + schunk]);
        #pragma unroll
        for (int rep = 0; rep < 2; ++rep) {
            int wrow = rep * 128 + srow;
            *reinterpret_cast<bf16x8*>(&Ws[wrow * 40 + schunk]) =
                *reinterpret_cast<const bf16x8*>(&WT[(size_t)wrow * K + kk + schunk]);
        }
        __syncthreads();
        bf16x8 a[4], b[4];
        #pragma unroll
        for (int mi = 0; mi < 4; ++mi)
            a[mi] = *reinterpret_cast<const bf16x8*>(&Xs[(wr * 64 + mi * 16 + lrow) * 40 + lko]);
        #pragma unroll
        for (int ni = 0; ni < 4; ++ni)
            b[ni] = *reinterpret_cast<const bf16x8*>(&Ws[(wc * 64 + ni * 16 + lrow) * 40 + lko]);
        #pragma unroll
        for (int mi = 0; mi < 4; ++mi)
            #pragma unroll
            for (int ni = 0; ni < 4; ++ni)
                acc[mi][ni] = __builtin_amdgcn_mfma_f32_16x16x32_bf16(a[mi], b[ni], acc[mi][ni], 0, 0, 0);
    }
    #pragma unroll
    for (int mi = 0; mi < 4; ++mi) {
        #pragma unroll
        for (int ni = 0; ni < 4; ++ni) {
            int col = wc * 64 + ni * 16 + lrow;
            #pragma unroll
            for (int r = 0; r < 4; ++r) {
                size_t row = row0 + wr * 64 + mi * 16 + (l >> 4) * 4 + r;
                Y[row * 256 + col] = f2bf(acc[mi][ni][r]);
            }
        }
    }
}

// ---------------- GCN aggregation as dense per-graph 64x64 MFMA GEMM ----------------
__global__ __launch_bounds__(512) void k_agg_mfma(const ushort_t* __restrict__ X,
                                                  const ushort_t* __restrict__ AHb,
                                                  const float* __restrict__ bias,
                                                  ushort_t* __restrict__ Y) {
    __shared__ ushort_t A_lds[64 * 72];
    __shared__ ushort_t Xt[256 * 72];
    int g = blockIdx.x >> 7;
    int t = blockIdx.x & 127;
    int tid = threadIdx.x;
    int l = tid & 63, w = tid >> 6;
    int lrow = l & 15, lko = (l >> 4) * 8;

    {
        int row = tid >> 3, off = (tid & 7) * 8;
        *reinterpret_cast<bf16x8*>(&A_lds[row * 72 + off]) =
            *reinterpret_cast<const bf16x8*>(&AHb[g * 4096 + row * 64 + off]);
    }
    #pragma unroll
    for (int it = 0; it < 4; ++it) {
        int lin = it * 512 + tid;
        int node = lin & 63, chunk = lin >> 6;
        bf16x8 v = *reinterpret_cast<const bf16x8*>(
            &X[((size_t)(g * 64 + node)) * 32768 + t * 256 + chunk * 8]);
        #pragma unroll
        for (int j = 0; j < 8; ++j) Xt[(chunk * 8 + j) * 72 + node] = v[j];
    }
    __syncthreads();

    f32x4 acc[4][2];
    #pragma unroll
    for (int i = 0; i < 4; ++i)
        #pragma unroll
        for (int j = 0; j < 2; ++j) acc[i][j] = (f32x4){0.f, 0.f, 0.f, 0.f};

    #pragma unroll
    for (int kc = 0; kc < 2; ++kc) {
        bf16x8 a[4], b[2];
        #pragma unroll
        for (int mi = 0; mi < 4; ++mi)
            a[mi] = *reinterpret_cast<const bf16x8*>(&A_lds[(mi * 16 + lrow) * 72 + kc * 32 + lko]);
        #pragma unroll
        for (int ni = 0; ni < 2; ++ni)
            b[ni] = *reinterpret_cast<const bf16x8*>(&Xt[(w * 32 + ni * 16 + lrow) * 72 + kc * 32 + lko]);
        #pragma unroll
        for (int mi = 0; mi < 4; ++mi)
            #pragma unroll
            for (int ni = 0; ni < 2; ++ni)
                acc[mi][ni] = __builtin_amdgcn_mfma_f32_16x16x32_bf16(b[ni], a[mi], acc[mi][ni], 0, 0, 0);
    }
    #pragma unroll
    for (int mi = 0; mi < 4; ++mi) {
        #pragma unroll
        for (int ni = 0; ni < 2; ++ni) {
            int node = mi * 16 + lrow;
            #pragma unroll
            for (int r = 0; r < 4; ++r) {
                int lc = w * 32 + ni * 16 + (l >> 4) * 4 + r;
                float v = fmaxf(acc[mi][ni][r] + bias[lc], 0.f);
                Y[((size_t)(g * 64 + node)) * 32768 + t * 256 + lc] = f2bf(v);
            }
        }
    }
}

// ---------------- conv2 as implicit GEMM + fused BN2 stats ----------------
__global__ __launch_bounds__(512) void k_conv2_mfma(const ushort_t* __restrict__ H,
                                                    const ushort_t* __restrict__ WT2,
                                                    float* __restrict__ OUT, float* S) {
    __shared__ ushort_t Xs[128 * 40];
    __shared__ ushort_t Ws[128 * 40];
    __shared__ float sS1[128];
    __shared__ float sS2[128];
    int n = blockIdx.x;
    int tid = threadIdx.x;
    int l = tid & 63, wid = tid >> 6;
    int wr = wid >> 1, wc = wid & 1;
    int lrow = l & 15, lko = (l >> 4) * 8;

    if (tid < 128) { sS1[tid] = 0.f; sS2[tid] = 0.f; }

    f32x4 acc[2][4];
    #pragma unroll
    for (int i = 0; i < 2; ++i)
        #pragma unroll
        for (int j = 0; j < 4; ++j) acc[i][j] = (f32x4){0.f, 0.f, 0.f, 0.f};

    int srow = tid >> 2, soff = (tid & 3) * 8;
    for (int kk = 0; kk < 1792; kk += 32) {
        int tap = kk >> 8;
        int cin0 = kk & 255;
        __syncthreads();
        int hrow = srow + tap; if (hrow > 127) hrow = 127;
        *reinterpret_cast<bf16x8*>(&Xs[srow * 40 + soff]) =
            *reinterpret_cast<const bf16x8*>(&H[((size_t)n * T + hrow) * 256 + cin0 + soff]);
        *reinterpret_cast<bf16x8*>(&Ws[srow * 40 + soff]) =
            *reinterpret_cast<const bf16x8*>(&WT2[(size_t)srow * 1792 + kk + soff]);
        __syncthreads();
        bf16x8 a[2], b[4];
        #pragma unroll
        for (int mi = 0; mi < 2; ++mi)
            a[mi] = *reinterpret_cast<const bf16x8*>(&Xs[(wr * 32 + mi * 16 + lrow) * 40 + lko]);
        #pragma unroll
        for (int ni = 0; ni < 4; ++ni)
            b[ni] = *reinterpret_cast<const bf16x8*>(&Ws[(wc * 64 + ni * 16 + lrow) * 40 + lko]);
        #pragma unroll
        for (int mi = 0; mi < 2; ++mi)
            #pragma unroll
            for (int ni = 0; ni < 4; ++ni)
                acc[mi][ni] = __builtin_amdgcn_mfma_f32_16x16x32_bf16(a[mi], b[ni], acc[mi][ni], 0, 0, 0);
    }
    // write + per-channel partial stats
    #pragma unroll
    for (int ni = 0; ni < 4; ++ni) {
        int col = wc * 64 + ni * 16 + lrow;
        float s1 = 0.f, s2 = 0.f;
        #pragma unroll
        for (int mi = 0; mi < 2; ++mi) {
            #pragma unroll
            for (int r = 0; r < 4; ++r) {
                int t = wr * 32 + mi * 16 + (l >> 4) * 4 + r;
                if (t < 122) {
                    float v = acc[mi][ni][r];
                    OUT[((size_t)n * 122 + t) * 128 + col] = v;
                    s1 += v; s2 += v * v;
                }
            }
        }
        atomicAdd(&sS1[col], s1);
        atomicAdd(&sS2[col], s2);
    }
    __syncthreads();
    if (tid < 128) {
        atomicAdd(&S[128 + tid], sS1[tid]);
        atomicAdd(&S[256 + tid], sS2[tid]);
    }
}

// ---------------- BN2 apply + avgpool4 + ReLU + graph-mean (fused) ----------------
__global__ void k_bn2gp(const float* __restrict__ OUT, const float* __restrict__ S,
                        const float* __restrict__ g2, const float* __restrict__ b2,
                        float* __restrict__ GP) {
    int n = blockIdx.x;
    int tp0 = blockIdx.y * 5;
    int c = threadIdx.x; // 128
    int b = n >> 6;
    const float inv = 1.f / (float)(N_NODES * 122);
    float mean = S[128 + c] * inv;
    float var  = S[256 + c] * inv - mean * mean;
    float sc = g2[c] * rsqrtf(var + EPS);
    float sh = b2[c] - mean * sc;
    for (int tp = tp0; tp < tp0 + 5; ++tp) {
        float s = 0.f;
        #pragma unroll
        for (int i = 0; i < 4; ++i) s += OUT[((size_t)n * 122 + tp * 4 + i) * 128 + c];
        float v = fmaxf(s * 0.25f * sc + sh, 0.f);
        atomicAdd(&GP[((size_t)b * 30 + tp) * 128 + c], v * (1.f / 64.f));
    }
}

// ---------------- conv3 (128->128, k=3, VALID) + BN3 stats ----------------
__global__ void k_conv3(const float* __restrict__ GP, const float* __restrict__ W3,
                        float* __restrict__ C3, float* S) {
    int b = blockIdx.x / 28, t = blockIdx.x % 28;
    int c = threadIdx.x; // 128
    __shared__ float gs[3 * 128];
    for (int i = c; i < 384; i += 128) gs[i] = GP[((size_t)b * 30 + t) * 128 + i];
    __syncthreads();
    float acc = 0.f;
    for (int i = 0; i < 384; ++i) acc += gs[i] * W3[i * 128 + c];
    C3[((size_t)b * 28 + t) * 128 + c] = acc;
    atomicAdd(&S[384 + c], acc);
    atomicAdd(&S[512 + c], acc * acc);
}

// ---------------- BN3 apply + avgpool4 + ReLU ----------------
__global__ void k_bn3pool(const float* __restrict__ C3, const float* __restrict__ S,
                          const float* __restrict__ g3, const float* __restrict__ b3,
                          float* __restrict__ P2) {
    int b = blockIdx.x;  // 8
    int c = threadIdx.x; // 128
    const float inv = 1.f / (float)(NG * 28);
    float mean = S[384 + c] * inv;
    float var  = S[512 + c] * inv - mean * mean;
    float sc = g3[c] * rsqrtf(var + EPS);
    float sh = b3[c] - mean * sc;
    for (int tp = 0; tp < 7; ++tp) {
        float s = 0.f;
        #pragma unroll
        for (int i = 0; i < 4; ++i) s += C3[((size_t)b * 28 + tp * 4 + i) * 128 + c];
        P2[((size_t)b * 7 + tp) * 128 + c] = fmaxf(s * 0.25f * sc + sh, 0.f);
    }
}

// ---------------- final linear + log_softmax ----------------
__global__ void k_final(const float* __restrict__ P2, const float* __restrict__ Wd,
                        const float* __restrict__ bd, float* __restrict__ out) {
    int tid = threadIdx.x; // 32
    int b = tid >> 2, j = tid & 3;
    float acc = bd[j];
    for (int i = 0; i < 896; ++i) acc += P2[b * 896 + i] * Wd[i * 4 + j];
    float m = acc;
    m = fmaxf(m, __shfl_xor(m, 1, 4));
    m = fmaxf(m, __shfl_xor(m, 2, 4));
    float e = expf(acc - m);
    float s = e;
    s += __shfl_xor(s, 1, 4);
    s += __shfl_xor(s, 2, 4);
    out[tid] = acc - m - logf(s);
}

extern "C" void kernel_launch(void* const* d_in, const int* in_sizes, int n_in,
                              void* d_out, int out_size, void* d_ws, size_t ws_size,
                              hipStream_t stream) {
    const float* x   = (const float*)d_in[0];
    const float* pos = (const float*)d_in[1];
    const int*   ei  = (const int*)d_in[2];
    const float* W1  = (const float*)d_in[4];
    const float* g1  = (const float*)d_in[5];
    const float* b1  = (const float*)d_in[6];
    const float* Wp1 = (const float*)d_in[7];
    const float* bp1 = (const float*)d_in[8];
    const float* Wp2 = (const float*)d_in[9];
    const float* bp2 = (const float*)d_in[10];
    const float* Wg1 = (const float*)d_in[11];
    const float* bg1 = (const float*)d_in[12];
    const float* Wg2 = (const float*)d_in[13];
    const float* bg2 = (const float*)d_in[14];
    const float* W2  = (const float*)d_in[15];
    const float* g2  = (const float*)d_in[16];
    const float* b2  = (const float*)d_in[17];
    const float* W3  = (const float*)d_in[18];
    const float* g3  = (const float*)d_in[19];
    const float* b3  = (const float*)d_in[20];
    const float* Wd  = (const float*)d_in[21];
    const float* bd  = (const float*)d_in[22];
    float* out = (float*)d_out;

    float* ws = (float*)d_ws;
    float* C    = ws;                  //  4,194,304 f
    float* OUT  = C + 4194304;         //  7,995,392 f
    float* PE   = OUT + 7995392;       //     32,768 f
    float* GPb  = PE + 32768;          //     30,720 f
    float* C3   = GPb + 30720;         //     28,672 f
    float* P2   = C3 + 28672;          //      7,168 f
    float* S    = P2 + 7168;           //        640 f
    float* DINV = S + 640;             //        512 f
    float* AH   = DINV + 512;          //     32,768 f
    ushort_t* H0b  = (ushort_t*)(AH + 32768); //  4,194,304 us
    ushort_t* Ybuf = H0b + 4194304;           // 16,777,216 us
    ushort_t* Bbuf = Ybuf + 16777216;         // 16,777,216 us
    ushort_t* Wg1T = Bbuf + 16777216;         //     16,384 us
    ushort_t* Wg2T = Wg1T + 16384;            //     65,536 us
    ushort_t* WT2  = Wg2T + 65536;            //    229,376 us
    ushort_t* AHb  = WT2 + 229376;            //     32,768 us
    int* DEG = (int*)(AHb + 32768);           //        512 i
    const int* srcv = ei;
    const int* dstv = ei + E_EDGES;

    hipLaunchKernelGGL(k_zero,   dim3(32),  dim3(1024), 0, stream, S, DEG, AH, GPb);
    hipLaunchKernelGGL(k_count,  dim3(16),  dim3(256),  0, stream, dstv, DEG);
    hipLaunchKernelGGL(k_dinv,   dim3(1),   dim3(512),  0, stream, DEG, DINV);
    hipLaunchKernelGGL(k_abuild, dim3(16),  dim3(256),  0, stream, srcv, dstv, DINV, AH);
    hipLaunchKernelGGL(k_adiag,  dim3(1),   dim3(512),  0, stream, DINV, AH);
    hipLaunchKernelGGL(k_cvta,   dim3(128), dim3(256),  0, stream, AH, AHb);
    hipLaunchKernelGGL(k_cvtw,   dim3(64),  dim3(256),  0, stream, Wg1, Wg1T, 64, 256);
    hipLaunchKernelGGL(k_cvtw,   dim3(256), dim3(256),  0, stream, Wg2, Wg2T, 256, 256);
    hipLaunchKernelGGL(k_cvtw,   dim3(896), dim3(256),  0, stream, W2, WT2, 1792, 128);
    hipLaunchKernelGGL(k_pe,     dim3(512), dim3(64),   0, stream, pos, Wp1, bp1, Wp2, bp2, PE);
    hipLaunchKernelGGL(k_conv1,  dim3(512), dim3(256),  0, stream, x, W1, C, S);
    hipLaunchKernelGGL(k_bn1,    dim3(512), dim3(256),  0, stream, C, S, g1, b1, PE, H0b);
    hipLaunchKernelGGL(k_gemm_mfma<64>,  dim3(512), dim3(512), 0, stream, H0b, Wg1T, Ybuf);
    hipLaunchKernelGGL(k_agg_mfma, dim3(1024), dim3(512), 0, stream, Ybuf, AHb, bg1, Bbuf);
    hipLaunchKernelGGL(k_gemm_mfma<256>, dim3(512), dim3(512), 0, stream, Bbuf, Wg2T, Ybuf);
    hipLaunchKernelGGL(k_agg_mfma, dim3(1024), dim3(512), 0, stream, Ybuf, AHb, bg2, Bbuf);
    hipLaunchKernelGGL(k_conv2_mfma, dim3(512), dim3(512), 0, stream, Bbuf, WT2, OUT, S);
    hipLaunchKernelGGL(k_bn2gp,  dim3(512, 6), dim3(128), 0, stream, OUT, S, g2, b2, GPb);
    hipLaunchKernelGGL(k_conv3,  dim3(224), dim3(128), 0, stream, GPb, W3, C3, S);
    hipLaunchKernelGGL(k_bn3pool, dim3(8),  dim3(128), 0, stream, C3, S, g3, b3, P2);
    hipLaunchKernelGGL(k_final,  dim3(1),   dim3(32),  0, stream, P2, Wd, bd, out);
}

// Round 7
// 323.220 us; speedup vs baseline: 3.7294x; 1.0694x over previous
//
#include <hip/hip_runtime.h>
#include <math.h>

#define N_NODES 512
#define T 128
#define E_EDGES 4096
#define C0 64
#define EMBED 256
#define C1 128
#define C2 128
#define NG 8
#define EPS 1e-5f

typedef unsigned short ushort_t;
typedef short bf16x8 __attribute__((ext_vector_type(8)));
typedef float f32x4 __attribute__((ext_vector_type(4)));

__device__ __forceinline__ ushort_t f2bf(float f) {
    union { float f; unsigned int u; } v; v.f = f;
    unsigned int r = v.u + 0x7fffu + ((v.u >> 16) & 1u);
    return (ushort_t)(r >> 16);
}
__device__ __forceinline__ float bf2f(ushort_t h) {
    union { unsigned int u; float f; } v; v.u = ((unsigned int)h) << 16;
    return v.f;
}

// ---------------- setup ----------------

__global__ void k_zero(float* S, int* DEG, float* AH, float* GP) {
    int i = blockIdx.x * 1024 + threadIdx.x;
    if (i < 640) S[i] = 0.f;
    if (i < 512) DEG[i] = 0;
    if (i < 32768) AH[i] = 0.f;
    if (i < 30720) GP[i] = 0.f;
}

__global__ void k_count(const int* __restrict__ dst, int* DEG) {
    int e = blockIdx.x * 256 + threadIdx.x;
    if (e < E_EDGES) atomicAdd(&DEG[dst[e]], 1);
}

__global__ void k_dinv(const int* __restrict__ DEG, float* DINV) {
    int n = threadIdx.x;
    DINV[n] = rsqrtf((float)DEG[n] + 1.0f);
}

__global__ void k_abuild(const int* __restrict__ src, const int* __restrict__ dst,
                         const float* __restrict__ DINV, float* AH) {
    int e = blockIdx.x * 256 + threadIdx.x;
    if (e < E_EDGES) {
        int d = dst[e], s = src[e];
        atomicAdd(&AH[(d >> 6) * 4096 + (d & 63) * 64 + (s & 63)], DINV[d] * DINV[s]);
    }
}

__global__ void k_adiag(const float* __restrict__ DINV, float* AH) {
    int n = threadIdx.x; // 512
    AH[(n >> 6) * 4096 + (n & 63) * 65] += DINV[n] * DINV[n];
}

__global__ void k_cvta(const float* __restrict__ AH, ushort_t* __restrict__ AHb) {
    int i = blockIdx.x * 256 + threadIdx.x;
    if (i < 32768) AHb[i] = f2bf(AH[i]);
}

// weight convert+transpose: in f32 (K x N) -> out bf16 (N x K)
__global__ void k_cvtw(const float* __restrict__ in, ushort_t* __restrict__ out, int K, int N) {
    int i = blockIdx.x * 256 + threadIdx.x;
    if (i < K * N) {
        int n = i / K, k = i % K;
        out[i] = f2bf(in[k * N + n]);
    }
}

// ---------------- position encoder MLP ----------------
__global__ void k_pe(const float* __restrict__ pos, const float* __restrict__ Wp1,
                     const float* __restrict__ bp1, const float* __restrict__ Wp2,
                     const float* __restrict__ bp2, float* __restrict__ PE) {
    int n = blockIdx.x;
    int c = threadIdx.x; // 64
    __shared__ float hid[64];
    float p0 = pos[n * 3], p1 = pos[n * 3 + 1], p2 = pos[n * 3 + 2];
    float h = p0 * Wp1[c] + p1 * Wp1[64 + c] + p2 * Wp1[128 + c] + bp1[c];
    hid[c] = fmaxf(h, 0.f);
    __syncthreads();
    float acc = bp2[c];
    #pragma unroll
    for (int j = 0; j < 64; ++j) acc += hid[j] * Wp2[j * 64 + c];
    PE[n * 64 + c] = acc;
}

// ---------------- conv1 (1->64, k=7, SAME) + BN stats ----------------
__global__ void k_conv1(const float* __restrict__ x, const float* __restrict__ W1,
                        float* __restrict__ C, float* S) {
    int n = blockIdx.x;
    int tid = threadIdx.x; // 256
    int c = tid & 63, tg = tid >> 6;
    __shared__ float xs[134];
    __shared__ float ws[448];
    __shared__ float red[256];
    for (int i = tid; i < 448; i += 256) ws[i] = W1[i];
    for (int i = tid; i < 134; i += 256) {
        int t = i - 3;
        xs[i] = (t >= 0 && t < T) ? x[n * T + t] : 0.f;
    }
    __syncthreads();
    float s1 = 0.f, s2 = 0.f;
    for (int t = tg; t < T; t += 4) {
        float acc = 0.f;
        #pragma unroll
        for (int k = 0; k < 7; ++k) acc += xs[t + k] * ws[k * 64 + c];
        C[(n * T + t) * 64 + c] = acc;
        s1 += acc; s2 += acc * acc;
    }
    red[tid] = s1; __syncthreads();
    if (tg == 0) { float v = red[c] + red[64 + c] + red[128 + c] + red[192 + c]; atomicAdd(&S[c], v); }
    __syncthreads();
    red[tid] = s2; __syncthreads();
    if (tg == 0) { float v = red[c] + red[64 + c] + red[128 + c] + red[192 + c]; atomicAdd(&S[64 + c], v); }
}

// ---------------- BN1 apply + ReLU + add pe -> bf16 H0 ----------------
__global__ void k_bn1(const float* __restrict__ C, const float* __restrict__ S,
                      const float* __restrict__ g1, const float* __restrict__ b1,
                      const float* __restrict__ PE, ushort_t* __restrict__ H0b) {
    int n = blockIdx.x, tid = threadIdx.x;
    int c = tid & 63, tg = tid >> 6;
    const float inv = 1.f / (float)(N_NODES * T);
    float mean = S[c] * inv;
    float var  = S[64 + c] * inv - mean * mean;
    float sc = g1[c] * rsqrtf(var + EPS);
    float sh = b1[c] - mean * sc;
    float pe = PE[n * 64 + c];
    for (int t = tg; t < T; t += 4) {
        int idx = (n * T + t) * 64 + c;
        H0b[idx] = f2bf(fmaxf(C[idx] * sc + sh, 0.f) + pe);
    }
}

// ---------------- fused GCN layer: per (graph, t) block ----------------
// P = X(64 x K) @ WT(256 x K)^T ; Y = relu( A(64x64) @ P + bias ), all MFMA
template <int K>
__global__ __launch_bounds__(512) void k_gcn(const ushort_t* __restrict__ X,
                                             const ushort_t* __restrict__ WT,
                                             const ushort_t* __restrict__ AHb,
                                             const float* __restrict__ bias,
                                             ushort_t* __restrict__ Y) {
    constexpr int KP = K + 8;
    constexpr int KC = K / 32;
    __shared__ ushort_t Xs[64 * KP];
    __shared__ ushort_t A_lds[64 * 72];
    __shared__ ushort_t Ws[2][256 * 40];
    __shared__ ushort_t Pt[256 * 72];
    int g = blockIdx.x >> 7, t = blockIdx.x & 127;
    int tid = threadIdx.x;
    int l = tid & 63, w = tid >> 6;
    int lrow = l & 15, lko = (l >> 4) * 8, lq = l >> 4;

    // stage A (64x64 row-major: [dst][src])
    {
        int row = tid >> 3, off = (tid & 7) * 8;
        *reinterpret_cast<bf16x8*>(&A_lds[row * 72 + off]) =
            *reinterpret_cast<const bf16x8*>(&AHb[g * 4096 + row * 64 + off]);
    }
    // stage Xs: 64 node-rows x K
    {
        constexpr int CPR = K / 8;
        constexpr int ITER = (64 * CPR) / 512;
        #pragma unroll
        for (int it = 0; it < ITER; ++it) {
            int lin = it * 512 + tid;
            int row = lin / CPR, ch = lin % CPR;
            *reinterpret_cast<bf16x8*>(&Xs[row * KP + ch * 8]) =
                *reinterpret_cast<const bf16x8*>(&X[((size_t)(g * 64 + row) * T + t) * K + ch * 8]);
        }
    }
    bf16x8 w0, w1;
    auto loadW = [&](int kc) {
        int lin1 = 512 + tid;
        w0 = *reinterpret_cast<const bf16x8*>(&WT[(size_t)(tid >> 2) * K + kc * 32 + (tid & 3) * 8]);
        w1 = *reinterpret_cast<const bf16x8*>(&WT[(size_t)(lin1 >> 2) * K + kc * 32 + (lin1 & 3) * 8]);
    };
    auto writeW = [&](int buf) {
        int lin1 = 512 + tid;
        *reinterpret_cast<bf16x8*>(&Ws[buf][(tid >> 2) * 40 + (tid & 3) * 8]) = w0;
        *reinterpret_cast<bf16x8*>(&Ws[buf][(lin1 >> 2) * 40 + (lin1 & 3) * 8]) = w1;
    };
    loadW(0); writeW(0);
    __syncthreads();

    // ---- stage 1: P = X @ W^T, wave w owns cols [w*32, w*32+32) ----
    f32x4 p[4][2];
    #pragma unroll
    for (int i = 0; i < 4; ++i)
        #pragma unroll
        for (int j = 0; j < 2; ++j) p[i][j] = (f32x4){0.f, 0.f, 0.f, 0.f};

    for (int kc = 0; kc < KC; ++kc) {
        if (kc + 1 < KC) loadW(kc + 1);
        bf16x8 a[4], b[2];
        #pragma unroll
        for (int mi = 0; mi < 4; ++mi)
            a[mi] = *reinterpret_cast<const bf16x8*>(&Xs[(mi * 16 + lrow) * KP + kc * 32 + lko]);
        #pragma unroll
        for (int ni = 0; ni < 2; ++ni)
            b[ni] = *reinterpret_cast<const bf16x8*>(&Ws[kc & 1][(w * 32 + ni * 16 + lrow) * 40 + lko]);
        #pragma unroll
        for (int mi = 0; mi < 4; ++mi)
            #pragma unroll
            for (int ni = 0; ni < 2; ++ni)
                p[mi][ni] = __builtin_amdgcn_mfma_f32_16x16x32_bf16(a[mi], b[ni], p[mi][ni], 0, 0, 0);
        if (kc + 1 < KC) { writeW((kc + 1) & 1); __syncthreads(); }
    }
    // ---- write P transposed: Pt[col][node], packed u32 ----
    #pragma unroll
    for (int mi = 0; mi < 4; ++mi) {
        int node0 = mi * 16 + lq * 4;
        #pragma unroll
        for (int ni = 0; ni < 2; ++ni) {
            int wcol = w * 32 + ni * 16 + lrow;
            unsigned u0 = (unsigned)f2bf(p[mi][ni][0]) | ((unsigned)f2bf(p[mi][ni][1]) << 16);
            unsigned u1 = (unsigned)f2bf(p[mi][ni][2]) | ((unsigned)f2bf(p[mi][ni][3]) << 16);
            *reinterpret_cast<unsigned*>(&Pt[wcol * 72 + node0]) = u0;
            *reinterpret_cast<unsigned*>(&Pt[wcol * 72 + node0 + 2]) = u1;
        }
    }
    __syncthreads();

    // ---- stage 2: D = A @ P, wave w owns cols [w*32, w*32+32) ----
    f32x4 d[4][2];
    #pragma unroll
    for (int i = 0; i < 4; ++i)
        #pragma unroll
        for (int j = 0; j < 2; ++j) d[i][j] = (f32x4){0.f, 0.f, 0.f, 0.f};

    #pragma unroll
    for (int kc = 0; kc < 2; ++kc) {
        bf16x8 a2[4], b2[2];
        #pragma unroll
        for (int mi = 0; mi < 4; ++mi)
            a2[mi] = *reinterpret_cast<const bf16x8*>(&A_lds[(mi * 16 + lrow) * 72 + kc * 32 + lko]);
        #pragma unroll
        for (int ni = 0; ni < 2; ++ni)
            b2[ni] = *reinterpret_cast<const bf16x8*>(&Pt[(w * 32 + ni * 16 + lrow) * 72 + kc * 32 + lko]);
        #pragma unroll
        for (int mi = 0; mi < 4; ++mi)
            #pragma unroll
            for (int ni = 0; ni < 2; ++ni)
                d[mi][ni] = __builtin_amdgcn_mfma_f32_16x16x32_bf16(a2[mi], b2[ni], d[mi][ni], 0, 0, 0);
    }
    #pragma unroll
    for (int ni = 0; ni < 2; ++ni) {
        int col = w * 32 + ni * 16 + lrow;
        float bs = bias[col];
        #pragma unroll
        for (int mi = 0; mi < 4; ++mi) {
            #pragma unroll
            for (int r = 0; r < 4; ++r) {
                int node = mi * 16 + lq * 4 + r;
                Y[((size_t)(g * 64 + node) * T + t) * 256 + col] =
                    f2bf(fmaxf(d[mi][ni][r] + bs, 0.f));
            }
        }
    }
}

// ---------------- conv2: H tile resident in LDS, W double-buffered, fused BN2 stats ----------------
__global__ __launch_bounds__(512) void k_conv2_mfma(const ushort_t* __restrict__ H,
                                                    const ushort_t* __restrict__ WT2,
                                                    float* __restrict__ OUT, float* S) {
    __shared__ ushort_t Hs[128 * 264];
    __shared__ ushort_t Ws[2][128 * 72];
    __shared__ float sS1[128];
    __shared__ float sS2[128];
    int n = blockIdx.x;
    int tid = threadIdx.x;
    int l = tid & 63, wid = tid >> 6;
    int wr = wid >> 1, wc = wid & 1;
    int lrow = l & 15, lko = (l >> 4) * 8, lq = l >> 4;

    if (tid < 128) { sS1[tid] = 0.f; sS2[tid] = 0.f; }

    // stage full H tile: 128 rows x 256
    #pragma unroll
    for (int it = 0; it < 8; ++it) {
        int lin = it * 512 + tid;
        int row = lin >> 5, ch = lin & 31;
        *reinterpret_cast<bf16x8*>(&Hs[row * 264 + ch * 8]) =
            *reinterpret_cast<const bf16x8*>(&H[((size_t)n * T + row) * 256 + ch * 8]);
    }
    bf16x8 w0, w1;
    auto loadW = [&](int tk) {
        int lin1 = 512 + tid;
        w0 = *reinterpret_cast<const bf16x8*>(&WT2[(size_t)(tid >> 3) * 1792 + tk * 64 + (tid & 7) * 8]);
        w1 = *reinterpret_cast<const bf16x8*>(&WT2[(size_t)(lin1 >> 3) * 1792 + tk * 64 + (lin1 & 7) * 8]);
    };
    auto writeW = [&](int buf) {
        int lin1 = 512 + tid;
        *reinterpret_cast<bf16x8*>(&Ws[buf][(tid >> 3) * 72 + (tid & 7) * 8]) = w0;
        *reinterpret_cast<bf16x8*>(&Ws[buf][(lin1 >> 3) * 72 + (lin1 & 7) * 8]) = w1;
    };
    loadW(0); writeW(0);
    __syncthreads();

    f32x4 acc[2][4];
    #pragma unroll
    for (int i = 0; i < 2; ++i)
        #pragma unroll
        for (int j = 0; j < 4; ++j) acc[i][j] = (f32x4){0.f, 0.f, 0.f, 0.f};

    for (int tk = 0; tk < 28; ++tk) {
        if (tk < 27) loadW(tk + 1);
        int tap = tk >> 2, cin0 = (tk & 3) * 64;
        int cur = tk & 1;
        bf16x8 a[2][2], b[4][2];
        #pragma unroll
        for (int mi = 0; mi < 2; ++mi) {
            int row = wr * 32 + mi * 16 + lrow + tap;
            if (row > 127) row = 127; // feeds only discarded outputs
            #pragma unroll
            for (int ks = 0; ks < 2; ++ks)
                a[mi][ks] = *reinterpret_cast<const bf16x8*>(&Hs[row * 264 + cin0 + ks * 32 + lko]);
        }
        #pragma unroll
        for (int ni = 0; ni < 4; ++ni)
            #pragma unroll
            for (int ks = 0; ks < 2; ++ks)
                b[ni][ks] = *reinterpret_cast<const bf16x8*>(&Ws[cur][(wc * 64 + ni * 16 + lrow) * 72 + ks * 32 + lko]);
        #pragma unroll
        for (int ks = 0; ks < 2; ++ks)
            #pragma unroll
            for (int mi = 0; mi < 2; ++mi)
                #pragma unroll
                for (int ni = 0; ni < 4; ++ni)
                    acc[mi][ni] = __builtin_amdgcn_mfma_f32_16x16x32_bf16(a[mi][ks], b[ni][ks], acc[mi][ni], 0, 0, 0);
        if (tk < 27) { writeW(cur ^ 1); __syncthreads(); }
    }
    // write + per-channel partial stats
    #pragma unroll
    for (int ni = 0; ni < 4; ++ni) {
        int col = wc * 64 + ni * 16 + lrow;
        float s1 = 0.f, s2 = 0.f;
        #pragma unroll
        for (int mi = 0; mi < 2; ++mi) {
            #pragma unroll
            for (int r = 0; r < 4; ++r) {
                int t = wr * 32 + mi * 16 + lq * 4 + r;
                if (t < 122) {
                    float v = acc[mi][ni][r];
                    OUT[((size_t)n * 122 + t) * 128 + col] = v;
                    s1 += v; s2 += v * v;
                }
            }
        }
        atomicAdd(&sS1[col], s1);
        atomicAdd(&sS2[col], s2);
    }
    __syncthreads();
    if (tid < 128) {
        atomicAdd(&S[128 + tid], sS1[tid]);
        atomicAdd(&S[256 + tid], sS2[tid]);
    }
}

// ---------------- BN2 apply + avgpool4 + ReLU + graph-mean (fused) ----------------
__global__ void k_bn2gp(const float* __restrict__ OUT, const float* __restrict__ S,
                        const float* __restrict__ g2, const float* __restrict__ b2,
                        float* __restrict__ GP) {
    int n = blockIdx.x;
    int tp0 = blockIdx.y * 5;
    int c = threadIdx.x; // 128
    int b = n >> 6;
    const float inv = 1.f / (float)(N_NODES * 122);
    float mean = S[128 + c] * inv;
    float var  = S[256 + c] * inv - mean * mean;
    float sc = g2[c] * rsqrtf(var + EPS);
    float sh = b2[c] - mean * sc;
    for (int tp = tp0; tp < tp0 + 5; ++tp) {
        float s = 0.f;
        #pragma unroll
        for (int i = 0; i < 4; ++i) s += OUT[((size_t)n * 122 + tp * 4 + i) * 128 + c];
        float v = fmaxf(s * 0.25f * sc + sh, 0.f);
        atomicAdd(&GP[((size_t)b * 30 + tp) * 128 + c], v * (1.f / 64.f));
    }
}

// ---------------- conv3 (128->128, k=3, VALID) + BN3 stats ----------------
__global__ void k_conv3(const float* __restrict__ GP, const float* __restrict__ W3,
                        float* __restrict__ C3, float* S) {
    int b = blockIdx.x / 28, t = blockIdx.x % 28;
    int c = threadIdx.x; // 128
    __shared__ float gs[3 * 128];
    for (int i = c; i < 384; i += 128) gs[i] = GP[((size_t)b * 30 + t) * 128 + i];
    __syncthreads();
    float acc = 0.f;
    for (int i = 0; i < 384; ++i) acc += gs[i] * W3[i * 128 + c];
    C3[((size_t)b * 28 + t) * 128 + c] = acc;
    atomicAdd(&S[384 + c], acc);
    atomicAdd(&S[512 + c], acc * acc);
}

// ---------------- BN3 apply + avgpool4 + ReLU ----------------
__global__ void k_bn3pool(const float* __restrict__ C3, const float* __restrict__ S,
                          const float* __restrict__ g3, const float* __restrict__ b3,
                          float* __restrict__ P2) {
    int b = blockIdx.x;  // 8
    int c = threadIdx.x; // 128
    const float inv = 1.f / (float)(NG * 28);
    float mean = S[384 + c] * inv;
    float var  = S[512 + c] * inv - mean * mean;
    float sc = g3[c] * rsqrtf(var + EPS);
    float sh = b3[c] - mean * sc;
    for (int tp = 0; tp < 7; ++tp) {
        float s = 0.f;
        #pragma unroll
        for (int i = 0; i < 4; ++i) s += C3[((size_t)b * 28 + tp * 4 + i) * 128 + c];
        P2[((size_t)b * 7 + tp) * 128 + c] = fmaxf(s * 0.25f * sc + sh, 0.f);
    }
}

// ---------------- final linear + log_softmax ----------------
__global__ void k_final(const float* __restrict__ P2, const float* __restrict__ Wd,
                        const float* __restrict__ bd, float* __restrict__ out) {
    int tid = threadIdx.x; // 32
    int b = tid >> 2, j = tid & 3;
    float acc = bd[j];
    for (int i = 0; i < 896; ++i) acc += P2[b * 896 + i] * Wd[i * 4 + j];
    float m = acc;
    m = fmaxf(m, __shfl_xor(m, 1, 4));
    m = fmaxf(m, __shfl_xor(m, 2, 4));
    float e = expf(acc - m);
    float s = e;
    s += __shfl_xor(s, 1, 4);
    s += __shfl_xor(s, 2, 4);
    out[tid] = acc - m - logf(s);
}

extern "C" void kernel_launch(void* const* d_in, const int* in_sizes, int n_in,
                              void* d_out, int out_size, void* d_ws, size_t ws_size,
                              hipStream_t stream) {
    const float* x   = (const float*)d_in[0];
    const float* pos = (const float*)d_in[1];
    const int*   ei  = (const int*)d_in[2];
    const float* W1  = (const float*)d_in[4];
    const float* g1  = (const float*)d_in[5];
    const float* b1  = (const float*)d_in[6];
    const float* Wp1 = (const float*)d_in[7];
    const float* bp1 = (const float*)d_in[8];
    const float* Wp2 = (const float*)d_in[9];
    const float* bp2 = (const float*)d_in[10];
    const float* Wg1 = (const float*)d_in[11];
    const float* bg1 = (const float*)d_in[12];
    const float* Wg2 = (const float*)d_in[13];
    const float* bg2 = (const float*)d_in[14];
    const float* W2  = (const float*)d_in[15];
    const float* g2  = (const float*)d_in[16];
    const float* b2  = (const float*)d_in[17];
    const float* W3  = (const float*)d_in[18];
    const float* g3  = (const float*)d_in[19];
    const float* b3  = (const float*)d_in[20];
    const float* Wd  = (const float*)d_in[21];
    const float* bd  = (const float*)d_in[22];
    float* out = (float*)d_out;

    float* ws = (float*)d_ws;
    float* C    = ws;                  //  4,194,304 f
    float* OUT  = C + 4194304;         //  7,995,392 f
    float* PE   = OUT + 7995392;       //     32,768 f
    float* GPb  = PE + 32768;          //     30,720 f
    float* C3   = GPb + 30720;         //     28,672 f
    float* P2   = C3 + 28672;          //      7,168 f
    float* S    = P2 + 7168;           //        640 f
    float* DINV = S + 640;             //        512 f
    float* AH   = DINV + 512;          //     32,768 f
    ushort_t* H0b  = (ushort_t*)(AH + 32768); //  4,194,304 us
    ushort_t* Ybuf = H0b + 4194304;           // 16,777,216 us : GCN layer-1 out
    ushort_t* Bbuf = Ybuf + 16777216;         // 16,777,216 us : GCN layer-2 out
    ushort_t* Wg1T = Bbuf + 16777216;         //     16,384 us
    ushort_t* Wg2T = Wg1T + 16384;            //     65,536 us
    ushort_t* WT2  = Wg2T + 65536;            //    229,376 us
    ushort_t* AHb  = WT2 + 229376;            //     32,768 us
    int* DEG = (int*)(AHb + 32768);           //        512 i
    const int* srcv = ei;
    const int* dstv = ei + E_EDGES;

    hipLaunchKernelGGL(k_zero,   dim3(32),  dim3(1024), 0, stream, S, DEG, AH, GPb);
    hipLaunchKernelGGL(k_count,  dim3(16),  dim3(256),  0, stream, dstv, DEG);
    hipLaunchKernelGGL(k_dinv,   dim3(1),   dim3(512),  0, stream, DEG, DINV);
    hipLaunchKernelGGL(k_abuild, dim3(16),  dim3(256),  0, stream, srcv, dstv, DINV, AH);
    hipLaunchKernelGGL(k_adiag,  dim3(1),   dim3(512),  0, stream, DINV, AH);
    hipLaunchKernelGGL(k_cvta,   dim3(128), dim3(256),  0, stream, AH, AHb);
    hipLaunchKernelGGL(k_cvtw,   dim3(64),  dim3(256),  0, stream, Wg1, Wg1T, 64, 256);
    hipLaunchKernelGGL(k_cvtw,   dim3(256), dim3(256),  0, stream, Wg2, Wg2T, 256, 256);
    hipLaunchKernelGGL(k_cvtw,   dim3(896), dim3(256),  0, stream, W2, WT2, 1792, 128);
    hipLaunchKernelGGL(k_pe,     dim3(512), dim3(64),   0, stream, pos, Wp1, bp1, Wp2, bp2, PE);
    hipLaunchKernelGGL(k_conv1,  dim3(512), dim3(256),  0, stream, x, W1, C, S);
    hipLaunchKernelGGL(k_bn1,    dim3(512), dim3(256),  0, stream, C, S, g1, b1, PE, H0b);
    hipLaunchKernelGGL(k_gcn<64>,  dim3(1024), dim3(512), 0, stream, H0b,  Wg1T, AHb, bg1, Ybuf);
    hipLaunchKernelGGL(k_gcn<256>, dim3(1024), dim3(512), 0, stream, Ybuf, Wg2T, AHb, bg2, Bbuf);
    hipLaunchKernelGGL(k_conv2_mfma, dim3(512), dim3(512), 0, stream, Bbuf, WT2, OUT, S);
    hipLaunchKernelGGL(k_bn2gp,  dim3(512, 6), dim3(128), 0, stream, OUT, S, g2, b2, GPb);
    hipLaunchKernelGGL(k_conv3,  dim3(224), dim3(128), 0, stream, GPb, W3, C3, S);
    hipLaunchKernelGGL(k_bn3pool, dim3(8),  dim3(128), 0, stream, C3, S, g3, b3, P2);
    hipLaunchKernelGGL(k_final,  dim3(1),   dim3(32),  0, stream, P2, Wd, bd, out);
}

// Round 8
// 292.460 us; speedup vs baseline: 4.1217x; 1.1052x over previous
//
#include <hip/hip_runtime.h>
#include <math.h>

#define N_NODES 512
#define T 128
#define E_EDGES 4096
#define C0 64
#define EMBED 256
#define C1 128
#define C2 128
#define NG 8
#define EPS 1e-5f

typedef unsigned short ushort_t;
typedef short bf16x8 __attribute__((ext_vector_type(8)));
typedef float f32x4 __attribute__((ext_vector_type(4)));

__device__ __forceinline__ ushort_t f2bf(float f) {
    union { float f; unsigned int u; } v; v.f = f;
    unsigned int r = v.u + 0x7fffu + ((v.u >> 16) & 1u);
    return (ushort_t)(r >> 16);
}
__device__ __forceinline__ float bf2f(ushort_t h) {
    union { unsigned int u; float f; } v; v.u = ((unsigned int)h) << 16;
    return v.f;
}

// ---------------- setup ----------------

__global__ void k_zero(float* S, int* DEG, float* AH, float* GP) {
    int i = blockIdx.x * 1024 + threadIdx.x;
    if (i < 640) S[i] = 0.f;
    if (i < 512) DEG[i] = 0;
    if (i < 32768) AH[i] = 0.f;
    if (i < 30720) GP[i] = 0.f;
}

__global__ void k_count(const int* __restrict__ dst, int* DEG) {
    int e = blockIdx.x * 256 + threadIdx.x;
    if (e < E_EDGES) atomicAdd(&DEG[dst[e]], 1);
}

__global__ void k_dinv(const int* __restrict__ DEG, float* DINV) {
    int n = threadIdx.x;
    DINV[n] = rsqrtf((float)DEG[n] + 1.0f);
}

__global__ void k_abuild(const int* __restrict__ src, const int* __restrict__ dst,
                         const float* __restrict__ DINV, float* AH) {
    int e = blockIdx.x * 256 + threadIdx.x;
    if (e < E_EDGES) {
        int d = dst[e], s = src[e];
        atomicAdd(&AH[(d >> 6) * 4096 + (d & 63) * 64 + (s & 63)], DINV[d] * DINV[s]);
    }
}

__global__ void k_adiag(const float* __restrict__ DINV, float* AH) {
    int n = threadIdx.x; // 512
    AH[(n >> 6) * 4096 + (n & 63) * 65] += DINV[n] * DINV[n];
}

__global__ void k_cvta(const float* __restrict__ AH, ushort_t* __restrict__ AHb) {
    int i = blockIdx.x * 256 + threadIdx.x;
    if (i < 32768) AHb[i] = f2bf(AH[i]);
}

// weight convert+transpose: in f32 (K x N) -> out bf16 (N x K)
__global__ void k_cvtw(const float* __restrict__ in, ushort_t* __restrict__ out, int K, int N) {
    int i = blockIdx.x * 256 + threadIdx.x;
    if (i < K * N) {
        int n = i / K, k = i % K;
        out[i] = f2bf(in[k * N + n]);
    }
}

// ---------------- position encoder MLP ----------------
__global__ void k_pe(const float* __restrict__ pos, const float* __restrict__ Wp1,
                     const float* __restrict__ bp1, const float* __restrict__ Wp2,
                     const float* __restrict__ bp2, float* __restrict__ PE) {
    int n = blockIdx.x;
    int c = threadIdx.x; // 64
    __shared__ float hid[64];
    float p0 = pos[n * 3], p1 = pos[n * 3 + 1], p2 = pos[n * 3 + 2];
    float h = p0 * Wp1[c] + p1 * Wp1[64 + c] + p2 * Wp1[128 + c] + bp1[c];
    hid[c] = fmaxf(h, 0.f);
    __syncthreads();
    float acc = bp2[c];
    #pragma unroll
    for (int j = 0; j < 64; ++j) acc += hid[j] * Wp2[j * 64 + c];
    PE[n * 64 + c] = acc;
}

// ---------------- conv1 (1->64, k=7, SAME) + BN stats ----------------
__global__ void k_conv1(const float* __restrict__ x, const float* __restrict__ W1,
                        float* __restrict__ C, float* S) {
    int n = blockIdx.x;
    int tid = threadIdx.x; // 256
    int c = tid & 63, tg = tid >> 6;
    __shared__ float xs[134];
    __shared__ float ws[448];
    __shared__ float red[256];
    for (int i = tid; i < 448; i += 256) ws[i] = W1[i];
    for (int i = tid; i < 134; i += 256) {
        int t = i - 3;
        xs[i] = (t >= 0 && t < T) ? x[n * T + t] : 0.f;
    }
    __syncthreads();
    float s1 = 0.f, s2 = 0.f;
    for (int t = tg; t < T; t += 4) {
        float acc = 0.f;
        #pragma unroll
        for (int k = 0; k < 7; ++k) acc += xs[t + k] * ws[k * 64 + c];
        C[(n * T + t) * 64 + c] = acc;
        s1 += acc; s2 += acc * acc;
    }
    red[tid] = s1; __syncthreads();
    if (tg == 0) { float v = red[c] + red[64 + c] + red[128 + c] + red[192 + c]; atomicAdd(&S[c], v); }
    __syncthreads();
    red[tid] = s2; __syncthreads();
    if (tg == 0) { float v = red[c] + red[64 + c] + red[128 + c] + red[192 + c]; atomicAdd(&S[64 + c], v); }
}

// ---------------- BN1 apply + ReLU + add pe -> bf16 H0 ----------------
__global__ void k_bn1(const float* __restrict__ C, const float* __restrict__ S,
                      const float* __restrict__ g1, const float* __restrict__ b1,
                      const float* __restrict__ PE, ushort_t* __restrict__ H0b) {
    int n = blockIdx.x, tid = threadIdx.x;
    int c = tid & 63, tg = tid >> 6;
    const float inv = 1.f / (float)(N_NODES * T);
    float mean = S[c] * inv;
    float var  = S[64 + c] * inv - mean * mean;
    float sc = g1[c] * rsqrtf(var + EPS);
    float sh = b1[c] - mean * sc;
    float pe = PE[n * 64 + c];
    for (int t = tg; t < T; t += 4) {
        int idx = (n * T + t) * 64 + c;
        H0b[idx] = f2bf(fmaxf(C[idx] * sc + sh, 0.f) + pe);
    }
}

// ---------------- fused GCN layer: per (graph, t) block, slim LDS (2 blocks/CU) ----------------
// P = X(64 x K) @ WT(256 x K)^T ; Y = relu( A(64x64) @ P + bias ), all MFMA
template <int K>
__global__ __launch_bounds__(512) void k_gcn(const ushort_t* __restrict__ X,
                                             const ushort_t* __restrict__ WT,
                                             const ushort_t* __restrict__ AHb,
                                             const float* __restrict__ bias,
                                             ushort_t* __restrict__ Y) {
    constexpr int KP = K + 8;
    constexpr int KC = K / 32;
    // union region: Xs (64 x KP shorts) during stage 1, Pt (256 x 68) during stage 2
    __shared__ ushort_t U[256 * 68];      // 34,816 B
    __shared__ ushort_t A_lds[64 * 68];   //  8,704 B
    __shared__ ushort_t Ws[2][256 * 36];  // 36,864 B   => total 80,384 B -> 2 blocks/CU
    ushort_t* Xs = U;
    ushort_t* Pt = U;
    int g = blockIdx.x >> 7, t = blockIdx.x & 127;
    int tid = threadIdx.x;
    int l = tid & 63, w = tid >> 6;
    int lrow = l & 15, lko = (l >> 4) * 8, lq = l >> 4;

    // stage A (64x64 row-major: [dst][src]) at stride 68
    {
        int row = tid >> 3, off = (tid & 7) * 8;
        *reinterpret_cast<bf16x8*>(&A_lds[row * 68 + off]) =
            *reinterpret_cast<const bf16x8*>(&AHb[g * 4096 + row * 64 + off]);
    }
    // stage Xs: 64 node-rows x K at stride KP
    {
        constexpr int CPR = K / 8;
        constexpr int ITER = (64 * CPR) / 512;
        #pragma unroll
        for (int it = 0; it < ITER; ++it) {
            int lin = it * 512 + tid;
            int row = lin / CPR, ch = lin % CPR;
            *reinterpret_cast<bf16x8*>(&Xs[row * KP + ch * 8]) =
                *reinterpret_cast<const bf16x8*>(&X[((size_t)(g * 64 + row) * T + t) * K + ch * 8]);
        }
    }
    bf16x8 w0, w1;
    auto loadW = [&](int kc) {
        int lin1 = 512 + tid;
        w0 = *reinterpret_cast<const bf16x8*>(&WT[(size_t)(tid >> 2) * K + kc * 32 + (tid & 3) * 8]);
        w1 = *reinterpret_cast<const bf16x8*>(&WT[(size_t)(lin1 >> 2) * K + kc * 32 + (lin1 & 3) * 8]);
    };
    auto writeW = [&](int buf) {
        int lin1 = 512 + tid;
        *reinterpret_cast<bf16x8*>(&Ws[buf][(tid >> 2) * 36 + (tid & 3) * 8]) = w0;
        *reinterpret_cast<bf16x8*>(&Ws[buf][(lin1 >> 2) * 36 + (lin1 & 3) * 8]) = w1;
    };
    loadW(0); writeW(0);
    __syncthreads();

    // ---- stage 1: P = X @ W^T, wave w owns cols [w*32, w*32+32) ----
    f32x4 p[4][2];
    #pragma unroll
    for (int i = 0; i < 4; ++i)
        #pragma unroll
        for (int j = 0; j < 2; ++j) p[i][j] = (f32x4){0.f, 0.f, 0.f, 0.f};

    for (int kc = 0; kc < KC; ++kc) {
        if (kc + 1 < KC) loadW(kc + 1);
        bf16x8 a[4], b[2];
        #pragma unroll
        for (int mi = 0; mi < 4; ++mi)
            a[mi] = *reinterpret_cast<const bf16x8*>(&Xs[(mi * 16 + lrow) * KP + kc * 32 + lko]);
        #pragma unroll
        for (int ni = 0; ni < 2; ++ni)
            b[ni] = *reinterpret_cast<const bf16x8*>(&Ws[kc & 1][(w * 32 + ni * 16 + lrow) * 36 + lko]);
        #pragma unroll
        for (int mi = 0; mi < 4; ++mi)
            #pragma unroll
            for (int ni = 0; ni < 2; ++ni)
                p[mi][ni] = __builtin_amdgcn_mfma_f32_16x16x32_bf16(a[mi], b[ni], p[mi][ni], 0, 0, 0);
        if (kc + 1 < KC) { writeW((kc + 1) & 1); __syncthreads(); }
    }
    __syncthreads(); // all Xs reads done before Pt overwrites the union

    // ---- write P transposed: Pt[col][node] at stride 68, packed u32 ----
    #pragma unroll
    for (int mi = 0; mi < 4; ++mi) {
        int node0 = mi * 16 + lq * 4;
        #pragma unroll
        for (int ni = 0; ni < 2; ++ni) {
            int wcol = w * 32 + ni * 16 + lrow;
            unsigned u0 = (unsigned)f2bf(p[mi][ni][0]) | ((unsigned)f2bf(p[mi][ni][1]) << 16);
            unsigned u1 = (unsigned)f2bf(p[mi][ni][2]) | ((unsigned)f2bf(p[mi][ni][3]) << 16);
            *reinterpret_cast<unsigned*>(&Pt[wcol * 68 + node0]) = u0;
            *reinterpret_cast<unsigned*>(&Pt[wcol * 68 + node0 + 2]) = u1;
        }
    }
    __syncthreads();

    // ---- stage 2: D = A @ P ----
    f32x4 d[4][2];
    #pragma unroll
    for (int i = 0; i < 4; ++i)
        #pragma unroll
        for (int j = 0; j < 2; ++j) d[i][j] = (f32x4){0.f, 0.f, 0.f, 0.f};

    #pragma unroll
    for (int kc = 0; kc < 2; ++kc) {
        bf16x8 a2[4], b2[2];
        #pragma unroll
        for (int mi = 0; mi < 4; ++mi)
            a2[mi] = *reinterpret_cast<const bf16x8*>(&A_lds[(mi * 16 + lrow) * 68 + kc * 32 + lko]);
        #pragma unroll
        for (int ni = 0; ni < 2; ++ni)
            b2[ni] = *reinterpret_cast<const bf16x8*>(&Pt[(w * 32 + ni * 16 + lrow) * 68 + kc * 32 + lko]);
        #pragma unroll
        for (int mi = 0; mi < 4; ++mi)
            #pragma unroll
            for (int ni = 0; ni < 2; ++ni)
                d[mi][ni] = __builtin_amdgcn_mfma_f32_16x16x32_bf16(a2[mi], b2[ni], d[mi][ni], 0, 0, 0);
    }
    #pragma unroll
    for (int ni = 0; ni < 2; ++ni) {
        int col = w * 32 + ni * 16 + lrow;
        float bs = bias[col];
        #pragma unroll
        for (int mi = 0; mi < 4; ++mi) {
            #pragma unroll
            for (int r = 0; r < 4; ++r) {
                int node = mi * 16 + lq * 4 + r;
                Y[((size_t)(g * 64 + node) * T + t) * 256 + col] =
                    f2bf(fmaxf(d[mi][ni][r] + bs, 0.f));
            }
        }
    }
}

// ---------------- conv2: cin-halved H tile (2 blocks/CU), W dbuf, fused stats + pooled sums ----------------
__global__ __launch_bounds__(512) void k_conv2_mfma(const ushort_t* __restrict__ H,
                                                    const ushort_t* __restrict__ WT2,
                                                    float* __restrict__ P1S, float* S) {
    __shared__ ushort_t Hs[128 * 136];    // 34,816 B (one cin half)
    __shared__ ushort_t Ws[2][128 * 72];  // 36,864 B
    __shared__ float sS1[128];
    __shared__ float sS2[128];
    int n = blockIdx.x;
    int tid = threadIdx.x;
    int l = tid & 63, wid = tid >> 6;
    int wr = wid >> 1, wc = wid & 1;
    int lrow = l & 15, lko = (l >> 4) * 8, lq = l >> 4;

    if (tid < 128) { sS1[tid] = 0.f; sS2[tid] = 0.f; }

    f32x4 acc[2][4];
    #pragma unroll
    for (int i = 0; i < 2; ++i)
        #pragma unroll
        for (int j = 0; j < 4; ++j) acc[i][j] = (f32x4){0.f, 0.f, 0.f, 0.f};

    bf16x8 w0, w1;
    for (int half = 0; half < 2; ++half) {
        __syncthreads(); // waves done reading previous Hs/Ws
        // stage Hs: 128 rows x 128 shorts (this cin half)
        #pragma unroll
        for (int it = 0; it < 4; ++it) {
            int lin = it * 512 + tid;
            int row = lin >> 4, off = (lin & 15) * 8;
            *reinterpret_cast<bf16x8*>(&Hs[row * 136 + off]) =
                *reinterpret_cast<const bf16x8*>(&H[((size_t)n * T + row) * 256 + half * 128 + off]);
        }
        // W chunk 0 of this half
        {
            int lin1 = 512 + tid;
            w0 = *reinterpret_cast<const bf16x8*>(&WT2[(size_t)(tid >> 3) * 1792 + half * 128 + (tid & 7) * 8]);
            w1 = *reinterpret_cast<const bf16x8*>(&WT2[(size_t)(lin1 >> 3) * 1792 + half * 128 + (lin1 & 7) * 8]);
            *reinterpret_cast<bf16x8*>(&Ws[0][(tid >> 3) * 72 + (tid & 7) * 8]) = w0;
            *reinterpret_cast<bf16x8*>(&Ws[0][(lin1 >> 3) * 72 + (lin1 & 7) * 8]) = w1;
        }
        __syncthreads();

        for (int tk = 0; tk < 14; ++tk) {
            if (tk < 13) {
                int nt = tk + 1;
                int ntap = nt >> 1, nsub = (nt & 1) * 64;
                int lin1 = 512 + tid;
                w0 = *reinterpret_cast<const bf16x8*>(&WT2[(size_t)(tid >> 3) * 1792 + ntap * 256 + half * 128 + nsub + (tid & 7) * 8]);
                w1 = *reinterpret_cast<const bf16x8*>(&WT2[(size_t)(lin1 >> 3) * 1792 + ntap * 256 + half * 128 + nsub + (lin1 & 7) * 8]);
            }
            int tap = tk >> 1, sub = (tk & 1) * 64;
            int cur = tk & 1;
            bf16x8 a[2][2], b[4][2];
            #pragma unroll
            for (int mi = 0; mi < 2; ++mi) {
                int row = wr * 32 + mi * 16 + lrow + tap;
                if (row > 127) row = 127; // feeds only discarded outputs
                #pragma unroll
                for (int ks = 0; ks < 2; ++ks)
                    a[mi][ks] = *reinterpret_cast<const bf16x8*>(&Hs[row * 136 + sub + ks * 32 + lko]);
            }
            #pragma unroll
            for (int ni = 0; ni < 4; ++ni)
                #pragma unroll
                for (int ks = 0; ks < 2; ++ks)
                    b[ni][ks] = *reinterpret_cast<const bf16x8*>(&Ws[cur][(wc * 64 + ni * 16 + lrow) * 72 + ks * 32 + lko]);
            #pragma unroll
            for (int ks = 0; ks < 2; ++ks)
                #pragma unroll
                for (int mi = 0; mi < 2; ++mi)
                    #pragma unroll
                    for (int ni = 0; ni < 4; ++ni)
                        acc[mi][ni] = __builtin_amdgcn_mfma_f32_16x16x32_bf16(a[mi][ks], b[ni][ks], acc[mi][ni], 0, 0, 0);
            if (tk < 13) {
                int lin1 = 512 + tid;
                *reinterpret_cast<bf16x8*>(&Ws[cur ^ 1][(tid >> 3) * 72 + (tid & 7) * 8]) = w0;
                *reinterpret_cast<bf16x8*>(&Ws[cur ^ 1][(lin1 >> 3) * 72 + (lin1 & 7) * 8]) = w1;
                __syncthreads();
            }
        }
    }
    // epilogue: per-channel stats over t<122 and pooled sums (pool groups of 4 live in one lane)
    #pragma unroll
    for (int ni = 0; ni < 4; ++ni) {
        int col = wc * 64 + ni * 16 + lrow;
        float s1 = 0.f, s2 = 0.f;
        #pragma unroll
        for (int mi = 0; mi < 2; ++mi) {
            int t0 = wr * 32 + mi * 16 + lq * 4;
            float psum = 0.f;
            #pragma unroll
            for (int r = 0; r < 4; ++r) {
                float v = acc[mi][ni][r];
                if (t0 + r < 122) { s1 += v; s2 += v * v; }
                psum += v;
            }
            if (t0 <= 116) P1S[((size_t)n * 30 + (t0 >> 2)) * 128 + col] = psum;
        }
        atomicAdd(&sS1[col], s1);
        atomicAdd(&sS2[col], s2);
    }
    __syncthreads();
    if (tid < 128) {
        atomicAdd(&S[128 + tid], sS1[tid]);
        atomicAdd(&S[256 + tid], sS2[tid]);
    }
}

// ---------------- BN2 affine on pooled sums + ReLU + graph-mean (fused) ----------------
__global__ void k_bn2gp(const float* __restrict__ P1S, const float* __restrict__ S,
                        const float* __restrict__ g2, const float* __restrict__ b2,
                        float* __restrict__ GP) {
    int n = blockIdx.x;
    int tp0 = blockIdx.y * 5;
    int c = threadIdx.x; // 128
    int b = n >> 6;
    const float inv = 1.f / (float)(N_NODES * 122);
    float mean = S[128 + c] * inv;
    float var  = S[256 + c] * inv - mean * mean;
    float sc = g2[c] * rsqrtf(var + EPS);
    float sh = b2[c] - mean * sc;
    for (int tp = tp0; tp < tp0 + 5; ++tp) {
        float psum = P1S[((size_t)n * 30 + tp) * 128 + c];
        float v = fmaxf(psum * 0.25f * sc + sh, 0.f);
        atomicAdd(&GP[((size_t)b * 30 + tp) * 128 + c], v * (1.f / 64.f));
    }
}

// ---------------- conv3 (128->128, k=3, VALID) + BN3 stats ----------------
__global__ void k_conv3(const float* __restrict__ GP, const float* __restrict__ W3,
                        float* __restrict__ C3, float* S) {
    int b = blockIdx.x / 28, t = blockIdx.x % 28;
    int c = threadIdx.x; // 128
    __shared__ float gs[3 * 128];
    for (int i = c; i < 384; i += 128) gs[i] = GP[((size_t)b * 30 + t) * 128 + i];
    __syncthreads();
    float acc = 0.f;
    for (int i = 0; i < 384; ++i) acc += gs[i] * W3[i * 128 + c];
    C3[((size_t)b * 28 + t) * 128 + c] = acc;
    atomicAdd(&S[384 + c], acc);
    atomicAdd(&S[512 + c], acc * acc);
}

// ---------------- BN3 apply + avgpool4 + ReLU ----------------
__global__ void k_bn3pool(const float* __restrict__ C3, const float* __restrict__ S,
                          const float* __restrict__ g3, const float* __restrict__ b3,
                          float* __restrict__ P2) {
    int b = blockIdx.x;  // 8
    int c = threadIdx.x; // 128
    const float inv = 1.f / (float)(NG * 28);
    float mean = S[384 + c] * inv;
    float var  = S[512 + c] * inv - mean * mean;
    float sc = g3[c] * rsqrtf(var + EPS);
    float sh = b3[c] - mean * sc;
    for (int tp = 0; tp < 7; ++tp) {
        float s = 0.f;
        #pragma unroll
        for (int i = 0; i < 4; ++i) s += C3[((size_t)b * 28 + tp * 4 + i) * 128 + c];
        P2[((size_t)b * 7 + tp) * 128 + c] = fmaxf(s * 0.25f * sc + sh, 0.f);
    }
}

// ---------------- final linear + log_softmax ----------------
__global__ void k_final(const float* __restrict__ P2, const float* __restrict__ Wd,
                        const float* __restrict__ bd, float* __restrict__ out) {
    int tid = threadIdx.x; // 32
    int b = tid >> 2, j = tid & 3;
    float acc = bd[j];
    for (int i = 0; i < 896; ++i) acc += P2[b * 896 + i] * Wd[i * 4 + j];
    float m = acc;
    m = fmaxf(m, __shfl_xor(m, 1, 4));
    m = fmaxf(m, __shfl_xor(m, 2, 4));
    float e = expf(acc - m);
    float s = e;
    s += __shfl_xor(s, 1, 4);
    s += __shfl_xor(s, 2, 4);
    out[tid] = acc - m - logf(s);
}

extern "C" void kernel_launch(void* const* d_in, const int* in_sizes, int n_in,
                              void* d_out, int out_size, void* d_ws, size_t ws_size,
                              hipStream_t stream) {
    const float* x   = (const float*)d_in[0];
    const float* pos = (const float*)d_in[1];
    const int*   ei  = (const int*)d_in[2];
    const float* W1  = (const float*)d_in[4];
    const float* g1  = (const float*)d_in[5];
    const float* b1  = (const float*)d_in[6];
    const float* Wp1 = (const float*)d_in[7];
    const float* bp1 = (const float*)d_in[8];
    const float* Wp2 = (const float*)d_in[9];
    const float* bp2 = (const float*)d_in[10];
    const float* Wg1 = (const float*)d_in[11];
    const float* bg1 = (const float*)d_in[12];
    const float* Wg2 = (const float*)d_in[13];
    const float* bg2 = (const float*)d_in[14];
    const float* W2  = (const float*)d_in[15];
    const float* g2  = (const float*)d_in[16];
    const float* b2  = (const float*)d_in[17];
    const float* W3  = (const float*)d_in[18];
    const float* g3  = (const float*)d_in[19];
    const float* b3  = (const float*)d_in[20];
    const float* Wd  = (const float*)d_in[21];
    const float* bd  = (const float*)d_in[22];
    float* out = (float*)d_out;

    float* ws = (float*)d_ws;
    float* C    = ws;                  //  4,194,304 f
    float* P1S  = C + 4194304;         //  1,966,080 f : conv2 pooled sums
    float* PE   = P1S + 1966080;       //     32,768 f
    float* GPb  = PE + 32768;          //     30,720 f
    float* C3   = GPb + 30720;         //     28,672 f
    float* P2   = C3 + 28672;          //      7,168 f
    float* S    = P2 + 7168;           //        640 f
    float* DINV = S + 640;             //        512 f
    float* AH   = DINV + 512;          //     32,768 f
    ushort_t* H0b  = (ushort_t*)(AH + 32768); //  4,194,304 us
    ushort_t* Ybuf = H0b + 4194304;           // 16,777,216 us : GCN layer-1 out
    ushort_t* Bbuf = Ybuf + 16777216;         // 16,777,216 us : GCN layer-2 out
    ushort_t* Wg1T = Bbuf + 16777216;         //     16,384 us
    ushort_t* Wg2T = Wg1T + 16384;            //     65,536 us
    ushort_t* WT2  = Wg2T + 65536;            //    229,376 us
    ushort_t* AHb  = WT2 + 229376;            //     32,768 us
    int* DEG = (int*)(AHb + 32768);           //        512 i
    const int* srcv = ei;
    const int* dstv = ei + E_EDGES;

    hipLaunchKernelGGL(k_zero,   dim3(32),  dim3(1024), 0, stream, S, DEG, AH, GPb);
    hipLaunchKernelGGL(k_count,  dim3(16),  dim3(256),  0, stream, dstv, DEG);
    hipLaunchKernelGGL(k_dinv,   dim3(1),   dim3(512),  0, stream, DEG, DINV);
    hipLaunchKernelGGL(k_abuild, dim3(16),  dim3(256),  0, stream, srcv, dstv, DINV, AH);
    hipLaunchKernelGGL(k_adiag,  dim3(1),   dim3(512),  0, stream, DINV, AH);
    hipLaunchKernelGGL(k_cvta,   dim3(128), dim3(256),  0, stream, AH, AHb);
    hipLaunchKernelGGL(k_cvtw,   dim3(64),  dim3(256),  0, stream, Wg1, Wg1T, 64, 256);
    hipLaunchKernelGGL(k_cvtw,   dim3(256), dim3(256),  0, stream, Wg2, Wg2T, 256, 256);
    hipLaunchKernelGGL(k_cvtw,   dim3(896), dim3(256),  0, stream, W2, WT2, 1792, 128);
    hipLaunchKernelGGL(k_pe,     dim3(512), dim3(64),   0, stream, pos, Wp1, bp1, Wp2, bp2, PE);
    hipLaunchKernelGGL(k_conv1,  dim3(512), dim3(256),  0, stream, x, W1, C, S);
    hipLaunchKernelGGL(k_bn1,    dim3(512), dim3(256),  0, stream, C, S, g1, b1, PE, H0b);
    hipLaunchKernelGGL(k_gcn<64>,  dim3(1024), dim3(512), 0, stream, H0b,  Wg1T, AHb, bg1, Ybuf);
    hipLaunchKernelGGL(k_gcn<256>, dim3(1024), dim3(512), 0, stream, Ybuf, Wg2T, AHb, bg2, Bbuf);
    hipLaunchKernelGGL(k_conv2_mfma, dim3(512), dim3(512), 0, stream, Bbuf, WT2, P1S, S);
    hipLaunchKernelGGL(k_bn2gp,  dim3(512, 6), dim3(128), 0, stream, P1S, S, g2, b2, GPb);
    hipLaunchKernelGGL(k_conv3,  dim3(224), dim3(128), 0, stream, GPb, W3, C3, S);
    hipLaunchKernelGGL(k_bn3pool, dim3(8),  dim3(128), 0, stream, C3, S, g3, b3, P2);
    hipLaunchKernelGGL(k_final,  dim3(1),   dim3(32),  0, stream, P2, Wd, bd, out);
}

// Round 9
// 270.193 us; speedup vs baseline: 4.4614x; 1.0824x over previous
//
#include <hip/hip_runtime.h>
#include <math.h>

#define N_NODES 512
#define T 128
#define E_EDGES 4096
#define EPS 1e-5f
#define NG 8

typedef unsigned short ushort_t;
typedef short bf16x8 __attribute__((ext_vector_type(8)));
typedef float f32x4 __attribute__((ext_vector_type(4)));

__device__ __forceinline__ ushort_t f2bf(float f) {
    union { float f; unsigned int u; } v; v.f = f;
    unsigned int r = v.u + 0x7fffu + ((v.u >> 16) & 1u);
    return (ushort_t)(r >> 16);
}
__device__ __forceinline__ float bf2f(ushort_t h) {
    union { unsigned int u; float f; } v; v.u = ((unsigned int)h) << 16;
    return v.f;
}

// ---------------- setup: zeroing + all weight convert/transpose ----------------
__global__ void k_setup(const float* __restrict__ Wg1, const float* __restrict__ Wg2,
                        const float* __restrict__ W2,
                        ushort_t* __restrict__ Wg1T, ushort_t* __restrict__ Wg2T,
                        ushort_t* __restrict__ WT2,
                        float* S, int* DEG, float* AH, float* GP) {
    int gtid = blockIdx.x * 256 + threadIdx.x;
    int stride = gridDim.x * 256;
    for (int i = gtid; i < 229376; i += stride) { int n = i / 1792, k = i % 1792; WT2[i] = f2bf(W2[k * 128 + n]); }
    for (int i = gtid; i < 65536; i += stride)  { int n = i >> 8, k = i & 255;    Wg2T[i] = f2bf(Wg2[k * 256 + n]); }
    for (int i = gtid; i < 16384; i += stride)  { int n = i >> 6, k = i & 63;     Wg1T[i] = f2bf(Wg1[k * 256 + n]); }
    for (int i = gtid; i < 32768; i += stride) AH[i] = 0.f;
    for (int i = gtid; i < 30720; i += stride) GP[i] = 0.f;
    for (int i = gtid; i < 640; i += stride) S[i] = 0.f;
    for (int i = gtid; i < 512; i += stride) DEG[i] = 0;
}

__global__ void k_count(const int* __restrict__ dst, int* DEG) {
    int e = blockIdx.x * 256 + threadIdx.x;
    if (e < E_EDGES) atomicAdd(&DEG[dst[e]], 1);
}

__global__ void k_abuild(const int* __restrict__ src, const int* __restrict__ dst,
                         const int* __restrict__ DEG, float* AH) {
    int e = blockIdx.x * 256 + threadIdx.x;
    if (e < E_EDGES) {
        int d = dst[e], s = src[e];
        float norm = rsqrtf((float)DEG[d] + 1.f) * rsqrtf((float)DEG[s] + 1.f);
        atomicAdd(&AH[(d >> 6) * 4096 + (d & 63) * 64 + (s & 63)], norm);
    }
}

__global__ void k_cvta(const float* __restrict__ AH, const int* __restrict__ DEG,
                       ushort_t* __restrict__ AHb) {
    int i = blockIdx.x * 256 + threadIdx.x;
    if (i < 32768) {
        int g = i >> 12, r = (i >> 6) & 63, c = i & 63;
        float v = AH[i];
        if (r == c) v += 1.f / ((float)DEG[g * 64 + r] + 1.f);
        AHb[i] = f2bf(v);
    }
}

// ---------------- position encoder MLP ----------------
__global__ void k_pe(const float* __restrict__ pos, const float* __restrict__ Wp1,
                     const float* __restrict__ bp1, const float* __restrict__ Wp2,
                     const float* __restrict__ bp2, float* __restrict__ PE) {
    int n = blockIdx.x;
    int c = threadIdx.x; // 64
    __shared__ float hid[64];
    float p0 = pos[n * 3], p1 = pos[n * 3 + 1], p2 = pos[n * 3 + 2];
    float h = p0 * Wp1[c] + p1 * Wp1[64 + c] + p2 * Wp1[128 + c] + bp1[c];
    hid[c] = fmaxf(h, 0.f);
    __syncthreads();
    float acc = bp2[c];
    #pragma unroll
    for (int j = 0; j < 64; ++j) acc += hid[j] * Wp2[j * 64 + c];
    PE[n * 64 + c] = acc;
}

// ---------------- conv1 (1->64, k=7, SAME) + BN stats, bf16 out ----------------
__global__ void k_conv1(const float* __restrict__ x, const float* __restrict__ W1,
                        ushort_t* __restrict__ Cb, float* S) {
    int n = blockIdx.x;
    int tid = threadIdx.x; // 256
    int c = tid & 63, tg = tid >> 6;
    __shared__ float xs[134];
    __shared__ float ws[448];
    __shared__ float red[256];
    for (int i = tid; i < 448; i += 256) ws[i] = W1[i];
    for (int i = tid; i < 134; i += 256) {
        int t = i - 3;
        xs[i] = (t >= 0 && t < T) ? x[n * T + t] : 0.f;
    }
    __syncthreads();
    float s1 = 0.f, s2 = 0.f;
    for (int t = tg; t < T; t += 4) {
        float acc = 0.f;
        #pragma unroll
        for (int k = 0; k < 7; ++k) acc += xs[t + k] * ws[k * 64 + c];
        Cb[(n * T + t) * 64 + c] = f2bf(acc);
        s1 += acc; s2 += acc * acc;
    }
    red[tid] = s1; __syncthreads();
    if (tg == 0) { float v = red[c] + red[64 + c] + red[128 + c] + red[192 + c]; atomicAdd(&S[c], v); }
    __syncthreads();
    red[tid] = s2; __syncthreads();
    if (tg == 0) { float v = red[c] + red[64 + c] + red[128 + c] + red[192 + c]; atomicAdd(&S[64 + c], v); }
}

// ---------------- fused 2-layer GCN per (graph, t): BN1+PE staging, both layers in LDS ----------------
__global__ __launch_bounds__(512) void k_gcn12(const ushort_t* __restrict__ Cb,
                                               const float* __restrict__ S,
                                               const float* __restrict__ g1, const float* __restrict__ b1,
                                               const float* __restrict__ PE,
                                               const ushort_t* __restrict__ W1T,
                                               const ushort_t* __restrict__ W2T,
                                               const ushort_t* __restrict__ AHb,
                                               const float* __restrict__ bg1, const float* __restrict__ bg2,
                                               ushort_t* __restrict__ Gout) {
    __shared__ ushort_t A_lds[64 * 68];   //  8,704 B
    __shared__ ushort_t U1[64 * 264];     // 33,792 B : Xs (stride 72) then D1 row-major (stride 264)
    __shared__ ushort_t U2[256 * 68];     // 34,816 B : P1t then P2t
    __shared__ ushort_t Ws[2][256 * 36];  // 36,864 B : W chunk double-buffer
    int g = blockIdx.x >> 7, t = blockIdx.x & 127;
    int tid = threadIdx.x;
    int l = tid & 63, w = tid >> 6;
    int lrow = l & 15, lko = (l >> 4) * 8, lq = l >> 4;

    // stage A
    {
        int row = tid >> 3, off = (tid & 7) * 8;
        *reinterpret_cast<bf16x8*>(&A_lds[row * 68 + off]) =
            *reinterpret_cast<const bf16x8*>(&AHb[g * 4096 + row * 64 + off]);
    }
    // stage Xs with BN1 affine + ReLU + PE
    {
        int node = tid >> 3, ch0 = (tid & 7) * 8;
        bf16x8 cv = *reinterpret_cast<const bf16x8*>(&Cb[((size_t)(g * 64 + node) * T + t) * 64 + ch0]);
        const float inv = 1.f / (float)(N_NODES * T);
        bf16x8 xv;
        #pragma unroll
        for (int j = 0; j < 8; ++j) {
            int c = ch0 + j;
            float mean = S[c] * inv;
            float var  = S[64 + c] * inv - mean * mean;
            float sc = g1[c] * rsqrtf(var + EPS);
            float sh = b1[c] - mean * sc;
            float v = fmaxf(bf2f((ushort_t)cv[j]) * sc + sh, 0.f) + PE[(g * 64 + node) * 64 + c];
            xv[j] = (short)f2bf(v);
        }
        *reinterpret_cast<bf16x8*>(&U1[node * 72 + ch0]) = xv;
    }

    bf16x8 w0, w1;
    auto loadW1 = [&](int kc) {
        int r1 = 128 + (tid >> 2);
        w0 = *reinterpret_cast<const bf16x8*>(&W1T[(size_t)(tid >> 2) * 64 + kc * 32 + (tid & 3) * 8]);
        w1 = *reinterpret_cast<const bf16x8*>(&W1T[(size_t)r1 * 64 + kc * 32 + (tid & 3) * 8]);
    };
    auto loadW2 = [&](int kc) {
        int r1 = 128 + (tid >> 2);
        w0 = *reinterpret_cast<const bf16x8*>(&W2T[(size_t)(tid >> 2) * 256 + kc * 32 + (tid & 3) * 8]);
        w1 = *reinterpret_cast<const bf16x8*>(&W2T[(size_t)r1 * 256 + kc * 32 + (tid & 3) * 8]);
    };
    auto writeW = [&](int buf) {
        int r1 = 128 + (tid >> 2);
        *reinterpret_cast<bf16x8*>(&Ws[buf][(tid >> 2) * 36 + (tid & 3) * 8]) = w0;
        *reinterpret_cast<bf16x8*>(&Ws[buf][r1 * 36 + (tid & 3) * 8]) = w1;
    };
    loadW1(0); writeW(0);
    __syncthreads();

    // ---- phase 1: P1 = X @ W1^T (K=64) ----
    f32x4 p[4][2];
    #pragma unroll
    for (int i = 0; i < 4; ++i)
        #pragma unroll
        for (int j = 0; j < 2; ++j) p[i][j] = (f32x4){0.f, 0.f, 0.f, 0.f};
    #pragma unroll
    for (int kc = 0; kc < 2; ++kc) {
        if (kc == 0) loadW1(1);
        bf16x8 a[4], b[2];
        #pragma unroll
        for (int mi = 0; mi < 4; ++mi)
            a[mi] = *reinterpret_cast<const bf16x8*>(&U1[(mi * 16 + lrow) * 72 + kc * 32 + lko]);
        #pragma unroll
        for (int ni = 0; ni < 2; ++ni)
            b[ni] = *reinterpret_cast<const bf16x8*>(&Ws[kc][(w * 32 + ni * 16 + lrow) * 36 + lko]);
        #pragma unroll
        for (int mi = 0; mi < 4; ++mi)
            #pragma unroll
            for (int ni = 0; ni < 2; ++ni)
                p[mi][ni] = __builtin_amdgcn_mfma_f32_16x16x32_bf16(a[mi], b[ni], p[mi][ni], 0, 0, 0);
        if (kc == 0) { writeW(1); __syncthreads(); }
    }
    loadW2(0);
    __syncthreads(); // all Xs / Ws reads complete

    // write P1t [col][node] + stage W2 chunk 0
    #pragma unroll
    for (int mi = 0; mi < 4; ++mi) {
        int node0 = mi * 16 + lq * 4;
        #pragma unroll
        for (int ni = 0; ni < 2; ++ni) {
            int col = w * 32 + ni * 16 + lrow;
            unsigned u0 = (unsigned)f2bf(p[mi][ni][0]) | ((unsigned)f2bf(p[mi][ni][1]) << 16);
            unsigned u1 = (unsigned)f2bf(p[mi][ni][2]) | ((unsigned)f2bf(p[mi][ni][3]) << 16);
            *reinterpret_cast<unsigned*>(&U2[col * 68 + node0]) = u0;
            *reinterpret_cast<unsigned*>(&U2[col * 68 + node0 + 2]) = u1;
        }
    }
    writeW(0);
    __syncthreads();

    // ---- phase 2: D1 = A @ P1t + bg1, ReLU -> D1 row-major in U1 ----
    f32x4 d[4][2];
    #pragma unroll
    for (int i = 0; i < 4; ++i)
        #pragma unroll
        for (int j = 0; j < 2; ++j) d[i][j] = (f32x4){0.f, 0.f, 0.f, 0.f};
    #pragma unroll
    for (int kc = 0; kc < 2; ++kc) {
        bf16x8 a2[4], b2[2];
        #pragma unroll
        for (int mi = 0; mi < 4; ++mi)
            a2[mi] = *reinterpret_cast<const bf16x8*>(&A_lds[(mi * 16 + lrow) * 68 + kc * 32 + lko]);
        #pragma unroll
        for (int ni = 0; ni < 2; ++ni)
            b2[ni] = *reinterpret_cast<const bf16x8*>(&U2[(w * 32 + ni * 16 + lrow) * 68 + kc * 32 + lko]);
        #pragma unroll
        for (int mi = 0; mi < 4; ++mi)
            #pragma unroll
            for (int ni = 0; ni < 2; ++ni)
                d[mi][ni] = __builtin_amdgcn_mfma_f32_16x16x32_bf16(a2[mi], b2[ni], d[mi][ni], 0, 0, 0);
    }
    #pragma unroll
    for (int ni = 0; ni < 2; ++ni) {
        int col = w * 32 + ni * 16 + lrow;
        float bs = bg1[col];
        #pragma unroll
        for (int mi = 0; mi < 4; ++mi) {
            #pragma unroll
            for (int r = 0; r < 4; ++r) {
                int node = mi * 16 + lq * 4 + r;
                U1[node * 264 + col] = f2bf(fmaxf(d[mi][ni][r] + bs, 0.f));
            }
        }
    }
    __syncthreads(); // D1rm visible; Ws[0] visible

    // ---- phase 3: P2 = D1 @ W2^T (K=256), W2 streamed dbuf ----
    f32x4 q[4][2];
    #pragma unroll
    for (int i = 0; i < 4; ++i)
        #pragma unroll
        for (int j = 0; j < 2; ++j) q[i][j] = (f32x4){0.f, 0.f, 0.f, 0.f};
    for (int kc = 0; kc < 8; ++kc) {
        if (kc < 7) loadW2(kc + 1);
        bf16x8 a[4], b[2];
        #pragma unroll
        for (int mi = 0; mi < 4; ++mi)
            a[mi] = *reinterpret_cast<const bf16x8*>(&U1[(mi * 16 + lrow) * 264 + kc * 32 + lko]);
        #pragma unroll
        for (int ni = 0; ni < 2; ++ni)
            b[ni] = *reinterpret_cast<const bf16x8*>(&Ws[kc & 1][(w * 32 + ni * 16 + lrow) * 36 + lko]);
        #pragma unroll
        for (int mi = 0; mi < 4; ++mi)
            #pragma unroll
            for (int ni = 0; ni < 2; ++ni)
                q[mi][ni] = __builtin_amdgcn_mfma_f32_16x16x32_bf16(a[mi], b[ni], q[mi][ni], 0, 0, 0);
        if (kc < 7) { writeW((kc + 1) & 1); __syncthreads(); }
    }
    // write P2t into U2 (P1t dead since phase 2 barrier)
    #pragma unroll
    for (int mi = 0; mi < 4; ++mi) {
        int node0 = mi * 16 + lq * 4;
        #pragma unroll
        for (int ni = 0; ni < 2; ++ni) {
            int col = w * 32 + ni * 16 + lrow;
            unsigned u0 = (unsigned)f2bf(q[mi][ni][0]) | ((unsigned)f2bf(q[mi][ni][1]) << 16);
            unsigned u1 = (unsigned)f2bf(q[mi][ni][2]) | ((unsigned)f2bf(q[mi][ni][3]) << 16);
            *reinterpret_cast<unsigned*>(&U2[col * 68 + node0]) = u0;
            *reinterpret_cast<unsigned*>(&U2[col * 68 + node0 + 2]) = u1;
        }
    }
    __syncthreads();

    // ---- phase 4: D2 = A @ P2t + bg2, ReLU -> global ----
    f32x4 d2[4][2];
    #pragma unroll
    for (int i = 0; i < 4; ++i)
        #pragma unroll
        for (int j = 0; j < 2; ++j) d2[i][j] = (f32x4){0.f, 0.f, 0.f, 0.f};
    #pragma unroll
    for (int kc = 0; kc < 2; ++kc) {
        bf16x8 a2[4], b2[2];
        #pragma unroll
        for (int mi = 0; mi < 4; ++mi)
            a2[mi] = *reinterpret_cast<const bf16x8*>(&A_lds[(mi * 16 + lrow) * 68 + kc * 32 + lko]);
        #pragma unroll
        for (int ni = 0; ni < 2; ++ni)
            b2[ni] = *reinterpret_cast<const bf16x8*>(&U2[(w * 32 + ni * 16 + lrow) * 68 + kc * 32 + lko]);
        #pragma unroll
        for (int mi = 0; mi < 4; ++mi)
            #pragma unroll
            for (int ni = 0; ni < 2; ++ni)
                d2[mi][ni] = __builtin_amdgcn_mfma_f32_16x16x32_bf16(a2[mi], b2[ni], d2[mi][ni], 0, 0, 0);
    }
    #pragma unroll
    for (int ni = 0; ni < 2; ++ni) {
        int col = w * 32 + ni * 16 + lrow;
        float bs = bg2[col];
        #pragma unroll
        for (int mi = 0; mi < 4; ++mi) {
            #pragma unroll
            for (int r = 0; r < 4; ++r) {
                int node = mi * 16 + lq * 4 + r;
                Gout[((size_t)(g * 64 + node) * T + t) * 256 + col] =
                    f2bf(fmaxf(d2[mi][ni][r] + bs, 0.f));
            }
        }
    }
}

// ---------------- conv2: cin-halved H tile, W dbuf, fused stats + pooled sums ----------------
__global__ __launch_bounds__(512) void k_conv2_mfma(const ushort_t* __restrict__ H,
                                                    const ushort_t* __restrict__ WT2,
                                                    float* __restrict__ P1S, float* S) {
    __shared__ ushort_t Hs[128 * 136];
    __shared__ ushort_t Ws[2][128 * 72];
    __shared__ float sS1[128];
    __shared__ float sS2[128];
    int n = blockIdx.x;
    int tid = threadIdx.x;
    int l = tid & 63, wid = tid >> 6;
    int wr = wid >> 1, wc = wid & 1;
    int lrow = l & 15, lko = (l >> 4) * 8, lq = l >> 4;

    if (tid < 128) { sS1[tid] = 0.f; sS2[tid] = 0.f; }

    f32x4 acc[2][4];
    #pragma unroll
    for (int i = 0; i < 2; ++i)
        #pragma unroll
        for (int j = 0; j < 4; ++j) acc[i][j] = (f32x4){0.f, 0.f, 0.f, 0.f};

    bf16x8 w0, w1;
    for (int half = 0; half < 2; ++half) {
        __syncthreads();
        #pragma unroll
        for (int it = 0; it < 4; ++it) {
            int lin = it * 512 + tid;
            int row = lin >> 4, off = (lin & 15) * 8;
            *reinterpret_cast<bf16x8*>(&Hs[row * 136 + off]) =
                *reinterpret_cast<const bf16x8*>(&H[((size_t)n * T + row) * 256 + half * 128 + off]);
        }
        {
            int lin1 = 512 + tid;
            w0 = *reinterpret_cast<const bf16x8*>(&WT2[(size_t)(tid >> 3) * 1792 + half * 128 + (tid & 7) * 8]);
            w1 = *reinterpret_cast<const bf16x8*>(&WT2[(size_t)(lin1 >> 3) * 1792 + half * 128 + (lin1 & 7) * 8]);
            *reinterpret_cast<bf16x8*>(&Ws[0][(tid >> 3) * 72 + (tid & 7) * 8]) = w0;
            *reinterpret_cast<bf16x8*>(&Ws[0][(lin1 >> 3) * 72 + (lin1 & 7) * 8]) = w1;
        }
        __syncthreads();

        for (int tk = 0; tk < 14; ++tk) {
            if (tk < 13) {
                int nt = tk + 1;
                int ntap = nt >> 1, nsub = (nt & 1) * 64;
                int lin1 = 512 + tid;
                w0 = *reinterpret_cast<const bf16x8*>(&WT2[(size_t)(tid >> 3) * 1792 + ntap * 256 + half * 128 + nsub + (tid & 7) * 8]);
                w1 = *reinterpret_cast<const bf16x8*>(&WT2[(size_t)(lin1 >> 3) * 1792 + ntap * 256 + half * 128 + nsub + (lin1 & 7) * 8]);
            }
            int tap = tk >> 1, sub = (tk & 1) * 64;
            int cur = tk & 1;
            bf16x8 a[2][2], b[4][2];
            #pragma unroll
            for (int mi = 0; mi < 2; ++mi) {
                int row = wr * 32 + mi * 16 + lrow + tap;
                if (row > 127) row = 127;
                #pragma unroll
                for (int ks = 0; ks < 2; ++ks)
                    a[mi][ks] = *reinterpret_cast<const bf16x8*>(&Hs[row * 136 + sub + ks * 32 + lko]);
            }
            #pragma unroll
            for (int ni = 0; ni < 4; ++ni)
                #pragma unroll
                for (int ks = 0; ks < 2; ++ks)
                    b[ni][ks] = *reinterpret_cast<const bf16x8*>(&Ws[cur][(wc * 64 + ni * 16 + lrow) * 72 + ks * 32 + lko]);
            #pragma unroll
            for (int ks = 0; ks < 2; ++ks)
                #pragma unroll
                for (int mi = 0; mi < 2; ++mi)
                    #pragma unroll
                    for (int ni = 0; ni < 4; ++ni)
                        acc[mi][ni] = __builtin_amdgcn_mfma_f32_16x16x32_bf16(a[mi][ks], b[ni][ks], acc[mi][ni], 0, 0, 0);
            if (tk < 13) {
                int lin1 = 512 + tid;
                *reinterpret_cast<bf16x8*>(&Ws[cur ^ 1][(tid >> 3) * 72 + (tid & 7) * 8]) = w0;
                *reinterpret_cast<bf16x8*>(&Ws[cur ^ 1][(lin1 >> 3) * 72 + (lin1 & 7) * 8]) = w1;
                __syncthreads();
            }
        }
    }
    #pragma unroll
    for (int ni = 0; ni < 4; ++ni) {
        int col = wc * 64 + ni * 16 + lrow;
        float s1 = 0.f, s2 = 0.f;
        #pragma unroll
        for (int mi = 0; mi < 2; ++mi) {
            int t0 = wr * 32 + mi * 16 + lq * 4;
            float psum = 0.f;
            #pragma unroll
            for (int r = 0; r < 4; ++r) {
                float v = acc[mi][ni][r];
                if (t0 + r < 122) { s1 += v; s2 += v * v; }
                psum += v;
            }
            if (t0 <= 116) P1S[((size_t)n * 30 + (t0 >> 2)) * 128 + col] = psum;
        }
        atomicAdd(&sS1[col], s1);
        atomicAdd(&sS2[col], s2);
    }
    __syncthreads();
    if (tid < 128) {
        atomicAdd(&S[128 + tid], sS1[tid]);
        atomicAdd(&S[256 + tid], sS2[tid]);
    }
}

// ---------------- BN2 affine on pooled sums + ReLU + graph-mean (fused) ----------------
__global__ void k_bn2gp(const float* __restrict__ P1S, const float* __restrict__ S,
                        const float* __restrict__ g2, const float* __restrict__ b2,
                        float* __restrict__ GP) {
    int n = blockIdx.x;
    int tp0 = blockIdx.y * 5;
    int c = threadIdx.x; // 128
    int b = n >> 6;
    const float inv = 1.f / (float)(N_NODES * 122);
    float mean = S[128 + c] * inv;
    float var  = S[256 + c] * inv - mean * mean;
    float sc = g2[c] * rsqrtf(var + EPS);
    float sh = b2[c] - mean * sc;
    for (int tp = tp0; tp < tp0 + 5; ++tp) {
        float psum = P1S[((size_t)n * 30 + tp) * 128 + c];
        float v = fmaxf(psum * 0.25f * sc + sh, 0.f);
        atomicAdd(&GP[((size_t)b * 30 + tp) * 128 + c], v * (1.f / 64.f));
    }
}

// ---------------- conv3 (128->128, k=3, VALID) + BN3 stats ----------------
__global__ void k_conv3(const float* __restrict__ GP, const float* __restrict__ W3,
                        float* __restrict__ C3, float* S) {
    int b = blockIdx.x / 28, t = blockIdx.x % 28;
    int c = threadIdx.x; // 128
    __shared__ float gs[3 * 128];
    for (int i = c; i < 384; i += 128) gs[i] = GP[((size_t)b * 30 + t) * 128 + i];
    __syncthreads();
    float acc = 0.f;
    for (int i = 0; i < 384; ++i) acc += gs[i] * W3[i * 128 + c];
    C3[((size_t)b * 28 + t) * 128 + c] = acc;
    atomicAdd(&S[384 + c], acc);
    atomicAdd(&S[512 + c], acc * acc);
}

// ---------------- BN3 apply + avgpool4 + ReLU ----------------
__global__ void k_bn3pool(const float* __restrict__ C3, const float* __restrict__ S,
                          const float* __restrict__ g3, const float* __restrict__ b3,
                          float* __restrict__ P2) {
    int b = blockIdx.x;  // 8
    int c = threadIdx.x; // 128
    const float inv = 1.f / (float)(NG * 28);
    float mean = S[384 + c] * inv;
    float var  = S[512 + c] * inv - mean * mean;
    float sc = g3[c] * rsqrtf(var + EPS);
    float sh = b3[c] - mean * sc;
    for (int tp = 0; tp < 7; ++tp) {
        float s = 0.f;
        #pragma unroll
        for (int i = 0; i < 4; ++i) s += C3[((size_t)b * 28 + tp * 4 + i) * 128 + c];
        P2[((size_t)b * 7 + tp) * 128 + c] = fmaxf(s * 0.25f * sc + sh, 0.f);
    }
}

// ---------------- final linear + log_softmax ----------------
__global__ void k_final(const float* __restrict__ P2, const float* __restrict__ Wd,
                        const float* __restrict__ bd, float* __restrict__ out) {
    int tid = threadIdx.x; // 32
    int b = tid >> 2, j = tid & 3;
    float acc = bd[j];
    for (int i = 0; i < 896; ++i) acc += P2[b * 896 + i] * Wd[i * 4 + j];
    float m = acc;
    m = fmaxf(m, __shfl_xor(m, 1, 4));
    m = fmaxf(m, __shfl_xor(m, 2, 4));
    float e = expf(acc - m);
    float s = e;
    s += __shfl_xor(s, 1, 4);
    s += __shfl_xor(s, 2, 4);
    out[tid] = acc - m - logf(s);
}

extern "C" void kernel_launch(void* const* d_in, const int* in_sizes, int n_in,
                              void* d_out, int out_size, void* d_ws, size_t ws_size,
                              hipStream_t stream) {
    const float* x   = (const float*)d_in[0];
    const float* pos = (const float*)d_in[1];
    const int*   ei  = (const int*)d_in[2];
    const float* W1  = (const float*)d_in[4];
    const float* g1  = (const float*)d_in[5];
    const float* b1  = (const float*)d_in[6];
    const float* Wp1 = (const float*)d_in[7];
    const float* bp1 = (const float*)d_in[8];
    const float* Wp2 = (const float*)d_in[9];
    const float* bp2 = (const float*)d_in[10];
    const float* Wg1 = (const float*)d_in[11];
    const float* bg1 = (const float*)d_in[12];
    const float* Wg2 = (const float*)d_in[13];
    const float* bg2 = (const float*)d_in[14];
    const float* W2  = (const float*)d_in[15];
    const float* g2  = (const float*)d_in[16];
    const float* b2  = (const float*)d_in[17];
    const float* W3  = (const float*)d_in[18];
    const float* g3  = (const float*)d_in[19];
    const float* b3  = (const float*)d_in[20];
    const float* Wd  = (const float*)d_in[21];
    const float* bd  = (const float*)d_in[22];
    float* out = (float*)d_out;

    float* ws = (float*)d_ws;
    float* P1S  = ws;                  //  1,966,080 f : conv2 pooled sums
    float* PE   = P1S + 1966080;       //     32,768 f
    float* GPb  = PE + 32768;          //     30,720 f
    float* C3   = GPb + 30720;         //     28,672 f
    float* P2   = C3 + 28672;          //      7,168 f
    float* S    = P2 + 7168;           //        640 f
    float* AH   = S + 640;             //     32,768 f
    ushort_t* Cb   = (ushort_t*)(AH + 32768); //  4,194,304 us : conv1 out bf16
    ushort_t* Gout = Cb + 4194304;            // 16,777,216 us : GCN stack out
    ushort_t* Wg1T = Gout + 16777216;         //     16,384 us
    ushort_t* Wg2T = Wg1T + 16384;            //     65,536 us
    ushort_t* WT2  = Wg2T + 65536;            //    229,376 us
    ushort_t* AHb  = WT2 + 229376;            //     32,768 us
    int* DEG = (int*)(AHb + 32768);           //        512 i
    const int* srcv = ei;
    const int* dstv = ei + E_EDGES;

    hipLaunchKernelGGL(k_setup,  dim3(896), dim3(256), 0, stream, Wg1, Wg2, W2, Wg1T, Wg2T, WT2, S, DEG, AH, GPb);
    hipLaunchKernelGGL(k_count,  dim3(16),  dim3(256), 0, stream, dstv, DEG);
    hipLaunchKernelGGL(k_abuild, dim3(16),  dim3(256), 0, stream, srcv, dstv, DEG, AH);
    hipLaunchKernelGGL(k_cvta,   dim3(128), dim3(256), 0, stream, AH, DEG, AHb);
    hipLaunchKernelGGL(k_pe,     dim3(512), dim3(64),  0, stream, pos, Wp1, bp1, Wp2, bp2, PE);
    hipLaunchKernelGGL(k_conv1,  dim3(512), dim3(256), 0, stream, x, W1, Cb, S);
    hipLaunchKernelGGL(k_gcn12,  dim3(1024), dim3(512), 0, stream, Cb, S, g1, b1, PE, Wg1T, Wg2T, AHb, bg1, bg2, Gout);
    hipLaunchKernelGGL(k_conv2_mfma, dim3(512), dim3(512), 0, stream, Gout, WT2, P1S, S);
    hipLaunchKernelGGL(k_bn2gp,  dim3(512, 6), dim3(128), 0, stream, P1S, S, g2, b2, GPb);
    hipLaunchKernelGGL(k_conv3,  dim3(224), dim3(128), 0, stream, GPb, W3, C3, S);
    hipLaunchKernelGGL(k_bn3pool, dim3(8),  dim3(128), 0, stream, C3, S, g3, b3, P2);
    hipLaunchKernelGGL(k_final,  dim3(1),   dim3(32),  0, stream, P2, Wd, bd, out);
}

// Round 10
// 265.155 us; speedup vs baseline: 4.5461x; 1.0190x over previous
//
#include <hip/hip_runtime.h>
#include <math.h>

#define N_NODES 512
#define T 128
#define E_EDGES 4096
#define EPS 1e-5f
#define NG 8

typedef unsigned short ushort_t;
typedef short bf16x8 __attribute__((ext_vector_type(8)));
typedef float f32x4 __attribute__((ext_vector_type(4)));

__device__ __forceinline__ ushort_t f2bf(float f) {
    union { float f; unsigned int u; } v; v.f = f;
    unsigned int r = v.u + 0x7fffu + ((v.u >> 16) & 1u);
    return (ushort_t)(r >> 16);
}
__device__ __forceinline__ float bf2f(ushort_t h) {
    union { unsigned int u; float f; } v; v.u = ((unsigned int)h) << 16;
    return v.f;
}
// async global->LDS, 16B per lane, dest = ldsbase + lane*16
__device__ __forceinline__ void gload16(const ushort_t* g, ushort_t* l) {
    __builtin_amdgcn_global_load_lds(
        (const __attribute__((address_space(1))) void*)g,
        (__attribute__((address_space(3))) void*)l, 16, 0, 0);
}

// ---------------- setup: zeroing + all weight convert/transpose ----------------
__global__ void k_setup(const float* __restrict__ Wg1, const float* __restrict__ Wg2,
                        const float* __restrict__ W2,
                        ushort_t* __restrict__ Wg1T, ushort_t* __restrict__ Wg2T,
                        ushort_t* __restrict__ WT2,
                        float* S, int* DEG, float* AH, float* GP) {
    int gtid = blockIdx.x * 256 + threadIdx.x;
    int stride = gridDim.x * 256;
    for (int i = gtid; i < 229376; i += stride) { int n = i / 1792, k = i % 1792; WT2[i] = f2bf(W2[k * 128 + n]); }
    for (int i = gtid; i < 65536; i += stride)  { int n = i >> 8, k = i & 255;    Wg2T[i] = f2bf(Wg2[k * 256 + n]); }
    for (int i = gtid; i < 16384; i += stride)  { int n = i >> 6, k = i & 63;     Wg1T[i] = f2bf(Wg1[k * 256 + n]); }
    for (int i = gtid; i < 32768; i += stride) AH[i] = 0.f;
    for (int i = gtid; i < 30720; i += stride) GP[i] = 0.f;
    for (int i = gtid; i < 640; i += stride) S[i] = 0.f;
    for (int i = gtid; i < 512; i += stride) DEG[i] = 0;
}

__global__ void k_count(const int* __restrict__ dst, int* DEG) {
    int e = blockIdx.x * 256 + threadIdx.x;
    if (e < E_EDGES) atomicAdd(&DEG[dst[e]], 1);
}

__global__ void k_abuild(const int* __restrict__ src, const int* __restrict__ dst,
                         const int* __restrict__ DEG, float* AH) {
    int e = blockIdx.x * 256 + threadIdx.x;
    if (e < E_EDGES) {
        int d = dst[e], s = src[e];
        float norm = rsqrtf((float)DEG[d] + 1.f) * rsqrtf((float)DEG[s] + 1.f);
        atomicAdd(&AH[(d >> 6) * 4096 + (d & 63) * 64 + (s & 63)], norm);
    }
}

__global__ void k_cvta(const float* __restrict__ AH, const int* __restrict__ DEG,
                       ushort_t* __restrict__ AHb) {
    int i = blockIdx.x * 256 + threadIdx.x;
    if (i < 32768) {
        int g = i >> 12, r = (i >> 6) & 63, c = i & 63;
        float v = AH[i];
        if (r == c) v += 1.f / ((float)DEG[g * 64 + r] + 1.f);
        AHb[i] = f2bf(v);
    }
}

// ---------------- position encoder MLP ----------------
__global__ void k_pe(const float* __restrict__ pos, const float* __restrict__ Wp1,
                     const float* __restrict__ bp1, const float* __restrict__ Wp2,
                     const float* __restrict__ bp2, float* __restrict__ PE) {
    int n = blockIdx.x;
    int c = threadIdx.x; // 64
    __shared__ float hid[64];
    float p0 = pos[n * 3], p1 = pos[n * 3 + 1], p2 = pos[n * 3 + 2];
    float h = p0 * Wp1[c] + p1 * Wp1[64 + c] + p2 * Wp1[128 + c] + bp1[c];
    hid[c] = fmaxf(h, 0.f);
    __syncthreads();
    float acc = bp2[c];
    #pragma unroll
    for (int j = 0; j < 64; ++j) acc += hid[j] * Wp2[j * 64 + c];
    PE[n * 64 + c] = acc;
}

// ---------------- conv1 (1->64, k=7, SAME) + BN stats, bf16 out ----------------
__global__ void k_conv1(const float* __restrict__ x, const float* __restrict__ W1,
                        ushort_t* __restrict__ Cb, float* S) {
    int n = blockIdx.x;
    int tid = threadIdx.x; // 256
    int c = tid & 63, tg = tid >> 6;
    __shared__ float xs[134];
    __shared__ float ws[448];
    __shared__ float red[256];
    for (int i = tid; i < 448; i += 256) ws[i] = W1[i];
    for (int i = tid; i < 134; i += 256) {
        int t = i - 3;
        xs[i] = (t >= 0 && t < T) ? x[n * T + t] : 0.f;
    }
    __syncthreads();
    float s1 = 0.f, s2 = 0.f;
    for (int t = tg; t < T; t += 4) {
        float acc = 0.f;
        #pragma unroll
        for (int k = 0; k < 7; ++k) acc += xs[t + k] * ws[k * 64 + c];
        Cb[(n * T + t) * 64 + c] = f2bf(acc);
        s1 += acc; s2 += acc * acc;
    }
    red[tid] = s1; __syncthreads();
    if (tg == 0) { float v = red[c] + red[64 + c] + red[128 + c] + red[192 + c]; atomicAdd(&S[c], v); }
    __syncthreads();
    red[tid] = s2; __syncthreads();
    if (tg == 0) { float v = red[c] + red[64 + c] + red[128 + c] + red[192 + c]; atomicAdd(&S[64 + c], v); }
}

// ---------------- fused 2-layer GCN per (graph, t): gload_lds W streaming ----------------
__global__ __launch_bounds__(512) void k_gcn12(const ushort_t* __restrict__ Cb,
                                               const float* __restrict__ S,
                                               const float* __restrict__ g1, const float* __restrict__ b1,
                                               const float* __restrict__ PE,
                                               const ushort_t* __restrict__ W1T,
                                               const ushort_t* __restrict__ W2T,
                                               const ushort_t* __restrict__ AHb,
                                               const float* __restrict__ bg1, const float* __restrict__ bg2,
                                               ushort_t* __restrict__ Gout) {
    __shared__ ushort_t A_lds[64 * 68];    //  8,704 B
    __shared__ ushort_t U1[64 * 264];      // 33,792 B : Xs (stride 72) then D1 row-major (stride 264)
    __shared__ ushort_t U2[256 * 68];      // 34,816 B : P1t then P2t
    __shared__ ushort_t Ws[2][256 * 32];   // 32,768 B : unpadded W chunk dbuf (gload_lds dest)
    int g = blockIdx.x >> 7, t = blockIdx.x & 127;
    int tid = threadIdx.x;
    int l = tid & 63, w = tid >> 6;
    int lrow = l & 15, lko = (l >> 4) * 8, lq = l >> 4;

    // per-lane source row/slot for W staging: dest row = w*32 + i*16 + (l>>2), slot = l&3
    int wrow0 = w * 32 + (l >> 2);
    int wslot = (l & 3) * 8;

    // stage A
    {
        int row = tid >> 3, off = (tid & 7) * 8;
        *reinterpret_cast<bf16x8*>(&A_lds[row * 68 + off]) =
            *reinterpret_cast<const bf16x8*>(&AHb[g * 4096 + row * 64 + off]);
    }
    // stage Xs with BN1 affine + ReLU + PE
    {
        int node = tid >> 3, ch0 = (tid & 7) * 8;
        bf16x8 cv = *reinterpret_cast<const bf16x8*>(&Cb[((size_t)(g * 64 + node) * T + t) * 64 + ch0]);
        const float inv = 1.f / (float)(N_NODES * T);
        bf16x8 xv;
        #pragma unroll
        for (int j = 0; j < 8; ++j) {
            int c = ch0 + j;
            float mean = S[c] * inv;
            float var  = S[64 + c] * inv - mean * mean;
            float sc = g1[c] * rsqrtf(var + EPS);
            float sh = b1[c] - mean * sc;
            float v = fmaxf(bf2f((ushort_t)cv[j]) * sc + sh, 0.f) + PE[(g * 64 + node) * 64 + c];
            xv[j] = (short)f2bf(v);
        }
        *reinterpret_cast<bf16x8*>(&U1[node * 72 + ch0]) = xv;
    }

    auto issueW1 = [&](int kc, int buf) {
        #pragma unroll
        for (int i = 0; i < 2; ++i)
            gload16(&W1T[(size_t)(wrow0 + i * 16) * 64 + kc * 32 + wslot],
                    &Ws[buf][w * 1024 + i * 512]);
    };
    auto issueW2 = [&](int kc, int buf) {
        #pragma unroll
        for (int i = 0; i < 2; ++i)
            gload16(&W2T[(size_t)(wrow0 + i * 16) * 256 + kc * 32 + wslot],
                    &Ws[buf][w * 1024 + i * 512]);
    };

    issueW1(0, 0);
    __syncthreads();

    // ---- phase 1: P1 = X @ W1^T (K=64) ----
    f32x4 p[4][2];
    #pragma unroll
    for (int i = 0; i < 4; ++i)
        #pragma unroll
        for (int j = 0; j < 2; ++j) p[i][j] = (f32x4){0.f, 0.f, 0.f, 0.f};
    issueW1(1, 1);
    {
        bf16x8 a[4], b[2];
        #pragma unroll
        for (int mi = 0; mi < 4; ++mi)
            a[mi] = *reinterpret_cast<const bf16x8*>(&U1[(mi * 16 + lrow) * 72 + lko]);
        #pragma unroll
        for (int ni = 0; ni < 2; ++ni)
            b[ni] = *reinterpret_cast<const bf16x8*>(&Ws[0][(w * 32 + ni * 16 + lrow) * 32 + lko]);
        #pragma unroll
        for (int mi = 0; mi < 4; ++mi)
            #pragma unroll
            for (int ni = 0; ni < 2; ++ni)
                p[mi][ni] = __builtin_amdgcn_mfma_f32_16x16x32_bf16(a[mi], b[ni], p[mi][ni], 0, 0, 0);
    }
    __syncthreads();
    {
        bf16x8 a[4], b[2];
        #pragma unroll
        for (int mi = 0; mi < 4; ++mi)
            a[mi] = *reinterpret_cast<const bf16x8*>(&U1[(mi * 16 + lrow) * 72 + 32 + lko]);
        #pragma unroll
        for (int ni = 0; ni < 2; ++ni)
            b[ni] = *reinterpret_cast<const bf16x8*>(&Ws[1][(w * 32 + ni * 16 + lrow) * 32 + lko]);
        #pragma unroll
        for (int mi = 0; mi < 4; ++mi)
            #pragma unroll
            for (int ni = 0; ni < 2; ++ni)
                p[mi][ni] = __builtin_amdgcn_mfma_f32_16x16x32_bf16(a[mi], b[ni], p[mi][ni], 0, 0, 0);
    }
    // write P1t [col][node] ; prefetch W2 chunk 0 into buf0 (free since phase-1 kc0 barrier)
    #pragma unroll
    for (int mi = 0; mi < 4; ++mi) {
        int node0 = mi * 16 + lq * 4;
        #pragma unroll
        for (int ni = 0; ni < 2; ++ni) {
            int col = w * 32 + ni * 16 + lrow;
            unsigned u0 = (unsigned)f2bf(p[mi][ni][0]) | ((unsigned)f2bf(p[mi][ni][1]) << 16);
            unsigned u1 = (unsigned)f2bf(p[mi][ni][2]) | ((unsigned)f2bf(p[mi][ni][3]) << 16);
            *reinterpret_cast<unsigned*>(&U2[col * 68 + node0]) = u0;
            *reinterpret_cast<unsigned*>(&U2[col * 68 + node0 + 2]) = u1;
        }
    }
    issueW2(0, 0);
    __syncthreads();

    // ---- phase 2: D1 = A @ P1t + bg1, ReLU -> D1 row-major in U1 ----
    f32x4 d[4][2];
    #pragma unroll
    for (int i = 0; i < 4; ++i)
        #pragma unroll
        for (int j = 0; j < 2; ++j) d[i][j] = (f32x4){0.f, 0.f, 0.f, 0.f};
    #pragma unroll
    for (int kc = 0; kc < 2; ++kc) {
        bf16x8 a2[4], b2[2];
        #pragma unroll
        for (int mi = 0; mi < 4; ++mi)
            a2[mi] = *reinterpret_cast<const bf16x8*>(&A_lds[(mi * 16 + lrow) * 68 + kc * 32 + lko]);
        #pragma unroll
        for (int ni = 0; ni < 2; ++ni)
            b2[ni] = *reinterpret_cast<const bf16x8*>(&U2[(w * 32 + ni * 16 + lrow) * 68 + kc * 32 + lko]);
        #pragma unroll
        for (int mi = 0; mi < 4; ++mi)
            #pragma unroll
            for (int ni = 0; ni < 2; ++ni)
                d[mi][ni] = __builtin_amdgcn_mfma_f32_16x16x32_bf16(a2[mi], b2[ni], d[mi][ni], 0, 0, 0);
    }
    #pragma unroll
    for (int ni = 0; ni < 2; ++ni) {
        int col = w * 32 + ni * 16 + lrow;
        float bs = bg1[col];
        #pragma unroll
        for (int mi = 0; mi < 4; ++mi) {
            #pragma unroll
            for (int r = 0; r < 4; ++r) {
                int node = mi * 16 + lq * 4 + r;
                U1[node * 264 + col] = f2bf(fmaxf(d[mi][ni][r] + bs, 0.f));
            }
        }
    }
    __syncthreads(); // D1rm visible; W2 chunk0 landed

    // ---- phase 3: P2 = D1 @ W2^T (K=256), W2 gload_lds dbuf ----
    f32x4 q[4][2];
    #pragma unroll
    for (int i = 0; i < 4; ++i)
        #pragma unroll
        for (int j = 0; j < 2; ++j) q[i][j] = (f32x4){0.f, 0.f, 0.f, 0.f};
    for (int kc = 0; kc < 8; ++kc) {
        if (kc < 7) issueW2(kc + 1, (kc + 1) & 1);
        bf16x8 a[4], b[2];
        #pragma unroll
        for (int mi = 0; mi < 4; ++mi)
            a[mi] = *reinterpret_cast<const bf16x8*>(&U1[(mi * 16 + lrow) * 264 + kc * 32 + lko]);
        #pragma unroll
        for (int ni = 0; ni < 2; ++ni)
            b[ni] = *reinterpret_cast<const bf16x8*>(&Ws[kc & 1][(w * 32 + ni * 16 + lrow) * 32 + lko]);
        #pragma unroll
        for (int mi = 0; mi < 4; ++mi)
            #pragma unroll
            for (int ni = 0; ni < 2; ++ni)
                q[mi][ni] = __builtin_amdgcn_mfma_f32_16x16x32_bf16(a[mi], b[ni], q[mi][ni], 0, 0, 0);
        __syncthreads();
    }
    // write P2t into U2
    #pragma unroll
    for (int mi = 0; mi < 4; ++mi) {
        int node0 = mi * 16 + lq * 4;
        #pragma unroll
        for (int ni = 0; ni < 2; ++ni) {
            int col = w * 32 + ni * 16 + lrow;
            unsigned u0 = (unsigned)f2bf(q[mi][ni][0]) | ((unsigned)f2bf(q[mi][ni][1]) << 16);
            unsigned u1 = (unsigned)f2bf(q[mi][ni][2]) | ((unsigned)f2bf(q[mi][ni][3]) << 16);
            *reinterpret_cast<unsigned*>(&U2[col * 68 + node0]) = u0;
            *reinterpret_cast<unsigned*>(&U2[col * 68 + node0 + 2]) = u1;
        }
    }
    __syncthreads();

    // ---- phase 4: D2 = A @ P2t + bg2, ReLU -> global ----
    f32x4 d2[4][2];
    #pragma unroll
    for (int i = 0; i < 4; ++i)
        #pragma unroll
        for (int j = 0; j < 2; ++j) d2[i][j] = (f32x4){0.f, 0.f, 0.f, 0.f};
    #pragma unroll
    for (int kc = 0; kc < 2; ++kc) {
        bf16x8 a2[4], b2[2];
        #pragma unroll
        for (int mi = 0; mi < 4; ++mi)
            a2[mi] = *reinterpret_cast<const bf16x8*>(&A_lds[(mi * 16 + lrow) * 68 + kc * 32 + lko]);
        #pragma unroll
        for (int ni = 0; ni < 2; ++ni)
            b2[ni] = *reinterpret_cast<const bf16x8*>(&U2[(w * 32 + ni * 16 + lrow) * 68 + kc * 32 + lko]);
        #pragma unroll
        for (int mi = 0; mi < 4; ++mi)
            #pragma unroll
            for (int ni = 0; ni < 2; ++ni)
                d2[mi][ni] = __builtin_amdgcn_mfma_f32_16x16x32_bf16(a2[mi], b2[ni], d2[mi][ni], 0, 0, 0);
    }
    #pragma unroll
    for (int ni = 0; ni < 2; ++ni) {
        int col = w * 32 + ni * 16 + lrow;
        float bs = bg2[col];
        #pragma unroll
        for (int mi = 0; mi < 4; ++mi) {
            #pragma unroll
            for (int r = 0; r < 4; ++r) {
                int node = mi * 16 + lq * 4 + r;
                Gout[((size_t)(g * 64 + node) * T + t) * 256 + col] =
                    f2bf(fmaxf(d2[mi][ni][r] + bs, 0.f));
            }
        }
    }
}

// ---------------- conv2: gload_lds W dbuf (XOR-swizzled), fused stats + pooled sums ----------------
__global__ __launch_bounds__(512) void k_conv2_mfma(const ushort_t* __restrict__ H,
                                                    const ushort_t* __restrict__ WT2,
                                                    float* __restrict__ P1S, float* S) {
    __shared__ ushort_t Hs[128 * 136];   // 34,816 B (one cin half)
    __shared__ ushort_t Ws[2][128 * 64]; // 32,768 B unpadded, XOR-swizzled content
    __shared__ float sS1[128];
    __shared__ float sS2[128];
    int n = blockIdx.x;
    int tid = threadIdx.x;
    int l = tid & 63, wid = tid >> 6;
    int wr = wid >> 1, wc = wid & 1;
    int lrow = l & 15, lko = (l >> 4) * 8, lq = l >> 4;

    if (tid < 128) { sS1[tid] = 0.f; sS2[tid] = 0.f; }

    f32x4 acc[2][4];
    #pragma unroll
    for (int i = 0; i < 2; ++i)
        #pragma unroll
        for (int j = 0; j < 4; ++j) acc[i][j] = (f32x4){0.f, 0.f, 0.f, 0.f};

    // W staging: dest row = wid*16 + i*8 + (l>>3), dest slot = l&7 (16B units)
    // swizzled content: LDS[row][slot] = W[row][slot ^ (row&7)]  -> src slot = (l&7) ^ (l>>3)
    int wrow0 = wid * 16 + (l >> 3);
    int wslot = ((l & 7) ^ (l >> 3)) * 8;

    auto stageHs = [&](int half) {
        #pragma unroll
        for (int it = 0; it < 4; ++it) {
            int lin = it * 512 + tid;
            int row = lin >> 4, off = (lin & 15) * 8;
            *reinterpret_cast<bf16x8*>(&Hs[row * 136 + off]) =
                *reinterpret_cast<const bf16x8*>(&H[((size_t)n * T + row) * 256 + half * 128 + off]);
        }
    };
    auto issueW = [&](int c) {
        int half = c / 14, tk = c % 14;
        int koff = (tk >> 1) * 256 + half * 128 + (tk & 1) * 64;
        int buf = c & 1;
        #pragma unroll
        for (int i = 0; i < 2; ++i)
            gload16(&WT2[(size_t)(wrow0 + i * 8) * 1792 + koff + wslot],
                    &Ws[buf][wid * 1024 + i * 512]);
    };

    stageHs(0);
    issueW(0);
    __syncthreads();

    for (int c = 0; c < 28; ++c) {
        if (c == 14) { stageHs(1); __syncthreads(); }
        if (c < 27) issueW(c + 1);
        int tk = c % 14;
        int tap = tk >> 1, sub = (tk & 1) * 64;
        int cur = c & 1;
        bf16x8 a[2][2], b[4][2];
        #pragma unroll
        for (int mi = 0; mi < 2; ++mi) {
            int row = wr * 32 + mi * 16 + lrow + tap;
            if (row > 127) row = 127; // feeds only discarded outputs
            #pragma unroll
            for (int ks = 0; ks < 2; ++ks)
                a[mi][ks] = *reinterpret_cast<const bf16x8*>(&Hs[row * 136 + sub + ks * 32 + lko]);
        }
        #pragma unroll
        for (int ni = 0; ni < 4; ++ni) {
            int row = wc * 64 + ni * 16 + lrow;
            #pragma unroll
            for (int ks = 0; ks < 2; ++ks) {
                int slot = (ks * 4 + lq) ^ (lrow & 7);
                b[ni][ks] = *reinterpret_cast<const bf16x8*>(&Ws[cur][row * 64 + slot * 8]);
            }
        }
        #pragma unroll
        for (int ks = 0; ks < 2; ++ks)
            #pragma unroll
            for (int mi = 0; mi < 2; ++mi)
                #pragma unroll
                for (int ni = 0; ni < 4; ++ni)
                    acc[mi][ni] = __builtin_amdgcn_mfma_f32_16x16x32_bf16(a[mi][ks], b[ni][ks], acc[mi][ni], 0, 0, 0);
        __syncthreads();
    }
    // epilogue: per-channel stats over t<122 and pooled sums
    #pragma unroll
    for (int ni = 0; ni < 4; ++ni) {
        int col = wc * 64 + ni * 16 + lrow;
        float s1 = 0.f, s2 = 0.f;
        #pragma unroll
        for (int mi = 0; mi < 2; ++mi) {
            int t0 = wr * 32 + mi * 16 + lq * 4;
            float psum = 0.f;
            #pragma unroll
            for (int r = 0; r < 4; ++r) {
                float v = acc[mi][ni][r];
                if (t0 + r < 122) { s1 += v; s2 += v * v; }
                psum += v;
            }
            if (t0 <= 116) P1S[((size_t)n * 30 + (t0 >> 2)) * 128 + col] = psum;
        }
        atomicAdd(&sS1[col], s1);
        atomicAdd(&sS2[col], s2);
    }
    __syncthreads();
    if (tid < 128) {
        atomicAdd(&S[128 + tid], sS1[tid]);
        atomicAdd(&S[256 + tid], sS2[tid]);
    }
}

// ---------------- BN2 affine on pooled sums + ReLU + graph-mean (fused) ----------------
__global__ void k_bn2gp(const float* __restrict__ P1S, const float* __restrict__ S,
                        const float* __restrict__ g2, const float* __restrict__ b2,
                        float* __restrict__ GP) {
    int n = blockIdx.x;
    int tp0 = blockIdx.y * 5;
    int c = threadIdx.x; // 128
    int b = n >> 6;
    const float inv = 1.f / (float)(N_NODES * 122);
    float mean = S[128 + c] * inv;
    float var  = S[256 + c] * inv - mean * mean;
    float sc = g2[c] * rsqrtf(var + EPS);
    float sh = b2[c] - mean * sc;
    for (int tp = tp0; tp < tp0 + 5; ++tp) {
        float psum = P1S[((size_t)n * 30 + tp) * 128 + c];
        float v = fmaxf(psum * 0.25f * sc + sh, 0.f);
        atomicAdd(&GP[((size_t)b * 30 + tp) * 128 + c], v * (1.f / 64.f));
    }
}

// ---------------- conv3 (128->128, k=3, VALID) + BN3 stats ----------------
__global__ void k_conv3(const float* __restrict__ GP, const float* __restrict__ W3,
                        float* __restrict__ C3, float* S) {
    int b = blockIdx.x / 28, t = blockIdx.x % 28;
    int c = threadIdx.x; // 128
    __shared__ float gs[3 * 128];
    for (int i = c; i < 384; i += 128) gs[i] = GP[((size_t)b * 30 + t) * 128 + i];
    __syncthreads();
    float acc = 0.f;
    for (int i = 0; i < 384; ++i) acc += gs[i] * W3[i * 128 + c];
    C3[((size_t)b * 28 + t) * 128 + c] = acc;
    atomicAdd(&S[384 + c], acc);
    atomicAdd(&S[512 + c], acc * acc);
}

// ---------------- BN3 apply + avgpool4 + ReLU ----------------
__global__ void k_bn3pool(const float* __restrict__ C3, const float* __restrict__ S,
                          const float* __restrict__ g3, const float* __restrict__ b3,
                          float* __restrict__ P2) {
    int b = blockIdx.x;  // 8
    int c = threadIdx.x; // 128
    const float inv = 1.f / (float)(NG * 28);
    float mean = S[384 + c] * inv;
    float var  = S[512 + c] * inv - mean * mean;
    float sc = g3[c] * rsqrtf(var + EPS);
    float sh = b3[c] - mean * sc;
    for (int tp = 0; tp < 7; ++tp) {
        float s = 0.f;
        #pragma unroll
        for (int i = 0; i < 4; ++i) s += C3[((size_t)b * 28 + tp * 4 + i) * 128 + c];
        P2[((size_t)b * 7 + tp) * 128 + c] = fmaxf(s * 0.25f * sc + sh, 0.f);
    }
}

// ---------------- final linear + log_softmax ----------------
__global__ void k_final(const float* __restrict__ P2, const float* __restrict__ Wd,
                        const float* __restrict__ bd, float* __restrict__ out) {
    int tid = threadIdx.x; // 32
    int b = tid >> 2, j = tid & 3;
    float acc = bd[j];
    for (int i = 0; i < 896; ++i) acc += P2[b * 896 + i] * Wd[i * 4 + j];
    float m = acc;
    m = fmaxf(m, __shfl_xor(m, 1, 4));
    m = fmaxf(m, __shfl_xor(m, 2, 4));
    float e = expf(acc - m);
    float s = e;
    s += __shfl_xor(s, 1, 4);
    s += __shfl_xor(s, 2, 4);
    out[tid] = acc - m - logf(s);
}

extern "C" void kernel_launch(void* const* d_in, const int* in_sizes, int n_in,
                              void* d_out, int out_size, void* d_ws, size_t ws_size,
                              hipStream_t stream) {
    const float* x   = (const float*)d_in[0];
    const float* pos = (const float*)d_in[1];
    const int*   ei  = (const int*)d_in[2];
    const float* W1  = (const float*)d_in[4];
    const float* g1  = (const float*)d_in[5];
    const float* b1  = (const float*)d_in[6];
    const float* Wp1 = (const float*)d_in[7];
    const float* bp1 = (const float*)d_in[8];
    const float* Wp2 = (const float*)d_in[9];
    const float* bp2 = (const float*)d_in[10];
    const float* Wg1 = (const float*)d_in[11];
    const float* bg1 = (const float*)d_in[12];
    const float* Wg2 = (const float*)d_in[13];
    const float* bg2 = (const float*)d_in[14];
    const float* W2  = (const float*)d_in[15];
    const float* g2  = (const float*)d_in[16];
    const float* b2  = (const float*)d_in[17];
    const float* W3  = (const float*)d_in[18];
    const float* g3  = (const float*)d_in[19];
    const float* b3  = (const float*)d_in[20];
    const float* Wd  = (const float*)d_in[21];
    const float* bd  = (const float*)d_in[22];
    float* out = (float*)d_out;

    float* ws = (float*)d_ws;
    float* P1S  = ws;                  //  1,966,080 f : conv2 pooled sums
    float* PE   = P1S + 1966080;       //     32,768 f
    float* GPb  = PE + 32768;          //     30,720 f
    float* C3   = GPb + 30720;         //     28,672 f
    float* P2   = C3 + 28672;          //      7,168 f
    float* S    = P2 + 7168;           //        640 f
    float* AH   = S + 640;             //     32,768 f
    ushort_t* Cb   = (ushort_t*)(AH + 32768); //  4,194,304 us : conv1 out bf16
    ushort_t* Gout = Cb + 4194304;            // 16,777,216 us : GCN stack out
    ushort_t* Wg1T = Gout + 16777216;         //     16,384 us
    ushort_t* Wg2T = Wg1T + 16384;            //     65,536 us
    ushort_t* WT2  = Wg2T + 65536;            //    229,376 us
    ushort_t* AHb  = WT2 + 229376;            //     32,768 us
    int* DEG = (int*)(AHb + 32768);           //        512 i
    const int* srcv = ei;
    const int* dstv = ei + E_EDGES;

    hipLaunchKernelGGL(k_setup,  dim3(896), dim3(256), 0, stream, Wg1, Wg2, W2, Wg1T, Wg2T, WT2, S, DEG, AH, GPb);
    hipLaunchKernelGGL(k_count,  dim3(16),  dim3(256), 0, stream, dstv, DEG);
    hipLaunchKernelGGL(k_abuild, dim3(16),  dim3(256), 0, stream, srcv, dstv, DEG, AH);
    hipLaunchKernelGGL(k_cvta,   dim3(128), dim3(256), 0, stream, AH, DEG, AHb);
    hipLaunchKernelGGL(k_pe,     dim3(512), dim3(64),  0, stream, pos, Wp1, bp1, Wp2, bp2, PE);
    hipLaunchKernelGGL(k_conv1,  dim3(512), dim3(256), 0, stream, x, W1, Cb, S);
    hipLaunchKernelGGL(k_gcn12,  dim3(1024), dim3(512), 0, stream, Cb, S, g1, b1, PE, Wg1T, Wg2T, AHb, bg1, bg2, Gout);
    hipLaunchKernelGGL(k_conv2_mfma, dim3(512), dim3(512), 0, stream, Gout, WT2, P1S, S);
    hipLaunchKernelGGL(k_bn2gp,  dim3(512, 6), dim3(128), 0, stream, P1S, S, g2, b2, GPb);
    hipLaunchKernelGGL(k_conv3,  dim3(224), dim3(128), 0, stream, GPb, W3, C3, S);
    hipLaunchKernelGGL(k_bn3pool, dim3(8),  dim3(128), 0, stream, C3, S, g3, b3, P2);
    hipLaunchKernelGGL(k_final,  dim3(1),   dim3(32),  0, stream, P2, Wd, bd, out);
}

// Round 11
// 261.288 us; speedup vs baseline: 4.6134x; 1.0148x over previous
//
#include <hip/hip_runtime.h>
#include <math.h>

#define N_NODES 512
#define T 128
#define E_EDGES 4096
#define EPS 1e-5f
#define NG 8

typedef unsigned short ushort_t;
typedef short bf16x8 __attribute__((ext_vector_type(8)));
typedef float f32x4 __attribute__((ext_vector_type(4)));

__device__ __forceinline__ ushort_t f2bf(float f) {
    union { float f; unsigned int u; } v; v.f = f;
    unsigned int r = v.u + 0x7fffu + ((v.u >> 16) & 1u);
    return (ushort_t)(r >> 16);
}
__device__ __forceinline__ float bf2f(ushort_t h) {
    union { unsigned int u; float f; } v; v.u = ((unsigned int)h) << 16;
    return v.f;
}
// async global->LDS, 16B per lane, dest = ldsbase + lane*16
__device__ __forceinline__ void gload16(const ushort_t* g, ushort_t* l) {
    __builtin_amdgcn_global_load_lds(
        (const __attribute__((address_space(1))) void*)g,
        (__attribute__((address_space(3))) void*)l, 16, 0, 0);
}

// ---------------- setup: zeroing + all weight convert/transpose ----------------
__global__ void k_setup(const float* __restrict__ Wg1, const float* __restrict__ Wg2,
                        const float* __restrict__ W2,
                        ushort_t* __restrict__ Wg1T, ushort_t* __restrict__ Wg2T,
                        ushort_t* __restrict__ WT2,
                        float* S, int* DEG, float* AH, float* GP) {
    int gtid = blockIdx.x * 256 + threadIdx.x;
    int stride = gridDim.x * 256;
    for (int i = gtid; i < 229376; i += stride) { int n = i / 1792, k = i % 1792; WT2[i] = f2bf(W2[k * 128 + n]); }
    for (int i = gtid; i < 65536; i += stride)  { int n = i >> 8, k = i & 255;    Wg2T[i] = f2bf(Wg2[k * 256 + n]); }
    for (int i = gtid; i < 16384; i += stride)  { int n = i >> 6, k = i & 63;     Wg1T[i] = f2bf(Wg1[k * 256 + n]); }
    for (int i = gtid; i < 32768; i += stride) AH[i] = 0.f;
    for (int i = gtid; i < 30720; i += stride) GP[i] = 0.f;
    for (int i = gtid; i < 640; i += stride) S[i] = 0.f;
    for (int i = gtid; i < 512; i += stride) DEG[i] = 0;
}

__global__ void k_count(const int* __restrict__ dst, int* DEG) {
    int e = blockIdx.x * 256 + threadIdx.x;
    if (e < E_EDGES) atomicAdd(&DEG[dst[e]], 1);
}

__global__ void k_abuild(const int* __restrict__ src, const int* __restrict__ dst,
                         const int* __restrict__ DEG, float* AH) {
    int e = blockIdx.x * 256 + threadIdx.x;
    if (e < E_EDGES) {
        int d = dst[e], s = src[e];
        float norm = rsqrtf((float)DEG[d] + 1.f) * rsqrtf((float)DEG[s] + 1.f);
        atomicAdd(&AH[(d >> 6) * 4096 + (d & 63) * 64 + (s & 63)], norm);
    }
}

__global__ void k_cvta(const float* __restrict__ AH, const int* __restrict__ DEG,
                       ushort_t* __restrict__ AHb) {
    int i = blockIdx.x * 256 + threadIdx.x;
    if (i < 32768) {
        int g = i >> 12, r = (i >> 6) & 63, c = i & 63;
        float v = AH[i];
        if (r == c) v += 1.f / ((float)DEG[g * 64 + r] + 1.f);
        AHb[i] = f2bf(v);
    }
}

// ---------------- position encoder MLP ----------------
__global__ void k_pe(const float* __restrict__ pos, const float* __restrict__ Wp1,
                     const float* __restrict__ bp1, const float* __restrict__ Wp2,
                     const float* __restrict__ bp2, float* __restrict__ PE) {
    int n = blockIdx.x;
    int c = threadIdx.x; // 64
    __shared__ float hid[64];
    float p0 = pos[n * 3], p1 = pos[n * 3 + 1], p2 = pos[n * 3 + 2];
    float h = p0 * Wp1[c] + p1 * Wp1[64 + c] + p2 * Wp1[128 + c] + bp1[c];
    hid[c] = fmaxf(h, 0.f);
    __syncthreads();
    float acc = bp2[c];
    #pragma unroll
    for (int j = 0; j < 64; ++j) acc += hid[j] * Wp2[j * 64 + c];
    PE[n * 64 + c] = acc;
}

// ---------------- conv1 (1->64, k=7, SAME) + BN stats, bf16 out ----------------
__global__ void k_conv1(const float* __restrict__ x, const float* __restrict__ W1,
                        ushort_t* __restrict__ Cb, float* S) {
    int n = blockIdx.x;
    int tid = threadIdx.x; // 256
    int c = tid & 63, tg = tid >> 6;
    __shared__ float xs[134];
    __shared__ float ws[448];
    __shared__ float red[256];
    for (int i = tid; i < 448; i += 256) ws[i] = W1[i];
    for (int i = tid; i < 134; i += 256) {
        int t = i - 3;
        xs[i] = (t >= 0 && t < T) ? x[n * T + t] : 0.f;
    }
    __syncthreads();
    float s1 = 0.f, s2 = 0.f;
    for (int t = tg; t < T; t += 4) {
        float acc = 0.f;
        #pragma unroll
        for (int k = 0; k < 7; ++k) acc += xs[t + k] * ws[k * 64 + c];
        Cb[(n * T + t) * 64 + c] = f2bf(acc);
        s1 += acc; s2 += acc * acc;
    }
    red[tid] = s1; __syncthreads();
    if (tg == 0) { float v = red[c] + red[64 + c] + red[128 + c] + red[192 + c]; atomicAdd(&S[c], v); }
    __syncthreads();
    red[tid] = s2; __syncthreads();
    if (tg == 0) { float v = red[c] + red[64 + c] + red[128 + c] + red[192 + c]; atomicAdd(&S[64 + c], v); }
}

// ---------------- fused 2-layer GCN per (graph, t): counted-vmcnt W2 pipeline ----------------
__global__ __launch_bounds__(512) void k_gcn12(const ushort_t* __restrict__ Cb,
                                               const float* __restrict__ S,
                                               const float* __restrict__ g1, const float* __restrict__ b1,
                                               const float* __restrict__ PE,
                                               const ushort_t* __restrict__ W1T,
                                               const ushort_t* __restrict__ W2T,
                                               const ushort_t* __restrict__ AHb,
                                               const float* __restrict__ bg1, const float* __restrict__ bg2,
                                               ushort_t* __restrict__ Gout) {
    __shared__ ushort_t A_lds[64 * 68];    //  8,704 B
    __shared__ ushort_t U1[64 * 264];      // 33,792 B : Xs (stride 72) then D1 row-major (stride 264)
    __shared__ ushort_t U2[256 * 68];      // 34,816 B : P1t then P2t
    __shared__ ushort_t Ws[3][256 * 32];   // 49,152 B : unpadded W chunk, 3-deep
    int g = blockIdx.x >> 7, t = blockIdx.x & 127;
    int tid = threadIdx.x;
    int l = tid & 63, w = tid >> 6;
    int lrow = l & 15, lko = (l >> 4) * 8, lq = l >> 4;

    // per-lane source row/slot for W staging: dest row = w*32 + i*16 + (l>>2), slot = l&3
    int wrow0 = w * 32 + (l >> 2);
    int wslot = (l & 3) * 8;

    // stage A
    {
        int row = tid >> 3, off = (tid & 7) * 8;
        *reinterpret_cast<bf16x8*>(&A_lds[row * 68 + off]) =
            *reinterpret_cast<const bf16x8*>(&AHb[g * 4096 + row * 64 + off]);
    }
    // stage Xs with BN1 affine + ReLU + PE
    {
        int node = tid >> 3, ch0 = (tid & 7) * 8;
        bf16x8 cv = *reinterpret_cast<const bf16x8*>(&Cb[((size_t)(g * 64 + node) * T + t) * 64 + ch0]);
        const float inv = 1.f / (float)(N_NODES * T);
        bf16x8 xv;
        #pragma unroll
        for (int j = 0; j < 8; ++j) {
            int c = ch0 + j;
            float mean = S[c] * inv;
            float var  = S[64 + c] * inv - mean * mean;
            float sc = g1[c] * rsqrtf(var + EPS);
            float sh = b1[c] - mean * sc;
            float v = fmaxf(bf2f((ushort_t)cv[j]) * sc + sh, 0.f) + PE[(g * 64 + node) * 64 + c];
            xv[j] = (short)f2bf(v);
        }
        *reinterpret_cast<bf16x8*>(&U1[node * 72 + ch0]) = xv;
    }

    auto issueW1 = [&](int kc, int buf) {
        #pragma unroll
        for (int i = 0; i < 2; ++i)
            gload16(&W1T[(size_t)(wrow0 + i * 16) * 64 + kc * 32 + wslot],
                    &Ws[buf][w * 1024 + i * 512]);
    };
    auto issueW2 = [&](int kc, int buf) {
        #pragma unroll
        for (int i = 0; i < 2; ++i)
            gload16(&W2T[(size_t)(wrow0 + i * 16) * 256 + kc * 32 + wslot],
                    &Ws[buf][w * 1024 + i * 512]);
    };

    issueW1(0, 0);
    __syncthreads();

    // ---- phase 1: P1 = X @ W1^T (K=64) ----
    f32x4 p[4][2];
    #pragma unroll
    for (int i = 0; i < 4; ++i)
        #pragma unroll
        for (int j = 0; j < 2; ++j) p[i][j] = (f32x4){0.f, 0.f, 0.f, 0.f};
    issueW1(1, 1);
    {
        bf16x8 a[4], b[2];
        #pragma unroll
        for (int mi = 0; mi < 4; ++mi)
            a[mi] = *reinterpret_cast<const bf16x8*>(&U1[(mi * 16 + lrow) * 72 + lko]);
        #pragma unroll
        for (int ni = 0; ni < 2; ++ni)
            b[ni] = *reinterpret_cast<const bf16x8*>(&Ws[0][(w * 32 + ni * 16 + lrow) * 32 + lko]);
        #pragma unroll
        for (int mi = 0; mi < 4; ++mi)
            #pragma unroll
            for (int ni = 0; ni < 2; ++ni)
                p[mi][ni] = __builtin_amdgcn_mfma_f32_16x16x32_bf16(a[mi], b[ni], p[mi][ni], 0, 0, 0);
    }
    __syncthreads();
    {
        bf16x8 a[4], b[2];
        #pragma unroll
        for (int mi = 0; mi < 4; ++mi)
            a[mi] = *reinterpret_cast<const bf16x8*>(&U1[(mi * 16 + lrow) * 72 + 32 + lko]);
        #pragma unroll
        for (int ni = 0; ni < 2; ++ni)
            b[ni] = *reinterpret_cast<const bf16x8*>(&Ws[1][(w * 32 + ni * 16 + lrow) * 32 + lko]);
        #pragma unroll
        for (int mi = 0; mi < 4; ++mi)
            #pragma unroll
            for (int ni = 0; ni < 2; ++ni)
                p[mi][ni] = __builtin_amdgcn_mfma_f32_16x16x32_bf16(a[mi], b[ni], p[mi][ni], 0, 0, 0);
    }
    // write P1t [col][node] ; prefetch W2 chunk 0 into buf0
    #pragma unroll
    for (int mi = 0; mi < 4; ++mi) {
        int node0 = mi * 16 + lq * 4;
        #pragma unroll
        for (int ni = 0; ni < 2; ++ni) {
            int col = w * 32 + ni * 16 + lrow;
            unsigned u0 = (unsigned)f2bf(p[mi][ni][0]) | ((unsigned)f2bf(p[mi][ni][1]) << 16);
            unsigned u1 = (unsigned)f2bf(p[mi][ni][2]) | ((unsigned)f2bf(p[mi][ni][3]) << 16);
            *reinterpret_cast<unsigned*>(&U2[col * 68 + node0]) = u0;
            *reinterpret_cast<unsigned*>(&U2[col * 68 + node0 + 2]) = u1;
        }
    }
    issueW2(0, 0);
    __syncthreads();

    // ---- phase 2: D1 = A @ P1t + bg1, ReLU -> D1 row-major in U1 ----
    f32x4 d[4][2];
    #pragma unroll
    for (int i = 0; i < 4; ++i)
        #pragma unroll
        for (int j = 0; j < 2; ++j) d[i][j] = (f32x4){0.f, 0.f, 0.f, 0.f};
    #pragma unroll
    for (int kc = 0; kc < 2; ++kc) {
        bf16x8 a2[4], b2[2];
        #pragma unroll
        for (int mi = 0; mi < 4; ++mi)
            a2[mi] = *reinterpret_cast<const bf16x8*>(&A_lds[(mi * 16 + lrow) * 68 + kc * 32 + lko]);
        #pragma unroll
        for (int ni = 0; ni < 2; ++ni)
            b2[ni] = *reinterpret_cast<const bf16x8*>(&U2[(w * 32 + ni * 16 + lrow) * 68 + kc * 32 + lko]);
        #pragma unroll
        for (int mi = 0; mi < 4; ++mi)
            #pragma unroll
            for (int ni = 0; ni < 2; ++ni)
                d[mi][ni] = __builtin_amdgcn_mfma_f32_16x16x32_bf16(a2[mi], b2[ni], d[mi][ni], 0, 0, 0);
    }
    #pragma unroll
    for (int ni = 0; ni < 2; ++ni) {
        int col = w * 32 + ni * 16 + lrow;
        float bs = bg1[col];
        #pragma unroll
        for (int mi = 0; mi < 4; ++mi) {
            #pragma unroll
            for (int r = 0; r < 4; ++r) {
                int node = mi * 16 + lq * 4 + r;
                U1[node * 264 + col] = f2bf(fmaxf(d[mi][ni][r] + bs, 0.f));
            }
        }
    }
    __syncthreads(); // D1rm visible; W2 chunk0 landed (drained here)

    // ---- phase 3: P2 = D1 @ W2^T (K=256), 3-deep counted-vmcnt W2 pipeline ----
    f32x4 q[4][2];
    #pragma unroll
    for (int i = 0; i < 4; ++i)
        #pragma unroll
        for (int j = 0; j < 2; ++j) q[i][j] = (f32x4){0.f, 0.f, 0.f, 0.f};
    issueW2(1, 1);
    for (int kc = 0; kc < 8; ++kc) {
        if (kc > 0) {
            if (kc < 7) asm volatile("s_waitcnt vmcnt(2) lgkmcnt(0)" ::: "memory");
            else        asm volatile("s_waitcnt vmcnt(0) lgkmcnt(0)" ::: "memory");
            __builtin_amdgcn_sched_barrier(0);
            __builtin_amdgcn_s_barrier();
            __builtin_amdgcn_sched_barrier(0);
        }
        if (kc + 2 < 8) issueW2(kc + 2, (kc + 2) % 3);
        bf16x8 a[4], b[2];
        #pragma unroll
        for (int mi = 0; mi < 4; ++mi)
            a[mi] = *reinterpret_cast<const bf16x8*>(&U1[(mi * 16 + lrow) * 264 + kc * 32 + lko]);
        #pragma unroll
        for (int ni = 0; ni < 2; ++ni)
            b[ni] = *reinterpret_cast<const bf16x8*>(&Ws[kc % 3][(w * 32 + ni * 16 + lrow) * 32 + lko]);
        #pragma unroll
        for (int mi = 0; mi < 4; ++mi)
            #pragma unroll
            for (int ni = 0; ni < 2; ++ni)
                q[mi][ni] = __builtin_amdgcn_mfma_f32_16x16x32_bf16(a[mi], b[ni], q[mi][ni], 0, 0, 0);
    }
    // write P2t into U2 (safe: U2 unused in phase 3)
    #pragma unroll
    for (int mi = 0; mi < 4; ++mi) {
        int node0 = mi * 16 + lq * 4;
        #pragma unroll
        for (int ni = 0; ni < 2; ++ni) {
            int col = w * 32 + ni * 16 + lrow;
            unsigned u0 = (unsigned)f2bf(q[mi][ni][0]) | ((unsigned)f2bf(q[mi][ni][1]) << 16);
            unsigned u1 = (unsigned)f2bf(q[mi][ni][2]) | ((unsigned)f2bf(q[mi][ni][3]) << 16);
            *reinterpret_cast<unsigned*>(&U2[col * 68 + node0]) = u0;
            *reinterpret_cast<unsigned*>(&U2[col * 68 + node0 + 2]) = u1;
        }
    }
    __syncthreads();

    // ---- phase 4: D2 = A @ P2t + bg2, ReLU -> global ----
    f32x4 d2[4][2];
    #pragma unroll
    for (int i = 0; i < 4; ++i)
        #pragma unroll
        for (int j = 0; j < 2; ++j) d2[i][j] = (f32x4){0.f, 0.f, 0.f, 0.f};
    #pragma unroll
    for (int kc = 0; kc < 2; ++kc) {
        bf16x8 a2[4], b2[2];
        #pragma unroll
        for (int mi = 0; mi < 4; ++mi)
            a2[mi] = *reinterpret_cast<const bf16x8*>(&A_lds[(mi * 16 + lrow) * 68 + kc * 32 + lko]);
        #pragma unroll
        for (int ni = 0; ni < 2; ++ni)
            b2[ni] = *reinterpret_cast<const bf16x8*>(&U2[(w * 32 + ni * 16 + lrow) * 68 + kc * 32 + lko]);
        #pragma unroll
        for (int mi = 0; mi < 4; ++mi)
            #pragma unroll
            for (int ni = 0; ni < 2; ++ni)
                d2[mi][ni] = __builtin_amdgcn_mfma_f32_16x16x32_bf16(a2[mi], b2[ni], d2[mi][ni], 0, 0, 0);
    }
    #pragma unroll
    for (int ni = 0; ni < 2; ++ni) {
        int col = w * 32 + ni * 16 + lrow;
        float bs = bg2[col];
        #pragma unroll
        for (int mi = 0; mi < 4; ++mi) {
            #pragma unroll
            for (int r = 0; r < 4; ++r) {
                int node = mi * 16 + lq * 4 + r;
                Gout[((size_t)(g * 64 + node) * T + t) * 256 + col] =
                    f2bf(fmaxf(d2[mi][ni][r] + bs, 0.f));
            }
        }
    }
}

// ---------------- conv2: quarter-Hs + 3-deep counted-vmcnt W pipeline, fused stats + pooled sums ----------------
__global__ __launch_bounds__(512) void k_conv2_mfma(const ushort_t* __restrict__ H,
                                                    const ushort_t* __restrict__ WT2,
                                                    float* __restrict__ P1S, float* S) {
    __shared__ ushort_t Hs[128 * 72];    // 18,432 B : one cin quarter (64 ch)
    __shared__ ushort_t Ws[3][128 * 64]; // 49,152 B : unpadded, XOR-swizzled content, 3-deep
    __shared__ float sS1[128];
    __shared__ float sS2[128];
    int n = blockIdx.x;
    int tid = threadIdx.x;
    int l = tid & 63, wid = tid >> 6;
    int wr = wid >> 1, wc = wid & 1;
    int lrow = l & 15, lko = (l >> 4) * 8, lq = l >> 4;

    if (tid < 128) { sS1[tid] = 0.f; sS2[tid] = 0.f; }

    f32x4 acc[2][4];
    #pragma unroll
    for (int i = 0; i < 2; ++i)
        #pragma unroll
        for (int j = 0; j < 4; ++j) acc[i][j] = (f32x4){0.f, 0.f, 0.f, 0.f};

    // W staging: dest row = wid*16 + i*8 + (l>>3), dest slot = l&7 (16B units)
    // swizzled content: LDS[row][slot] = W[row][slot ^ (row&7)]
    int wrow0 = wid * 16 + (l >> 3);
    int wslot = ((l & 7) ^ (l >> 3)) * 8;

    auto stageHs = [&](int q) {
        #pragma unroll
        for (int it = 0; it < 2; ++it) {
            int lin = it * 512 + tid;
            int row = lin >> 3, off = (lin & 7) * 8;
            *reinterpret_cast<bf16x8*>(&Hs[row * 72 + off]) =
                *reinterpret_cast<const bf16x8*>(&H[((size_t)n * T + row) * 256 + q * 64 + off]);
        }
    };
    auto issueW = [&](int c) {
        int q = c / 7, tap = c % 7;
        int koff = tap * 256 + q * 64;
        int buf = c % 3;
        #pragma unroll
        for (int i = 0; i < 2; ++i)
            gload16(&WT2[(size_t)(wrow0 + i * 8) * 1792 + koff + wslot],
                    &Ws[buf][wid * 1024 + i * 512]);
    };

    stageHs(0);
    issueW(0);
    issueW(1);
    __syncthreads(); // one full drain in prologue: Hs + chunks 0,1 landed

    for (int c = 0; c < 28; ++c) {
        if (c > 0) {
            if (c % 7 == 0) {
                // all waves done reading old Hs quarter (end of previous iteration)
                __builtin_amdgcn_s_barrier();
                __builtin_amdgcn_sched_barrier(0);
                stageHs(c / 7);
            }
            if (c < 27) asm volatile("s_waitcnt vmcnt(2) lgkmcnt(0)" ::: "memory");
            else        asm volatile("s_waitcnt vmcnt(0) lgkmcnt(0)" ::: "memory");
            __builtin_amdgcn_sched_barrier(0);
            __builtin_amdgcn_s_barrier();
            __builtin_amdgcn_sched_barrier(0);
        }
        if (c + 2 < 28) issueW(c + 2);
        int tap = c % 7;
        int cur = c % 3;
        bf16x8 a[2][2], b[4][2];
        #pragma unroll
        for (int mi = 0; mi < 2; ++mi) {
            int row = wr * 32 + mi * 16 + lrow + tap;
            if (row > 127) row = 127; // feeds only discarded outputs
            #pragma unroll
            for (int ks = 0; ks < 2; ++ks)
                a[mi][ks] = *reinterpret_cast<const bf16x8*>(&Hs[row * 72 + ks * 32 + lko]);
        }
        #pragma unroll
        for (int ni = 0; ni < 4; ++ni) {
            int row = wc * 64 + ni * 16 + lrow;
            #pragma unroll
            for (int ks = 0; ks < 2; ++ks) {
                int slot = (ks * 4 + lq) ^ (lrow & 7);
                b[ni][ks] = *reinterpret_cast<const bf16x8*>(&Ws[cur][row * 64 + slot * 8]);
            }
        }
        #pragma unroll
        for (int ks = 0; ks < 2; ++ks)
            #pragma unroll
            for (int mi = 0; mi < 2; ++mi)
                #pragma unroll
                for (int ni = 0; ni < 4; ++ni)
                    acc[mi][ni] = __builtin_amdgcn_mfma_f32_16x16x32_bf16(a[mi][ks], b[ni][ks], acc[mi][ni], 0, 0, 0);
    }
    // epilogue: per-channel stats over t<122 and pooled sums
    #pragma unroll
    for (int ni = 0; ni < 4; ++ni) {
        int col = wc * 64 + ni * 16 + lrow;
        float s1 = 0.f, s2 = 0.f;
        #pragma unroll
        for (int mi = 0; mi < 2; ++mi) {
            int t0 = wr * 32 + mi * 16 + lq * 4;
            float psum = 0.f;
            #pragma unroll
            for (int r = 0; r < 4; ++r) {
                float v = acc[mi][ni][r];
                if (t0 + r < 122) { s1 += v; s2 += v * v; }
                psum += v;
            }
            if (t0 <= 116) P1S[((size_t)n * 30 + (t0 >> 2)) * 128 + col] = psum;
        }
        atomicAdd(&sS1[col], s1);
        atomicAdd(&sS2[col], s2);
    }
    __syncthreads();
    if (tid < 128) {
        atomicAdd(&S[128 + tid], sS1[tid]);
        atomicAdd(&S[256 + tid], sS2[tid]);
    }
}

// ---------------- BN2 affine on pooled sums + ReLU + graph-mean (fused) ----------------
__global__ void k_bn2gp(const float* __restrict__ P1S, const float* __restrict__ S,
                        const float* __restrict__ g2, const float* __restrict__ b2,
                        float* __restrict__ GP) {
    int n = blockIdx.x;
    int tp0 = blockIdx.y * 5;
    int c = threadIdx.x; // 128
    int b = n >> 6;
    const float inv = 1.f / (float)(N_NODES * 122);
    float mean = S[128 + c] * inv;
    float var  = S[256 + c] * inv - mean * mean;
    float sc = g2[c] * rsqrtf(var + EPS);
    float sh = b2[c] - mean * sc;
    for (int tp = tp0; tp < tp0 + 5; ++tp) {
        float psum = P1S[((size_t)n * 30 + tp) * 128 + c];
        float v = fmaxf(psum * 0.25f * sc + sh, 0.f);
        atomicAdd(&GP[((size_t)b * 30 + tp) * 128 + c], v * (1.f / 64.f));
    }
}

// ---------------- conv3 (128->128, k=3, VALID) + BN3 stats ----------------
__global__ void k_conv3(const float* __restrict__ GP, const float* __restrict__ W3,
                        float* __restrict__ C3, float* S) {
    int b = blockIdx.x / 28, t = blockIdx.x % 28;
    int c = threadIdx.x; // 128
    __shared__ float gs[3 * 128];
    for (int i = c; i < 384; i += 128) gs[i] = GP[((size_t)b * 30 + t) * 128 + i];
    __syncthreads();
    float acc = 0.f;
    for (int i = 0; i < 384; ++i) acc += gs[i] * W3[i * 128 + c];
    C3[((size_t)b * 28 + t) * 128 + c] = acc;
    atomicAdd(&S[384 + c], acc);
    atomicAdd(&S[512 + c], acc * acc);
}

// ---------------- BN3 apply + avgpool4 + ReLU ----------------
__global__ void k_bn3pool(const float* __restrict__ C3, const float* __restrict__ S,
                          const float* __restrict__ g3, const float* __restrict__ b3,
                          float* __restrict__ P2) {
    int b = blockIdx.x;  // 8
    int c = threadIdx.x; // 128
    const float inv = 1.f / (float)(NG * 28);
    float mean = S[384 + c] * inv;
    float var  = S[512 + c] * inv - mean * mean;
    float sc = g3[c] * rsqrtf(var + EPS);
    float sh = b3[c] - mean * sc;
    for (int tp = 0; tp < 7; ++tp) {
        float s = 0.f;
        #pragma unroll
        for (int i = 0; i < 4; ++i) s += C3[((size_t)b * 28 + tp * 4 + i) * 128 + c];
        P2[((size_t)b * 7 + tp) * 128 + c] = fmaxf(s * 0.25f * sc + sh, 0.f);
    }
}

// ---------------- final linear + log_softmax ----------------
__global__ void k_final(const float* __restrict__ P2, const float* __restrict__ Wd,
                        const float* __restrict__ bd, float* __restrict__ out) {
    int tid = threadIdx.x; // 32
    int b = tid >> 2, j = tid & 3;
    float acc = bd[j];
    for (int i = 0; i < 896; ++i) acc += P2[b * 896 + i] * Wd[i * 4 + j];
    float m = acc;
    m = fmaxf(m, __shfl_xor(m, 1, 4));
    m = fmaxf(m, __shfl_xor(m, 2, 4));
    float e = expf(acc - m);
    float s = e;
    s += __shfl_xor(s, 1, 4);
    s += __shfl_xor(s, 2, 4);
    out[tid] = acc - m - logf(s);
}

extern "C" void kernel_launch(void* const* d_in, const int* in_sizes, int n_in,
                              void* d_out, int out_size, void* d_ws, size_t ws_size,
                              hipStream_t stream) {
    const float* x   = (const float*)d_in[0];
    const float* pos = (const float*)d_in[1];
    const int*   ei  = (const int*)d_in[2];
    const float* W1  = (const float*)d_in[4];
    const float* g1  = (const float*)d_in[5];
    const float* b1  = (const float*)d_in[6];
    const float* Wp1 = (const float*)d_in[7];
    const float* bp1 = (const float*)d_in[8];
    const float* Wp2 = (const float*)d_in[9];
    const float* bp2 = (const float*)d_in[10];
    const float* Wg1 = (const float*)d_in[11];
    const float* bg1 = (const float*)d_in[12];
    const float* Wg2 = (const float*)d_in[13];
    const float* bg2 = (const float*)d_in[14];
    const float* W2  = (const float*)d_in[15];
    const float* g2  = (const float*)d_in[16];
    const float* b2  = (const float*)d_in[17];
    const float* W3  = (const float*)d_in[18];
    const float* g3  = (const float*)d_in[19];
    const float* b3  = (const float*)d_in[20];
    const float* Wd  = (const float*)d_in[21];
    const float* bd  = (const float*)d_in[22];
    float* out = (float*)d_out;

    float* ws = (float*)d_ws;
    float* P1S  = ws;                  //  1,966,080 f : conv2 pooled sums
    float* PE   = P1S + 1966080;       //     32,768 f
    float* GPb  = PE + 32768;          //     30,720 f
    float* C3   = GPb + 30720;         //     28,672 f
    float* P2   = C3 + 28672;          //      7,168 f
    float* S    = P2 + 7168;           //        640 f
    float* AH   = S + 640;             //     32,768 f
    ushort_t* Cb   = (ushort_t*)(AH + 32768); //  4,194,304 us : conv1 out bf16
    ushort_t* Gout = Cb + 4194304;            // 16,777,216 us : GCN stack out
    ushort_t* Wg1T = Gout + 16777216;         //     16,384 us
    ushort_t* Wg2T = Wg1T + 16384;            //     65,536 us
    ushort_t* WT2  = Wg2T + 65536;            //    229,376 us
    ushort_t* AHb  = WT2 + 229376;            //     32,768 us
    int* DEG = (int*)(AHb + 32768);           //        512 i
    const int* srcv = ei;
    const int* dstv = ei + E_EDGES;

    hipLaunchKernelGGL(k_setup,  dim3(896), dim3(256), 0, stream, Wg1, Wg2, W2, Wg1T, Wg2T, WT2, S, DEG, AH, GPb);
    hipLaunchKernelGGL(k_count,  dim3(16),  dim3(256), 0, stream, dstv, DEG);
    hipLaunchKernelGGL(k_abuild, dim3(16),  dim3(256), 0, stream, srcv, dstv, DEG, AH);
    hipLaunchKernelGGL(k_cvta,   dim3(128), dim3(256), 0, stream, AH, DEG, AHb);
    hipLaunchKernelGGL(k_pe,     dim3(512), dim3(64),  0, stream, pos, Wp1, bp1, Wp2, bp2, PE);
    hipLaunchKernelGGL(k_conv1,  dim3(512), dim3(256), 0, stream, x, W1, Cb, S);
    hipLaunchKernelGGL(k_gcn12,  dim3(1024), dim3(512), 0, stream, Cb, S, g1, b1, PE, Wg1T, Wg2T, AHb, bg1, bg2, Gout);
    hipLaunchKernelGGL(k_conv2_mfma, dim3(512), dim3(512), 0, stream, Gout, WT2, P1S, S);
    hipLaunchKernelGGL(k_bn2gp,  dim3(512, 6), dim3(128), 0, stream, P1S, S, g2, b2, GPb);
    hipLaunchKernelGGL(k_conv3,  dim3(224), dim3(128), 0, stream, GPb, W3, C3, S);
    hipLaunchKernelGGL(k_bn3pool, dim3(8),  dim3(128), 0, stream, C3, S, g3, b3, P2);
    hipLaunchKernelGGL(k_final,  dim3(1),   dim3(32),  0, stream, P2, Wd, bd, out);
}